// Round 2
// baseline (13845.711 us; speedup 1.0000x reference)
//
#include <hip/hip_runtime.h>
#include <cstdio>
#include <type_traits>

#define NQ 10000
#define NT 50000
#define NA 50000
#define E_GR 50000
#define E_LT 50000
#define E_SIM 80000
#define E_COMP 100000
#define E_GEN 50000
#define NEG_SLOPE 0.2f

typedef unsigned short bf16_t;
typedef unsigned int u32;

__device__ __forceinline__ float bf2f(u32 bits) { return __uint_as_float(bits << 16); }
__device__ __forceinline__ u32 f2bf(float f) {
  u32 u = __float_as_uint(f);
  return (u + 0x7FFFu + ((u >> 16) & 1u)) >> 16;   // RTNE
}
__device__ __forceinline__ u32 pack2(float a, float b) { return f2bf(a) | (f2bf(b) << 16); }
__device__ __forceinline__ void unpack8(uint4 u, float* f) {
  f[0] = bf2f(u.x & 0xffffu); f[1] = bf2f(u.x >> 16);
  f[2] = bf2f(u.y & 0xffffu); f[3] = bf2f(u.y >> 16);
  f[4] = bf2f(u.z & 0xffffu); f[5] = bf2f(u.z >> 16);
  f[6] = bf2f(u.w & 0xffffu); f[7] = bf2f(u.w >> 16);
}
// HW atomics via inline asm (guaranteed instruction, no CAS fallback).
__device__ __forceinline__ void atomic_add_f32(float* addr, float v) {
  asm volatile("global_atomic_add_f32 %0, %1, off" :: "v"(addr), "v"(v) : "memory");
}
__device__ __forceinline__ void atomic_pk_bf16(bf16_t* addr, u32 v) {
  asm volatile("global_atomic_pk_add_bf16 %0, %1, off" :: "v"(addr), "v"(v) : "memory");
}

// ---------------------------------------------------------------------------
// 128x128x8 tiled GEMM, fp32 FMA core. C[N,M] = A[N,K] @ B[K,M] (+bias|+=C).
// AT in {float, bf16_t}; CT in {float, bf16_t}. M%128==0, K%8==0, N guarded.
// ---------------------------------------------------------------------------
template <typename AT, typename CT>
__global__ __launch_bounds__(256) void sgemm128(
    const AT* __restrict__ A, const float* __restrict__ B,
    const float* __restrict__ bias, CT* __restrict__ C,
    int N, int K, int M, int accumulate)
{
  __shared__ float As[8][132];
  __shared__ float Bs[8][132];
  const int tid = threadIdx.x;
  const int bn = blockIdx.x * 128;
  const int bm = blockIdx.y * 128;
  const int ty = tid >> 4, tx = tid & 15;

  float acc[8][8];
#pragma unroll
  for (int i = 0; i < 8; ++i)
#pragma unroll
    for (int j = 0; j < 8; ++j) acc[i][j] = 0.f;

  const int arow = tid >> 1;        // 0..127
  const int acol = (tid & 1) * 4;   // 0 or 4
  const int brow = tid >> 5;        // 0..7
  const int bcol = (tid & 31) * 4;  // 0..124
  const int aRow = bm + arow;
  const bool aValid = aRow < N;

  for (int k0 = 0; k0 < K; k0 += 8) {
    float4 av = make_float4(0.f, 0.f, 0.f, 0.f);
    if (aValid) {
      if constexpr (std::is_same<AT, float>::value) {
        av = *(const float4*)(A + (size_t)aRow * K + k0 + acol);
      } else {
        uint2 u = *(const uint2*)(A + (size_t)aRow * K + k0 + acol);
        av.x = bf2f(u.x & 0xffffu); av.y = bf2f(u.x >> 16);
        av.z = bf2f(u.y & 0xffffu); av.w = bf2f(u.y >> 16);
      }
    }
    float4 bv = *(const float4*)(B + (size_t)(k0 + brow) * M + bn + bcol);
    __syncthreads();
    As[acol + 0][arow] = av.x;
    As[acol + 1][arow] = av.y;
    As[acol + 2][arow] = av.z;
    As[acol + 3][arow] = av.w;
    *(float4*)(&Bs[brow][bcol]) = bv;
    __syncthreads();
#pragma unroll
    for (int kk = 0; kk < 8; ++kk) {
      float a[8], b[8];
      *(float4*)(a)     = *(const float4*)(&As[kk][ty * 8]);
      *(float4*)(a + 4) = *(const float4*)(&As[kk][ty * 8 + 4]);
      *(float4*)(b)     = *(const float4*)(&Bs[kk][tx * 4]);
      *(float4*)(b + 4) = *(const float4*)(&Bs[kk][64 + tx * 4]);
#pragma unroll
      for (int i = 0; i < 8; ++i)
#pragma unroll
        for (int j = 0; j < 8; ++j) acc[i][j] = fmaf(a[i], b[j], acc[i][j]);
    }
  }

  float4 bv0 = make_float4(0.f, 0.f, 0.f, 0.f), bv1 = bv0;
  if (!accumulate && bias) {
    bv0 = *(const float4*)(bias + bn + tx * 4);
    bv1 = *(const float4*)(bias + bn + 64 + tx * 4);
  }
#pragma unroll
  for (int i = 0; i < 8; ++i) {
    int row = bm + ty * 8 + i;
    if (row >= N) break;
    if constexpr (std::is_same<CT, float>::value) {
      float* c0 = C + (size_t)row * M + bn + tx * 4;
      float* c1 = C + (size_t)row * M + bn + 64 + tx * 4;
      if (accumulate) {
        float4 o0 = *(float4*)c0, o1 = *(float4*)c1;
        o0.x += acc[i][0]; o0.y += acc[i][1]; o0.z += acc[i][2]; o0.w += acc[i][3];
        o1.x += acc[i][4]; o1.y += acc[i][5]; o1.z += acc[i][6]; o1.w += acc[i][7];
        *(float4*)c0 = o0; *(float4*)c1 = o1;
      } else {
        *(float4*)c0 = make_float4(acc[i][0] + bv0.x, acc[i][1] + bv0.y,
                                   acc[i][2] + bv0.z, acc[i][3] + bv0.w);
        *(float4*)c1 = make_float4(acc[i][4] + bv1.x, acc[i][5] + bv1.y,
                                   acc[i][6] + bv1.z, acc[i][7] + bv1.w);
      }
    } else {
      bf16_t* c0 = C + (size_t)row * M + bn + tx * 4;
      bf16_t* c1 = C + (size_t)row * M + bn + 64 + tx * 4;
      uint2 s0, s1;
      s0.x = pack2(acc[i][0] + bv0.x, acc[i][1] + bv0.y);
      s0.y = pack2(acc[i][2] + bv0.z, acc[i][3] + bv0.w);
      s1.x = pack2(acc[i][4] + bv1.x, acc[i][5] + bv1.y);
      s1.y = pack2(acc[i][6] + bv1.z, acc[i][7] + bv1.w);
      *(uint2*)c0 = s0; *(uint2*)c1 = s1;
    }
  }
}

// ---------------------------------------------------------------------------
// GATv2 edge pass A: wave/edge. logit_h = att[h,:].lrelu(xl+xr); ex=exp(logit)
// (segment-max dropped: softmax is shift-invariant; logits are O(1)).
// ---------------------------------------------------------------------------
__global__ __launch_bounds__(256) void gat_edge(
    const bf16_t* __restrict__ xl, const bf16_t* __restrict__ xr,
    const int* __restrict__ src, const int* __restrict__ dst,
    const float* __restrict__ att, float* __restrict__ elog,
    float* __restrict__ den, int E)
{
  int e = blockIdx.x * 4 + (threadIdx.x >> 6);
  if (e >= E) return;
  int lane = threadIdx.x & 63;
  int s = src[e], d = dst[e];
  uint4 ua = *(const uint4*)(xl + (size_t)s * 512 + lane * 8);
  uint4 ub = *(const uint4*)(xr + (size_t)d * 512 + lane * 8);
  float fa[8], fb[8];
  unpack8(ua, fa); unpack8(ub, fb);
  float4 t0 = *(const float4*)(att + lane * 8);
  float4 t1 = *(const float4*)(att + lane * 8 + 4);
  const float* t = &t0.x;
  float p = 0.f;
#pragma unroll
  for (int k = 0; k < 8; ++k) {
    float x = fa[k] + fb[k];
    float tk = (k < 4) ? (&t0.x)[k] : (&t1.x)[k - 4];
    p = fmaf(tk, x >= 0.f ? x : NEG_SLOPE * x, p);
  }
  (void)t;
#pragma unroll
  for (int m = 8; m >= 1; m >>= 1) p += __shfl_xor(p, m);
  if ((lane & 15) == 0) {
    int h = lane >> 4;
    float ex = __expf(p);
    elog[(size_t)e * 4 + h] = ex;
    atomic_add_f32(&den[(size_t)d * 4 + h], ex);
  }
}

// Edge pass C: alpha-weighted scatter of xl[src] into per-dst accumulator.
template <typename AccT>
__global__ __launch_bounds__(256) void gat_aggr(
    const bf16_t* __restrict__ xl,
    const int* __restrict__ src, const int* __restrict__ dst,
    const float* __restrict__ elog, const float* __restrict__ den,
    AccT* __restrict__ acc, int E)
{
  int e = blockIdx.x * 4 + (threadIdx.x >> 6);
  if (e >= E) return;
  int lane = threadIdx.x & 63;
  int s = src[e], d = dst[e];
  int h = lane >> 4;
  float alpha = elog[(size_t)e * 4 + h] / (den[(size_t)d * 4 + h] + 1e-16f);
  uint4 u = *(const uint4*)(xl + (size_t)s * 512 + lane * 8);
  float f[8];
  unpack8(u, f);
  if constexpr (std::is_same<AccT, float>::value) {
    float* out = acc + (size_t)d * 512 + lane * 8;
#pragma unroll
    for (int k = 0; k < 8; ++k) atomic_add_f32(out + k, alpha * f[k]);
  } else {
    bf16_t* out = acc + (size_t)d * 512 + lane * 8;
    atomic_pk_bf16(out + 0, pack2(alpha * f[0], alpha * f[1]));
    atomic_pk_bf16(out + 2, pack2(alpha * f[2], alpha * f[3]));
    atomic_pk_bf16(out + 4, pack2(alpha * f[4], alpha * f[5]));
    atomic_pk_bf16(out + 6, pack2(alpha * f[6], alpha * f[7]));
  }
}

// h_new = relu((acc + b0 [+ b1 + b2]) * inv_div) -> bf16, 8 elems/thread.
template <typename AccT>
__global__ __launch_bounds__(256) void finalize_relu(
    const AccT* __restrict__ acc, const float* __restrict__ b0,
    const float* __restrict__ b1, const float* __restrict__ b2,
    float inv_div, bf16_t* __restrict__ out, long n8)
{
  long g = (long)blockIdx.x * 256 + threadIdx.x;
  if (g >= n8) return;
  long base = g * 8;
  int j = (int)(base & 511);
  float v[8];
  if constexpr (std::is_same<AccT, float>::value) {
    float4 a0 = *(const float4*)(acc + base);
    float4 a1 = *(const float4*)(acc + base + 4);
    v[0] = a0.x; v[1] = a0.y; v[2] = a0.z; v[3] = a0.w;
    v[4] = a1.x; v[5] = a1.y; v[6] = a1.z; v[7] = a1.w;
  } else {
    unpack8(*(const uint4*)(acc + base), v);
  }
#pragma unroll
  for (int k = 0; k < 8; ++k) {
    float b = b0[j + k];
    if (b1) b += b1[j + k];
    if (b2) b += b2[j + k];
    v[k] = fmaxf((v[k] + b) * inv_div, 0.f);
  }
  uint4 s;
  s.x = pack2(v[0], v[1]); s.y = pack2(v[2], v[3]);
  s.z = pack2(v[4], v[5]); s.w = pack2(v[6], v[7]);
  *(uint4*)(out + base) = s;
}

// out[e,:512] = src[idx[e],:512]  (bf16, uint4 = 8 elems per thread)
__global__ __launch_bounds__(256) void gather512(
    const bf16_t* __restrict__ src, const int* __restrict__ idx,
    bf16_t* __restrict__ out, int E)
{
  int g = blockIdx.x * blockDim.x + threadIdx.x;
  if (g >= E * 64) return;
  int e = g >> 6, c = g & 63;
  ((uint4*)out)[g] = ((const uint4*)src)[(size_t)idx[e] * 64 + c];
}

// afh = relu(answer_features @ W1 + b1), K=6, M=64 (fp32)
__global__ __launch_bounds__(256) void af_hidden(
    const float* __restrict__ af, const float* __restrict__ W1,
    const float* __restrict__ b1, float* __restrict__ out, int n)
{
  int t = blockIdx.x * blockDim.x + threadIdx.x;
  if (t >= n * 64) return;
  int i = t >> 6, j = t & 63;
  const float* a = af + (size_t)i * 6;
  float s = b1[j];
#pragma unroll
  for (int k = 0; k < 6; ++k) s = fmaf(a[k], W1[k * 64 + j], s);
  out[t] = fmaxf(s, 0.f);
}

// sim edges with appended self loops
__global__ __launch_bounds__(256) void build_sim(
    const int* __restrict__ ei, int* __restrict__ ss, int* __restrict__ sd)
{
  int t = blockIdx.x * blockDim.x + threadIdx.x;
  if (t >= E_SIM + NQ) return;
  if (t < E_SIM) { ss[t] = ei[t]; sd[t] = ei[E_SIM + t]; }
  else           { ss[t] = t - E_SIM; sd[t] = t - E_SIM; }
}

// q = LN(qpre)*g+b; r = LN(rpre)*g+b; out = dot(q,r)/16 + sb. Wave/edge.
__global__ __launch_bounds__(256) void head_final(
    const float* __restrict__ qpre, const float* __restrict__ rpre,
    const float* __restrict__ qg, const float* __restrict__ qb,
    const float* __restrict__ rg, const float* __restrict__ rb,
    const float* __restrict__ score_bias, float* __restrict__ out, int E)
{
  int e = blockIdx.x * 4 + (threadIdx.x >> 6);
  if (e >= E) return;
  int lane = threadIdx.x & 63;

  float4 q = *(const float4*)(qpre + (size_t)e * 256 + lane * 4);
  float s = q.x + q.y + q.z + q.w;
#pragma unroll
  for (int m = 32; m >= 1; m >>= 1) s += __shfl_xor(s, m);
  float mu = s * (1.f / 256.f);
  float dq0 = q.x - mu, dq1 = q.y - mu, dq2 = q.z - mu, dq3 = q.w - mu;
  float v = dq0 * dq0 + dq1 * dq1 + dq2 * dq2 + dq3 * dq3;
#pragma unroll
  for (int m = 32; m >= 1; m >>= 1) v += __shfl_xor(v, m);
  float rstd = rsqrtf(v * (1.f / 256.f) + 1e-5f);
  float4 g4 = *(const float4*)(qg + lane * 4);
  float4 b4 = *(const float4*)(qb + lane * 4);
  float qn0 = dq0 * rstd * g4.x + b4.x, qn1 = dq1 * rstd * g4.y + b4.y;
  float qn2 = dq2 * rstd * g4.z + b4.z, qn3 = dq3 * rstd * g4.w + b4.w;

  float4 r = *(const float4*)(rpre + (size_t)e * 256 + lane * 4);
  s = r.x + r.y + r.z + r.w;
#pragma unroll
  for (int m = 32; m >= 1; m >>= 1) s += __shfl_xor(s, m);
  mu = s * (1.f / 256.f);
  float dr0 = r.x - mu, dr1 = r.y - mu, dr2 = r.z - mu, dr3 = r.w - mu;
  v = dr0 * dr0 + dr1 * dr1 + dr2 * dr2 + dr3 * dr3;
#pragma unroll
  for (int m = 32; m >= 1; m >>= 1) v += __shfl_xor(v, m);
  rstd = rsqrtf(v * (1.f / 256.f) + 1e-5f);
  g4 = *(const float4*)(rg + lane * 4);
  b4 = *(const float4*)(rb + lane * 4);
  float rn0 = dr0 * rstd * g4.x + b4.x, rn1 = dr1 * rstd * g4.y + b4.y;
  float rn2 = dr2 * rstd * g4.z + b4.z, rn3 = dr3 * rstd * g4.w + b4.w;

  float d = qn0 * rn0 + qn1 * rn1 + qn2 * rn2 + qn3 * rn3;
#pragma unroll
  for (int m = 32; m >= 1; m >>= 1) d += __shfl_xor(d, m);
  if (lane == 0) out[e] = d * 0.0625f + score_bias[0];
}

// ---------------------------------------------------------------------------
extern "C" void kernel_launch(void* const* d_in, const int* in_sizes, int n_in,
                              void* d_out, int out_size, void* d_ws, size_t ws_size,
                              hipStream_t stream) {
  (void)in_sizes; (void)n_in; (void)out_size;
  const float* xq      = (const float*)d_in[0];
  const float* xt      = (const float*)d_in[1];
  const float* xa      = (const float*)d_in[2];
  const float* af      = (const float*)d_in[3];
  const float* qp_W    = (const float*)d_in[4];
  const float* qp_b    = (const float*)d_in[5];
  const float* tp_W    = (const float*)d_in[6];
  const float* tp_b    = (const float*)d_in[7];
  const float* ap_W    = (const float*)d_in[8];
  const float* ap_b    = (const float*)d_in[9];
  const float* afp_W1  = (const float*)d_in[10];
  const float* afp_b1  = (const float*)d_in[11];
  const float* afp_W2  = (const float*)d_in[12];
  const float* afp_b2  = (const float*)d_in[13];
  const float* conv_Wl = (const float*)d_in[14];
  const float* conv_bl = (const float*)d_in[15];
  const float* conv_Wr = (const float*)d_in[16];
  const float* conv_br = (const float*)d_in[17];
  const float* conv_att  = (const float*)d_in[18];
  const float* conv_bias = (const float*)d_in[19];
  const float* qh_W    = (const float*)d_in[20];
  const float* qh_b    = (const float*)d_in[21];
  const float* qh_g    = (const float*)d_in[22];
  const float* qh_beta = (const float*)d_in[23];
  const float* rh_W    = (const float*)d_in[24];
  const float* rh_b    = (const float*)d_in[25];
  const float* rh_g    = (const float*)d_in[26];
  const float* rh_beta = (const float*)d_in[27];
  const float* score_b = (const float*)d_in[28];
  const int* ei_gr   = (const int*)d_in[29];
  const int* ei_lt   = (const int*)d_in[30];
  const int* ei_sim  = (const int*)d_in[31];
  const int* ei_comp = (const int*)d_in[32];
  const int* ei_gen  = (const int*)d_in[33];

  char* base = (char*)d_ws;
  size_t off = 0;
  auto alloc = [&](size_t bytes) {
    void* p = base + off;
    off = (off + bytes + 255) & ~(size_t)255;
    return p;
  };
  bf16_t* hq   = (bf16_t*)alloc((size_t)NQ * 512 * 2);   // 10.24 MB
  bf16_t* ht   = (bf16_t*)alloc((size_t)NT * 512 * 2);   // 51.2
  bf16_t* ha   = (bf16_t*)alloc((size_t)NA * 512 * 2);   // 51.2 (also acca)
  bf16_t* acct = (bf16_t*)alloc((size_t)NT * 512 * 2);   // 51.2 (also qpre f32)
  float*  accq = (float*) alloc((size_t)NQ * 512 * 4);   // 20.48 (also afh f32)
  bf16_t* xlb  = (bf16_t*)alloc((size_t)50000 * 512 * 2);// 51.2 (also gathers/af_emb)
  bf16_t* xrb  = (bf16_t*)alloc((size_t)50000 * 512 * 2);// 51.2 (also rpre f32)
  float*  elog = (float*) alloc((size_t)100000 * 4 * 4); // 1.6
  float*  den  = (float*) alloc((size_t)50000 * 4 * 4);  // 0.8
  int* simsrc  = (int*)   alloc((size_t)(E_SIM + NQ) * 4);
  int* simdst  = (int*)   alloc((size_t)(E_SIM + NQ) * 4);
  if (off > ws_size) {
    fprintf(stderr, "kernel_launch: ws too small, need %zu have %zu\n", off, ws_size);
    return;
  }

  // Input projections (fp32 A -> bf16 C)
  {
    dim3 g(512 / 128, (NQ + 127) / 128);
    sgemm128<float, bf16_t><<<g, 256, 0, stream>>>(xq, qp_W, qp_b, hq, NQ, 384, 512, 0);
  }
  {
    dim3 g(512 / 128, (NT + 127) / 128);
    sgemm128<float, bf16_t><<<g, 256, 0, stream>>>(xt, tp_W, tp_b, ht, NT, 384, 512, 0);
  }
  {
    dim3 g(512 / 128, (NA + 127) / 128);
    sgemm128<float, bf16_t><<<g, 256, 0, stream>>>(xa, ap_W, ap_b, ha, NA, 384, 512, 0);
  }
  build_sim<<<(E_SIM + NQ + 255) / 256, 256, 0, stream>>>(ei_sim, simsrc, simdst);

  // Relation processing order puts lt LAST so old ha dies after its lin_r
  // GEMM and the ha buffer doubles as the answer accumulator.
  struct Rel {
    const bf16_t* xs; const bf16_t* xd; const int* src; const int* dst;
    int Ns, Nd, E, po;       // po = original relation index (param offset)
    int accKind;             // 0=accq(f32) 1=acct(bf16) 2=ha(bf16, zero here)
  };
  for (int l = 0; l < 2; ++l) {
    hipMemsetAsync(accq, 0, (size_t)NQ * 512 * 4, stream);
    hipMemsetAsync(acct, 0, (size_t)NT * 512 * 2, stream);
    Rel rels[6] = {
      {hq, ht, ei_gr,        ei_gr + E_GR,     NQ, NT, E_GR,       0, 1}, // gr
      {ht, hq, ei_gr + E_GR, ei_gr,            NT, NQ, E_GR,       1, 0}, // rgr
      {ha, ht, ei_lt + E_LT, ei_lt,            NA, NT, E_LT,       3, 1}, // rlt
      {hq, hq, simsrc,       simdst,           NQ, NQ, E_SIM + NQ, 4, 0}, // sim
      {ht, ht, ei_comp,      ei_comp + E_COMP, NT, NT, E_COMP,     5, 1}, // comp
      {ht, ha, ei_lt,        ei_lt + E_LT,     NT, NA, E_LT,       2, 2}, // lt LAST
    };
    for (int r = 0; r < 6; ++r) {
      const Rel& R = rels[r];
      size_t po = (size_t)l * 6 + R.po;
      {
        dim3 g(512 / 128, (R.Ns + 127) / 128);
        sgemm128<bf16_t, bf16_t><<<g, 256, 0, stream>>>(
            R.xs, conv_Wl + po * 512 * 512, conv_bl + po * 512, xlb, R.Ns, 512, 512, 0);
      }
      {
        dim3 g(512 / 128, (R.Nd + 127) / 128);
        sgemm128<bf16_t, bf16_t><<<g, 256, 0, stream>>>(
            R.xd, conv_Wr + po * 512 * 512, conv_br + po * 512, xrb, R.Nd, 512, 512, 0);
      }
      if (R.accKind == 2)  // old ha fully consumed; becomes answer accumulator
        hipMemsetAsync(ha, 0, (size_t)NA * 512 * 2, stream);
      hipMemsetAsync(den, 0, (size_t)R.Nd * 4 * 4, stream);
      int eb = (R.E + 3) / 4;
      gat_edge<<<eb, 256, 0, stream>>>(xlb, xrb, R.src, R.dst,
                                       conv_att + po * 512, elog, den, R.E);
      if (R.accKind == 0)
        gat_aggr<float><<<eb, 256, 0, stream>>>(xlb, R.src, R.dst, elog, den, accq, R.E);
      else if (R.accKind == 1)
        gat_aggr<bf16_t><<<eb, 256, 0, stream>>>(xlb, R.src, R.dst, elog, den, acct, R.E);
      else
        gat_aggr<bf16_t><<<eb, 256, 0, stream>>>(xlb, R.src, R.dst, elog, den, ha, R.E);
    }
    size_t b = (size_t)l * 6;
    finalize_relu<float><<<(NQ * 64 + 255) / 256, 256, 0, stream>>>(
        accq, conv_bias + (b + 1) * 512, conv_bias + (b + 4) * 512, nullptr,
        0.5f, hq, (long)NQ * 64);
    finalize_relu<bf16_t><<<(NT * 64 + 255) / 256, 256, 0, stream>>>(
        acct, conv_bias + (b + 0) * 512, conv_bias + (b + 3) * 512,
        conv_bias + (b + 5) * 512, 1.f / 3.f, ht, (long)NT * 64);
    finalize_relu<bf16_t><<<(NA * 64 + 255) / 256, 256, 0, stream>>>(
        ha, conv_bias + (b + 2) * 512, nullptr, nullptr, 1.f, ha, (long)NA * 64);
  }

  // Head. qpre(f32)->acct region, rpre(f32)->xrb region, gathers/af_emb->xlb,
  // afh(f32)->accq.
  float* qpre = (float*)acct;
  float* rpre = (float*)xrb;
  float* afh  = accq;
  const int* gsrc = ei_gen;
  const int* gdst = ei_gen + E_GEN;
  dim3 gg((E_GEN * 64 + 255) / 256);
  dim3 gh(256 / 128, (E_GEN + 127) / 128);

  gather512<<<gg, 256, 0, stream>>>(hq, gsrc, xlb, E_GEN);                 // q_emb
  sgemm128<bf16_t, float><<<gh, 256, 0, stream>>>(xlb, qh_W, qh_b, qpre,
                                                  E_GEN, 512, 256, 0);
  gather512<<<gg, 256, 0, stream>>>(ht, gdst, xlb, E_GEN);                 // t_emb
  sgemm128<bf16_t, float><<<gh, 256, 0, stream>>>(xlb, rh_W, rh_b, rpre,
                                                  E_GEN, 512, 256, 0);
  gather512<<<gg, 256, 0, stream>>>(ha, gdst, xlb, E_GEN);                 // a_emb
  sgemm128<bf16_t, float><<<gh, 256, 0, stream>>>(xlb, rh_W + 512 * 256, nullptr,
                                                  rpre, E_GEN, 512, 256, 1);
  af_hidden<<<(E_GEN * 64 + 255) / 256, 256, 0, stream>>>(af, afp_W1, afp_b1,
                                                          afh, E_GEN);
  {
    dim3 g(512 / 128, (E_GEN + 127) / 128);
    sgemm128<float, bf16_t><<<g, 256, 0, stream>>>(afh, afp_W2, afp_b2, xlb,
                                                   E_GEN, 64, 512, 0);     // af_emb
  }
  sgemm128<bf16_t, float><<<gh, 256, 0, stream>>>(xlb, rh_W + 1024 * 256, nullptr,
                                                  rpre, E_GEN, 512, 256, 1);
  head_final<<<(E_GEN + 3) / 4, 256, 0, stream>>>(
      qpre, rpre, qh_g, qh_beta, rh_g, rh_beta, score_b, (float*)d_out, E_GEN);
}

// Round 4
// 8627.634 us; speedup vs baseline: 1.6048x; 1.6048x over previous
//
#include <hip/hip_runtime.h>
#include <cstdio>
#include <type_traits>

#define NQ 10000
#define NT 50000
#define NA 50000
#define E_GR 50000
#define E_LT 50000
#define E_SIM 80000
#define E_COMP 100000
#define E_GEN 50000
#define MAXE 100000
#define NEG_SLOPE 0.2f

typedef unsigned short bf16_t;
typedef unsigned int u32;

__device__ __forceinline__ float bf2f(u32 bits) { return __uint_as_float(bits << 16); }
__device__ __forceinline__ u32 f2bf(float f) {
  u32 u = __float_as_uint(f);
  return (u + 0x7FFFu + ((u >> 16) & 1u)) >> 16;   // RTNE
}
__device__ __forceinline__ u32 pack2(float a, float b) { return f2bf(a) | (f2bf(b) << 16); }
__device__ __forceinline__ void unpack8(uint4 u, float* f) {
  f[0] = bf2f(u.x & 0xffffu); f[1] = bf2f(u.x >> 16);
  f[2] = bf2f(u.y & 0xffffu); f[3] = bf2f(u.y >> 16);
  f[4] = bf2f(u.z & 0xffffu); f[5] = bf2f(u.z >> 16);
  f[6] = bf2f(u.w & 0xffffu); f[7] = bf2f(u.w >> 16);
}

// ---------------------------------------------------------------------------
// 128x128x8 tiled GEMM, fp32 FMA core. C[N,M] = A[N,K] @ B[K,M] (+bias|+=C).
// ---------------------------------------------------------------------------
template <typename AT, typename CT>
__global__ __launch_bounds__(256) void sgemm128(
    const AT* __restrict__ A, const float* __restrict__ B,
    const float* __restrict__ bias, CT* __restrict__ C,
    int N, int K, int M, int accumulate)
{
  __shared__ float As[8][132];
  __shared__ float Bs[8][132];
  const int tid = threadIdx.x;
  const int bn = blockIdx.x * 128;
  const int bm = blockIdx.y * 128;
  const int ty = tid >> 4, tx = tid & 15;

  float acc[8][8];
#pragma unroll
  for (int i = 0; i < 8; ++i)
#pragma unroll
    for (int j = 0; j < 8; ++j) acc[i][j] = 0.f;

  const int arow = tid >> 1;
  const int acol = (tid & 1) * 4;
  const int brow = tid >> 5;
  const int bcol = (tid & 31) * 4;
  const int aRow = bm + arow;
  const bool aValid = aRow < N;

  for (int k0 = 0; k0 < K; k0 += 8) {
    float4 av = make_float4(0.f, 0.f, 0.f, 0.f);
    if (aValid) {
      if constexpr (std::is_same<AT, float>::value) {
        av = *(const float4*)(A + (size_t)aRow * K + k0 + acol);
      } else {
        uint2 u = *(const uint2*)(A + (size_t)aRow * K + k0 + acol);
        av.x = bf2f(u.x & 0xffffu); av.y = bf2f(u.x >> 16);
        av.z = bf2f(u.y & 0xffffu); av.w = bf2f(u.y >> 16);
      }
    }
    float4 bv = *(const float4*)(B + (size_t)(k0 + brow) * M + bn + bcol);
    __syncthreads();
    As[acol + 0][arow] = av.x;
    As[acol + 1][arow] = av.y;
    As[acol + 2][arow] = av.z;
    As[acol + 3][arow] = av.w;
    *(float4*)(&Bs[brow][bcol]) = bv;
    __syncthreads();
#pragma unroll
    for (int kk = 0; kk < 8; ++kk) {
      float a[8], b[8];
      *(float4*)(a)     = *(const float4*)(&As[kk][ty * 8]);
      *(float4*)(a + 4) = *(const float4*)(&As[kk][ty * 8 + 4]);
      *(float4*)(b)     = *(const float4*)(&Bs[kk][tx * 4]);
      *(float4*)(b + 4) = *(const float4*)(&Bs[kk][64 + tx * 4]);
#pragma unroll
      for (int i = 0; i < 8; ++i)
#pragma unroll
        for (int j = 0; j < 8; ++j) acc[i][j] = fmaf(a[i], b[j], acc[i][j]);
    }
  }

  float4 bv0 = make_float4(0.f, 0.f, 0.f, 0.f), bv1 = bv0;
  if (!accumulate && bias) {
    bv0 = *(const float4*)(bias + bn + tx * 4);
    bv1 = *(const float4*)(bias + bn + 64 + tx * 4);
  }
#pragma unroll
  for (int i = 0; i < 8; ++i) {
    int row = bm + ty * 8 + i;
    if (row >= N) break;
    if constexpr (std::is_same<CT, float>::value) {
      float* c0 = C + (size_t)row * M + bn + tx * 4;
      float* c1 = C + (size_t)row * M + bn + 64 + tx * 4;
      if (accumulate) {
        float4 o0 = *(float4*)c0, o1 = *(float4*)c1;
        o0.x += acc[i][0]; o0.y += acc[i][1]; o0.z += acc[i][2]; o0.w += acc[i][3];
        o1.x += acc[i][4]; o1.y += acc[i][5]; o1.z += acc[i][6]; o1.w += acc[i][7];
        *(float4*)c0 = o0; *(float4*)c1 = o1;
      } else {
        *(float4*)c0 = make_float4(acc[i][0] + bv0.x, acc[i][1] + bv0.y,
                                   acc[i][2] + bv0.z, acc[i][3] + bv0.w);
        *(float4*)c1 = make_float4(acc[i][4] + bv1.x, acc[i][5] + bv1.y,
                                   acc[i][6] + bv1.z, acc[i][7] + bv1.w);
      }
    } else {
      bf16_t* c0 = C + (size_t)row * M + bn + tx * 4;
      bf16_t* c1 = C + (size_t)row * M + bn + 64 + tx * 4;
      uint2 s0, s1;
      s0.x = pack2(acc[i][0] + bv0.x, acc[i][1] + bv0.y);
      s0.y = pack2(acc[i][2] + bv0.z, acc[i][3] + bv0.w);
      s1.x = pack2(acc[i][4] + bv1.x, acc[i][5] + bv1.y);
      s1.y = pack2(acc[i][6] + bv1.z, acc[i][7] + bv1.w);
      *(uint2*)c0 = s0; *(uint2*)c1 = s1;
    }
  }
}

// ---------------------------------------------------------------------------
// CSR build: histogram w/ slot assignment, 3-kernel exclusive scan, scatter.
// ---------------------------------------------------------------------------
__global__ __launch_bounds__(256) void csr_hist(
    const int* __restrict__ dst, int* __restrict__ deg, int* __restrict__ pos, int E)
{
  int e = blockIdx.x * 256 + threadIdx.x;
  if (e >= E) return;
  pos[e] = atomicAdd(&deg[dst[e]], 1);
}

// exclusive scan over n ints; 1024 items/block (256 thr x 4)
__global__ __launch_bounds__(256) void scan1(
    const int* __restrict__ in, int* __restrict__ out, int* __restrict__ bsum, int n)
{
  __shared__ int sm[256];
  int t = threadIdx.x;
  int base = blockIdx.x * 1024 + t * 4;
  int v[4], sum = 0;
#pragma unroll
  for (int k = 0; k < 4; ++k) { v[k] = (base + k < n) ? in[base + k] : 0; sum += v[k]; }
  sm[t] = sum;
  __syncthreads();
  for (int off = 1; off < 256; off <<= 1) {
    int x = (t >= off) ? sm[t - off] : 0;
    __syncthreads();
    sm[t] += x;
    __syncthreads();
  }
  int run = (t > 0) ? sm[t - 1] : 0;
  if (t == 255) bsum[blockIdx.x] = sm[255];
#pragma unroll
  for (int k = 0; k < 4; ++k) {
    if (base + k < n) out[base + k] = run;
    run += v[k];
  }
}

__global__ __launch_bounds__(64) void scan2(int* __restrict__ bsum, int nb)
{
  __shared__ int sm[64];
  int t = threadIdx.x;
  int v = (t < nb) ? bsum[t] : 0;
  sm[t] = v;
  __syncthreads();
  for (int off = 1; off < 64; off <<= 1) {
    int x = (t >= off) ? sm[t - off] : 0;
    __syncthreads();
    sm[t] += x;
    __syncthreads();
  }
  if (t < nb) bsum[t] = sm[t] - v;   // exclusive
}

__global__ __launch_bounds__(256) void scan3(
    int* __restrict__ out, const int* __restrict__ bsum, int n)
{
  int g = blockIdx.x * 256 + threadIdx.x;
  if (g < n) out[g] += bsum[g >> 10];
}

__global__ __launch_bounds__(256) void csr_scatter(
    const int* __restrict__ dst, const int* __restrict__ start,
    const int* __restrict__ pos, int* __restrict__ eidx, int E)
{
  int e = blockIdx.x * 256 + threadIdx.x;
  if (e >= E) return;
  eidx[start[dst[e]] + pos[e]] = e;
}

// ---------------------------------------------------------------------------
// Fused GATv2 message+softmax+aggregate, one wave per dst node, no atomics.
// Lane owns 8 channels (head = lane>>4). Softmax max-shift dropped (invariant).
// ---------------------------------------------------------------------------
template <typename AccT>
__global__ __launch_bounds__(256) void gat_fused(
    const bf16_t* __restrict__ xl, const bf16_t* __restrict__ xr,
    const int* __restrict__ srcArr, const int* __restrict__ start,
    const int* __restrict__ deg, const int* __restrict__ eidx,
    const float* __restrict__ att, AccT* __restrict__ acc,
    int Nd, int accumulate)
{
  int d = blockIdx.x * 4 + (threadIdx.x >> 6);
  if (d >= Nd) return;
  int lane = threadIdx.x & 63;

  float xrr[8];
  unpack8(*(const uint4*)(xr + (size_t)d * 512 + lane * 8), xrr);
  float at[8];
  *(float4*)(at)     = *(const float4*)(att + lane * 8);
  *(float4*)(at + 4) = *(const float4*)(att + lane * 8 + 4);

  float acc8[8] = {0.f, 0.f, 0.f, 0.f, 0.f, 0.f, 0.f, 0.f};
  float den = 0.f;
  int n = deg[d], s0 = start[d];
  for (int i = 0; i < n; ++i) {
    int e = eidx[s0 + i];
    int s = srcArr[e];
    float f[8];
    unpack8(*(const uint4*)(xl + (size_t)s * 512 + lane * 8), f);
    float p = 0.f;
#pragma unroll
    for (int k = 0; k < 8; ++k) {
      float x = f[k] + xrr[k];
      p = fmaf(at[k], x >= 0.f ? x : NEG_SLOPE * x, p);
    }
#pragma unroll
    for (int m = 8; m >= 1; m >>= 1) p += __shfl_xor(p, m);  // 16-lane group = head
    float ex = __expf(p);
    den += ex;
#pragma unroll
    for (int k = 0; k < 8; ++k) acc8[k] = fmaf(ex, f[k], acc8[k]);
  }
  float inv = 1.f / (den + 1e-16f);
#pragma unroll
  for (int k = 0; k < 8; ++k) acc8[k] *= inv;

  if constexpr (std::is_same<AccT, float>::value) {
    float* out = acc + (size_t)d * 512 + lane * 8;
    if (accumulate) {
      float4 o0 = *(float4*)out, o1 = *(float4*)(out + 4);
      o0.x += acc8[0]; o0.y += acc8[1]; o0.z += acc8[2]; o0.w += acc8[3];
      o1.x += acc8[4]; o1.y += acc8[5]; o1.z += acc8[6]; o1.w += acc8[7];
      *(float4*)out = o0; *(float4*)(out + 4) = o1;
    } else {
      *(float4*)out = make_float4(acc8[0], acc8[1], acc8[2], acc8[3]);
      *(float4*)(out + 4) = make_float4(acc8[4], acc8[5], acc8[6], acc8[7]);
    }
  } else {
    bf16_t* out = acc + (size_t)d * 512 + lane * 8;
    if (accumulate) {
      float old[8];
      unpack8(*(const uint4*)out, old);
#pragma unroll
      for (int k = 0; k < 8; ++k) acc8[k] += old[k];
    }
    uint4 s;
    s.x = pack2(acc8[0], acc8[1]); s.y = pack2(acc8[2], acc8[3]);
    s.z = pack2(acc8[4], acc8[5]); s.w = pack2(acc8[6], acc8[7]);
    *(uint4*)out = s;
  }
}

// h_new = relu((acc + b0 [+ b1 + b2]) * inv_div) -> bf16, 8 elems/thread.
template <typename AccT>
__global__ __launch_bounds__(256) void finalize_relu(
    const AccT* __restrict__ acc, const float* __restrict__ b0,
    const float* __restrict__ b1, const float* __restrict__ b2,
    float inv_div, bf16_t* __restrict__ out, long n8)
{
  long g = (long)blockIdx.x * 256 + threadIdx.x;
  if (g >= n8) return;
  long base = g * 8;
  int j = (int)(base & 511);
  float v[8];
  if constexpr (std::is_same<AccT, float>::value) {
    float4 a0 = *(const float4*)(acc + base);
    float4 a1 = *(const float4*)(acc + base + 4);
    v[0] = a0.x; v[1] = a0.y; v[2] = a0.z; v[3] = a0.w;
    v[4] = a1.x; v[5] = a1.y; v[6] = a1.z; v[7] = a1.w;
  } else {
    unpack8(*(const uint4*)(acc + base), v);
  }
#pragma unroll
  for (int k = 0; k < 8; ++k) {
    float b = b0[j + k];
    if (b1) b += b1[j + k];
    if (b2) b += b2[j + k];
    v[k] = fmaxf((v[k] + b) * inv_div, 0.f);
  }
  uint4 s;
  s.x = pack2(v[0], v[1]); s.y = pack2(v[2], v[3]);
  s.z = pack2(v[4], v[5]); s.w = pack2(v[6], v[7]);
  *(uint4*)(out + base) = s;
}

__global__ __launch_bounds__(256) void gather512(
    const bf16_t* __restrict__ src, const int* __restrict__ idx,
    bf16_t* __restrict__ out, int E)
{
  int g = blockIdx.x * blockDim.x + threadIdx.x;
  if (g >= E * 64) return;
  int e = g >> 6, c = g & 63;
  ((uint4*)out)[g] = ((const uint4*)src)[(size_t)idx[e] * 64 + c];
}

__global__ __launch_bounds__(256) void af_hidden(
    const float* __restrict__ af, const float* __restrict__ W1,
    const float* __restrict__ b1, float* __restrict__ out, int n)
{
  int t = blockIdx.x * blockDim.x + threadIdx.x;
  if (t >= n * 64) return;
  int i = t >> 6, j = t & 63;
  const float* a = af + (size_t)i * 6;
  float s = b1[j];
#pragma unroll
  for (int k = 0; k < 6; ++k) s = fmaf(a[k], W1[k * 64 + j], s);
  out[t] = fmaxf(s, 0.f);
}

__global__ __launch_bounds__(256) void build_sim(
    const int* __restrict__ ei, int* __restrict__ ss, int* __restrict__ sd)
{
  int t = blockIdx.x * blockDim.x + threadIdx.x;
  if (t >= E_SIM + NQ) return;
  if (t < E_SIM) { ss[t] = ei[t]; sd[t] = ei[E_SIM + t]; }
  else           { ss[t] = t - E_SIM; sd[t] = t - E_SIM; }
}

__global__ __launch_bounds__(256) void head_final(
    const float* __restrict__ qpre, const float* __restrict__ rpre,
    const float* __restrict__ qg, const float* __restrict__ qb,
    const float* __restrict__ rg, const float* __restrict__ rb,
    const float* __restrict__ score_bias, float* __restrict__ out, int E)
{
  int e = blockIdx.x * 4 + (threadIdx.x >> 6);
  if (e >= E) return;
  int lane = threadIdx.x & 63;

  float4 q = *(const float4*)(qpre + (size_t)e * 256 + lane * 4);
  float s = q.x + q.y + q.z + q.w;
#pragma unroll
  for (int m = 32; m >= 1; m >>= 1) s += __shfl_xor(s, m);
  float mu = s * (1.f / 256.f);
  float dq0 = q.x - mu, dq1 = q.y - mu, dq2 = q.z - mu, dq3 = q.w - mu;
  float v = dq0 * dq0 + dq1 * dq1 + dq2 * dq2 + dq3 * dq3;
#pragma unroll
  for (int m = 32; m >= 1; m >>= 1) v += __shfl_xor(v, m);
  float rstd = rsqrtf(v * (1.f / 256.f) + 1e-5f);
  float4 g4 = *(const float4*)(qg + lane * 4);
  float4 b4 = *(const float4*)(qb + lane * 4);
  float qn0 = dq0 * rstd * g4.x + b4.x, qn1 = dq1 * rstd * g4.y + b4.y;
  float qn2 = dq2 * rstd * g4.z + b4.z, qn3 = dq3 * rstd * g4.w + b4.w;

  float4 r = *(const float4*)(rpre + (size_t)e * 256 + lane * 4);
  s = r.x + r.y + r.z + r.w;
#pragma unroll
  for (int m = 32; m >= 1; m >>= 1) s += __shfl_xor(s, m);
  mu = s * (1.f / 256.f);
  float dr0 = r.x - mu, dr1 = r.y - mu, dr2 = r.z - mu, dr3 = r.w - mu;
  v = dr0 * dr0 + dr1 * dr1 + dr2 * dr2 + dr3 * dr3;
#pragma unroll
  for (int m = 32; m >= 1; m >>= 1) v += __shfl_xor(v, m);
  rstd = rsqrtf(v * (1.f / 256.f) + 1e-5f);
  g4 = *(const float4*)(rg + lane * 4);
  b4 = *(const float4*)(rb + lane * 4);
  float rn0 = dr0 * rstd * g4.x + b4.x, rn1 = dr1 * rstd * g4.y + b4.y;
  float rn2 = dr2 * rstd * g4.z + b4.z, rn3 = dr3 * rstd * g4.w + b4.w;

  float d = qn0 * rn0 + qn1 * rn1 + qn2 * rn2 + qn3 * rn3;
#pragma unroll
  for (int m = 32; m >= 1; m >>= 1) d += __shfl_xor(d, m);
  if (lane == 0) out[e] = d * 0.0625f + score_bias[0];
}

// ---------------------------------------------------------------------------
extern "C" void kernel_launch(void* const* d_in, const int* in_sizes, int n_in,
                              void* d_out, int out_size, void* d_ws, size_t ws_size,
                              hipStream_t stream) {
  (void)in_sizes; (void)n_in; (void)out_size;
  const float* xq      = (const float*)d_in[0];
  const float* xt      = (const float*)d_in[1];
  const float* xa      = (const float*)d_in[2];
  const float* af      = (const float*)d_in[3];
  const float* qp_W    = (const float*)d_in[4];
  const float* qp_b    = (const float*)d_in[5];
  const float* tp_W    = (const float*)d_in[6];
  const float* tp_b    = (const float*)d_in[7];
  const float* ap_W    = (const float*)d_in[8];
  const float* ap_b    = (const float*)d_in[9];
  const float* afp_W1  = (const float*)d_in[10];
  const float* afp_b1  = (const float*)d_in[11];
  const float* afp_W2  = (const float*)d_in[12];
  const float* afp_b2  = (const float*)d_in[13];
  const float* conv_Wl = (const float*)d_in[14];
  const float* conv_bl = (const float*)d_in[15];
  const float* conv_Wr = (const float*)d_in[16];
  const float* conv_br = (const float*)d_in[17];
  const float* conv_att  = (const float*)d_in[18];
  const float* conv_bias = (const float*)d_in[19];
  const float* qh_W    = (const float*)d_in[20];
  const float* qh_b    = (const float*)d_in[21];
  const float* qh_g    = (const float*)d_in[22];
  const float* qh_beta = (const float*)d_in[23];
  const float* rh_W    = (const float*)d_in[24];
  const float* rh_b    = (const float*)d_in[25];
  const float* rh_g    = (const float*)d_in[26];
  const float* rh_beta = (const float*)d_in[27];
  const float* score_b = (const float*)d_in[28];
  const int* ei_gr   = (const int*)d_in[29];
  const int* ei_lt   = (const int*)d_in[30];
  const int* ei_sim  = (const int*)d_in[31];
  const int* ei_comp = (const int*)d_in[32];
  const int* ei_gen  = (const int*)d_in[33];

  char* base = (char*)d_ws;
  size_t off = 0;
  auto alloc = [&](size_t bytes) {
    void* p = base + off;
    off = (off + bytes + 255) & ~(size_t)255;
    return p;
  };
  bf16_t* hq   = (bf16_t*)alloc((size_t)NQ * 512 * 2);
  bf16_t* ht   = (bf16_t*)alloc((size_t)NT * 512 * 2);
  bf16_t* ha   = (bf16_t*)alloc((size_t)NA * 512 * 2);
  bf16_t* acct = (bf16_t*)alloc((size_t)NT * 512 * 2);   // also qpre f32
  float*  accq = (float*) alloc((size_t)NQ * 512 * 4);   // also afh f32
  bf16_t* xlb  = (bf16_t*)alloc((size_t)50000 * 512 * 2);
  bf16_t* xrb  = (bf16_t*)alloc((size_t)50000 * 512 * 2);// also rpre f32
  int* simsrc  = (int*)alloc((size_t)(E_SIM + NQ) * 4);
  int* simdst  = (int*)alloc((size_t)(E_SIM + NQ) * 4);

  // CSR topology (constant across layers): build once, reuse.
  // Order: 0=gr 1=rgr 2=rlt 3=sim 4=comp 5=lt  (lt LAST so ha can be reused)
  struct Topo { const int* src; const int* dst; int Nd, E; };
  Topo topo[6] = {
    {ei_gr,        ei_gr + E_GR,     NT, E_GR},
    {ei_gr + E_GR, ei_gr,            NQ, E_GR},
    {ei_lt + E_LT, ei_lt,            NT, E_LT},
    {simsrc,       simdst,           NQ, E_SIM + NQ},
    {ei_comp,      ei_comp + E_COMP, NT, E_COMP},
    {ei_lt,        ei_lt + E_LT,     NA, E_LT},
  };
  int *deg[6], *startp[6], *eidx[6];
  for (int r = 0; r < 6; ++r) {
    deg[r]    = (int*)alloc((size_t)topo[r].Nd * 4);
    startp[r] = (int*)alloc((size_t)topo[r].Nd * 4);
    eidx[r]   = (int*)alloc((size_t)topo[r].E * 4);
  }
  int* posb = (int*)alloc((size_t)MAXE * 4);   // r3 fixed: must hold max-E relation
  int* bsum = (int*)alloc(64 * 4);
  if (off > ws_size) {
    fprintf(stderr, "kernel_launch: ws too small, need %zu have %zu\n", off, ws_size);
    return;
  }

  build_sim<<<(E_SIM + NQ + 255) / 256, 256, 0, stream>>>(ei_sim, simsrc, simdst);
  for (int r = 0; r < 6; ++r) {
    const Topo& T = topo[r];
    hipMemsetAsync(deg[r], 0, (size_t)T.Nd * 4, stream);
    csr_hist<<<(T.E + 255) / 256, 256, 0, stream>>>(T.dst, deg[r], posb, T.E);
    int nb = (T.Nd + 1023) / 1024;
    scan1<<<nb, 256, 0, stream>>>(deg[r], startp[r], bsum, T.Nd);
    scan2<<<1, 64, 0, stream>>>(bsum, nb);
    scan3<<<(T.Nd + 255) / 256, 256, 0, stream>>>(startp[r], bsum, T.Nd);
    csr_scatter<<<(T.E + 255) / 256, 256, 0, stream>>>(T.dst, startp[r], posb,
                                                       eidx[r], T.E);
  }

  // Input projections (fp32 A -> bf16 C)
  {
    dim3 g(512 / 128, (NQ + 127) / 128);
    sgemm128<float, bf16_t><<<g, 256, 0, stream>>>(xq, qp_W, qp_b, hq, NQ, 384, 512, 0);
  }
  {
    dim3 g(512 / 128, (NT + 127) / 128);
    sgemm128<float, bf16_t><<<g, 256, 0, stream>>>(xt, tp_W, tp_b, ht, NT, 384, 512, 0);
  }
  {
    dim3 g(512 / 128, (NA + 127) / 128);
    sgemm128<float, bf16_t><<<g, 256, 0, stream>>>(xa, ap_W, ap_b, ha, NA, 384, 512, 0);
  }

  // Relations in processing order; po = parameter index of each relation.
  struct Rel { const bf16_t* xs; const bf16_t* xd; int Ns, po, accKind, accum; };
  for (int l = 0; l < 2; ++l) {
    Rel rels[6] = {
      {hq, ht, NQ, 0, 1, 0},  // gr    -> acct  (first)
      {ht, hq, NT, 1, 0, 0},  // rgr   -> accq  (first)
      {ha, ht, NA, 3, 1, 1},  // rlt   -> acct
      {hq, hq, NQ, 4, 0, 1},  // sim   -> accq
      {ht, ht, NT, 5, 1, 1},  // comp  -> acct
      {ht, ha, NT, 2, 2, 0},  // lt    -> ha (direct write; old ha dead by now)
    };
    for (int r = 0; r < 6; ++r) {
      const Rel& R = rels[r];
      const Topo& T = topo[r];
      size_t po = (size_t)l * 6 + R.po;
      {
        dim3 g(512 / 128, (R.Ns + 127) / 128);
        sgemm128<bf16_t, bf16_t><<<g, 256, 0, stream>>>(
            R.xs, conv_Wl + po * 512 * 512, conv_bl + po * 512, xlb, R.Ns, 512, 512, 0);
      }
      {
        dim3 g(512 / 128, (T.Nd + 127) / 128);
        sgemm128<bf16_t, bf16_t><<<g, 256, 0, stream>>>(
            R.xd, conv_Wr + po * 512 * 512, conv_br + po * 512, xrb, T.Nd, 512, 512, 0);
      }
      int gb = (T.Nd + 3) / 4;
      if (R.accKind == 0)
        gat_fused<float><<<gb, 256, 0, stream>>>(
            xlb, xrb, T.src, startp[r], deg[r], eidx[r],
            conv_att + po * 512, accq, T.Nd, R.accum);
      else if (R.accKind == 1)
        gat_fused<bf16_t><<<gb, 256, 0, stream>>>(
            xlb, xrb, T.src, startp[r], deg[r], eidx[r],
            conv_att + po * 512, acct, T.Nd, R.accum);
      else
        gat_fused<bf16_t><<<gb, 256, 0, stream>>>(
            xlb, xrb, T.src, startp[r], deg[r], eidx[r],
            conv_att + po * 512, ha, T.Nd, R.accum);
    }
    size_t b = (size_t)l * 6;
    finalize_relu<float><<<(NQ * 64 + 255) / 256, 256, 0, stream>>>(
        accq, conv_bias + (b + 1) * 512, conv_bias + (b + 4) * 512, nullptr,
        0.5f, hq, (long)NQ * 64);
    finalize_relu<bf16_t><<<(NT * 64 + 255) / 256, 256, 0, stream>>>(
        acct, conv_bias + (b + 0) * 512, conv_bias + (b + 3) * 512,
        conv_bias + (b + 5) * 512, 1.f / 3.f, ht, (long)NT * 64);
    finalize_relu<bf16_t><<<(NA * 64 + 255) / 256, 256, 0, stream>>>(
        ha, conv_bias + (b + 2) * 512, nullptr, nullptr, 1.f, ha, (long)NA * 64);
  }

  // Head. qpre(f32)->acct region, rpre(f32)->xrb region, gathers/af_emb->xlb,
  // afh(f32)->accq.
  float* qpre = (float*)acct;
  float* rpre = (float*)xrb;
  float* afh  = accq;
  const int* gsrc = ei_gen;
  const int* gdst = ei_gen + E_GEN;
  dim3 gg((E_GEN * 64 + 255) / 256);
  dim3 gh(256 / 128, (E_GEN + 127) / 128);

  gather512<<<gg, 256, 0, stream>>>(hq, gsrc, xlb, E_GEN);                 // q_emb
  sgemm128<bf16_t, float><<<gh, 256, 0, stream>>>(xlb, qh_W, qh_b, qpre,
                                                  E_GEN, 512, 256, 0);
  gather512<<<gg, 256, 0, stream>>>(ht, gdst, xlb, E_GEN);                 // t_emb
  sgemm128<bf16_t, float><<<gh, 256, 0, stream>>>(xlb, rh_W, rh_b, rpre,
                                                  E_GEN, 512, 256, 0);
  gather512<<<gg, 256, 0, stream>>>(ha, gdst, xlb, E_GEN);                 // a_emb
  sgemm128<bf16_t, float><<<gh, 256, 0, stream>>>(xlb, rh_W + 512 * 256, nullptr,
                                                  rpre, E_GEN, 512, 256, 1);
  af_hidden<<<(E_GEN * 64 + 255) / 256, 256, 0, stream>>>(af, afp_W1, afp_b1,
                                                          afh, E_GEN);
  {
    dim3 g(512 / 128, (E_GEN + 127) / 128);
    sgemm128<float, bf16_t><<<g, 256, 0, stream>>>(afh, afp_W2, afp_b2, xlb,
                                                   E_GEN, 64, 512, 0);     // af_emb
  }
  sgemm128<bf16_t, float><<<gh, 256, 0, stream>>>(xlb, rh_W + 1024 * 256, nullptr,
                                                  rpre, E_GEN, 512, 256, 1);
  head_final<<<(E_GEN + 3) / 4, 256, 0, stream>>>(
      qpre, rpre, qh_g, qh_beta, rh_g, rh_beta, score_b, (float*)d_out, E_GEN);
}

// Round 5
// 2922.106 us; speedup vs baseline: 4.7383x; 2.9525x over previous
//
#include <hip/hip_runtime.h>
#include <cstdio>
#include <type_traits>

#define NQ 10000
#define NT 50000
#define NA 50000
#define E_GR 50000
#define E_LT 50000
#define E_SIM 80000
#define E_COMP 100000
#define E_GEN 50000
#define MAXE 100000
#define NEG_SLOPE 0.2f

typedef unsigned short bf16_t;
typedef unsigned int u32;
typedef __attribute__((ext_vector_type(8))) short short8v;
typedef __attribute__((ext_vector_type(4))) float f32x4;

__device__ __forceinline__ float bf2f(u32 bits) { return __uint_as_float(bits << 16); }
__device__ __forceinline__ u32 f2bf(float f) {
  u32 u = __float_as_uint(f);
  return (u + 0x7FFFu + ((u >> 16) & 1u)) >> 16;   // RTNE
}
__device__ __forceinline__ u32 pack2(float a, float b) { return f2bf(a) | (f2bf(b) << 16); }
__device__ __forceinline__ void unpack8(uint4 u, float* f) {
  f[0] = bf2f(u.x & 0xffffu); f[1] = bf2f(u.x >> 16);
  f[2] = bf2f(u.y & 0xffffu); f[3] = bf2f(u.y >> 16);
  f[4] = bf2f(u.z & 0xffffu); f[5] = bf2f(u.z >> 16);
  f[6] = bf2f(u.w & 0xffffu); f[7] = bf2f(u.w >> 16);
}

// ---------------------------------------------------------------------------
// MFMA bf16 GEMM. C[N,M] = A[N,K] @ Bt[M,K]^T (+bias | +=C).
// 128x128 tile, BK=32, 4 waves (2x2), each 64x64 via 4x4 mfma_16x16x32_bf16.
// LDS rows padded to 40 shorts (80 B = 20 banks): 16-row b128 frag reads tile
// all 32 banks at exactly 2-way aliasing (free, m136). Reg-staged dbuf.
// Requires M%128==0, K%32==0; N guarded.
// ---------------------------------------------------------------------------
template <typename CT>
__global__ __launch_bounds__(256) void bgemm(
    const bf16_t* __restrict__ A, const bf16_t* __restrict__ Bt,
    const float* __restrict__ bias, CT* __restrict__ C,
    int N, int K, int M, int accumulate)
{
  __shared__ short As[128 * 40];
  __shared__ short Bs[128 * 40];
  const int tid = threadIdx.x;
  const int bm = blockIdx.y * 128;
  const int bn = blockIdx.x * 128;
  const int lane = tid & 63;
  const int w = tid >> 6;
  const int wm = (w >> 1) * 64, wn = (w & 1) * 64;
  const int fr = lane & 15, fg = lane >> 4;

  // staging: 512 16B-chunks (128 rows x 4 k-chunks), 2 per thread
  const int r0 = tid >> 2, kc = tid & 3;
  const int r1 = r0 + 64;
  const int gr0 = bm + r0, gr1 = bm + r1;

  f32x4 acc[4][4];
#pragma unroll
  for (int i = 0; i < 4; ++i)
#pragma unroll
    for (int j = 0; j < 4; ++j) acc[i][j] = (f32x4){0.f, 0.f, 0.f, 0.f};

  uint4 ra0, ra1, rb0, rb1;
  const uint4 z4 = make_uint4(0, 0, 0, 0);
  auto gload = [&](int k0) {
    ra0 = (gr0 < N) ? *(const uint4*)(A + (size_t)gr0 * K + k0 + kc * 8) : z4;
    ra1 = (gr1 < N) ? *(const uint4*)(A + (size_t)gr1 * K + k0 + kc * 8) : z4;
    rb0 = *(const uint4*)(Bt + (size_t)(bn + r0) * K + k0 + kc * 8);
    rb1 = *(const uint4*)(Bt + (size_t)(bn + r1) * K + k0 + kc * 8);
  };

  gload(0);
  const int nsteps = K >> 5;
  for (int s = 0; s < nsteps; ++s) {
    __syncthreads();                       // prev compute done reading LDS
    *(uint4*)(As + r0 * 40 + kc * 8) = ra0;
    *(uint4*)(As + r1 * 40 + kc * 8) = ra1;
    *(uint4*)(Bs + r0 * 40 + kc * 8) = rb0;
    *(uint4*)(Bs + r1 * 40 + kc * 8) = rb1;
    __syncthreads();
    if (s + 1 < nsteps) gload((s + 1) << 5);   // in flight under MFMA
    short8v a[4], b[4];
#pragma unroll
    for (int f = 0; f < 4; ++f) {
      a[f] = *(const short8v*)(As + (wm + f * 16 + fr) * 40 + fg * 8);
      b[f] = *(const short8v*)(Bs + (wn + f * 16 + fr) * 40 + fg * 8);
    }
#pragma unroll
    for (int i = 0; i < 4; ++i)
#pragma unroll
      for (int j = 0; j < 4; ++j)
        acc[i][j] = __builtin_amdgcn_mfma_f32_16x16x32_bf16(a[i], b[j],
                                                            acc[i][j], 0, 0, 0);
  }

  // epilogue: C/D layout col=lane&15, row=(lane>>4)*4+reg (m89)
#pragma unroll
  for (int j = 0; j < 4; ++j) {
    int col = bn + wn + j * 16 + fr;
    float bv = (!accumulate && bias) ? bias[col] : 0.f;
#pragma unroll
    for (int i = 0; i < 4; ++i) {
      int rowb = bm + wm + i * 16 + fg * 4;
#pragma unroll
      for (int q = 0; q < 4; ++q) {
        int r = rowb + q;
        if (r >= N) continue;
        float v = acc[i][j][q] + bv;
        if constexpr (std::is_same<CT, float>::value) {
          if (accumulate) C[(size_t)r * M + col] += v;
          else            C[(size_t)r * M + col] = v;
        } else {
          C[(size_t)r * M + col] = (bf16_t)f2bf(v);
        }
      }
    }
  }
}

// fp32 W[K][M] -> bf16 Wt[M][K] (transpose), 32x32 LDS tiles, z-batched.
__global__ __launch_bounds__(256) void convert_wT(
    const float* __restrict__ W, bf16_t* __restrict__ Wt, int K, int M)
{
  __shared__ float sm[32][33];
  W  += (size_t)blockIdx.z * K * M;
  Wt += (size_t)blockIdx.z * K * M;
  int mb = blockIdx.x * 32, kb = blockIdx.y * 32;
  int tx = threadIdx.x & 31, ty = threadIdx.x >> 5;
#pragma unroll
  for (int i = 0; i < 4; ++i)
    sm[ty + i * 8][tx] = W[(size_t)(kb + ty + i * 8) * M + mb + tx];
  __syncthreads();
#pragma unroll
  for (int i = 0; i < 4; ++i)
    Wt[(size_t)(mb + ty + i * 8) * K + kb + tx] = (bf16_t)f2bf(sm[tx][ty + i * 8]);
}

// fp32 -> bf16 flat cast, 4 elems/thread
__global__ __launch_bounds__(256) void f2bf_vec(
    const float* __restrict__ in, bf16_t* __restrict__ out, long n4)
{
  long t = (long)blockIdx.x * 256 + threadIdx.x;
  if (t >= n4) return;
  float4 v = ((const float4*)in)[t];
  uint2 o;
  o.x = pack2(v.x, v.y);
  o.y = pack2(v.z, v.w);
  ((uint2*)out)[t] = o;
}

// ---------------------------------------------------------------------------
// CSR build: histogram w/ slot assignment, 3-kernel exclusive scan, scatter.
// ---------------------------------------------------------------------------
__global__ __launch_bounds__(256) void csr_hist(
    const int* __restrict__ dst, int* __restrict__ deg, int* __restrict__ pos, int E)
{
  int e = blockIdx.x * 256 + threadIdx.x;
  if (e >= E) return;
  pos[e] = atomicAdd(&deg[dst[e]], 1);
}

__global__ __launch_bounds__(256) void scan1(
    const int* __restrict__ in, int* __restrict__ out, int* __restrict__ bsum, int n)
{
  __shared__ int sm[256];
  int t = threadIdx.x;
  int base = blockIdx.x * 1024 + t * 4;
  int v[4], sum = 0;
#pragma unroll
  for (int k = 0; k < 4; ++k) { v[k] = (base + k < n) ? in[base + k] : 0; sum += v[k]; }
  sm[t] = sum;
  __syncthreads();
  for (int off = 1; off < 256; off <<= 1) {
    int x = (t >= off) ? sm[t - off] : 0;
    __syncthreads();
    sm[t] += x;
    __syncthreads();
  }
  int run = (t > 0) ? sm[t - 1] : 0;
  if (t == 255) bsum[blockIdx.x] = sm[255];
#pragma unroll
  for (int k = 0; k < 4; ++k) {
    if (base + k < n) out[base + k] = run;
    run += v[k];
  }
}

__global__ __launch_bounds__(64) void scan2(int* __restrict__ bsum, int nb)
{
  __shared__ int sm[64];
  int t = threadIdx.x;
  int v = (t < nb) ? bsum[t] : 0;
  sm[t] = v;
  __syncthreads();
  for (int off = 1; off < 64; off <<= 1) {
    int x = (t >= off) ? sm[t - off] : 0;
    __syncthreads();
    sm[t] += x;
    __syncthreads();
  }
  if (t < nb) bsum[t] = sm[t] - v;   // exclusive
}

__global__ __launch_bounds__(256) void scan3(
    int* __restrict__ out, const int* __restrict__ bsum, int n)
{
  int g = blockIdx.x * 256 + threadIdx.x;
  if (g < n) out[g] += bsum[g >> 10];
}

__global__ __launch_bounds__(256) void csr_scatter(
    const int* __restrict__ dst, const int* __restrict__ start,
    const int* __restrict__ pos, int* __restrict__ eidx, int E)
{
  int e = blockIdx.x * 256 + threadIdx.x;
  if (e >= E) return;
  eidx[start[dst[e]] + pos[e]] = e;
}

// ---------------------------------------------------------------------------
// Fused GATv2 message+softmax+aggregate, one wave per dst node, no atomics.
// ---------------------------------------------------------------------------
__global__ __launch_bounds__(256) void gat_fused(
    const bf16_t* __restrict__ xl, const bf16_t* __restrict__ xr,
    const int* __restrict__ srcArr, const int* __restrict__ start,
    const int* __restrict__ deg, const int* __restrict__ eidx,
    const float* __restrict__ att, bf16_t* __restrict__ acc,
    int Nd, int accumulate)
{
  int d = blockIdx.x * 4 + (threadIdx.x >> 6);
  if (d >= Nd) return;
  int lane = threadIdx.x & 63;

  float xrr[8];
  unpack8(*(const uint4*)(xr + (size_t)d * 512 + lane * 8), xrr);
  float at[8];
  *(float4*)(at)     = *(const float4*)(att + lane * 8);
  *(float4*)(at + 4) = *(const float4*)(att + lane * 8 + 4);

  float acc8[8] = {0.f, 0.f, 0.f, 0.f, 0.f, 0.f, 0.f, 0.f};
  float den = 0.f;
  int n = deg[d], s0 = start[d];
  for (int i = 0; i < n; ++i) {
    int e = eidx[s0 + i];
    int s = srcArr[e];
    float f[8];
    unpack8(*(const uint4*)(xl + (size_t)s * 512 + lane * 8), f);
    float p = 0.f;
#pragma unroll
    for (int k = 0; k < 8; ++k) {
      float x = f[k] + xrr[k];
      p = fmaf(at[k], x >= 0.f ? x : NEG_SLOPE * x, p);
    }
#pragma unroll
    for (int m = 8; m >= 1; m >>= 1) p += __shfl_xor(p, m);  // 16-lane group = head
    float ex = __expf(p);
    den += ex;
#pragma unroll
    for (int k = 0; k < 8; ++k) acc8[k] = fmaf(ex, f[k], acc8[k]);
  }
  float inv = 1.f / (den + 1e-16f);
#pragma unroll
  for (int k = 0; k < 8; ++k) acc8[k] *= inv;

  bf16_t* out = acc + (size_t)d * 512 + lane * 8;
  if (accumulate) {
    float old[8];
    unpack8(*(const uint4*)out, old);
#pragma unroll
    for (int k = 0; k < 8; ++k) acc8[k] += old[k];
  }
  uint4 s;
  s.x = pack2(acc8[0], acc8[1]); s.y = pack2(acc8[2], acc8[3]);
  s.z = pack2(acc8[4], acc8[5]); s.w = pack2(acc8[6], acc8[7]);
  *(uint4*)out = s;
}

// h_new = relu((acc + b0 [+ b1 + b2]) * inv_div) -> bf16, 8 elems/thread.
__global__ __launch_bounds__(256) void finalize_relu(
    const bf16_t* __restrict__ acc, const float* __restrict__ b0,
    const float* __restrict__ b1, const float* __restrict__ b2,
    float inv_div, bf16_t* __restrict__ out, long n8)
{
  long g = (long)blockIdx.x * 256 + threadIdx.x;
  if (g >= n8) return;
  long base = g * 8;
  int j = (int)(base & 511);
  float v[8];
  unpack8(*(const uint4*)(acc + base), v);
#pragma unroll
  for (int k = 0; k < 8; ++k) {
    float b = b0[j + k];
    if (b1) b += b1[j + k];
    if (b2) b += b2[j + k];
    v[k] = fmaxf((v[k] + b) * inv_div, 0.f);
  }
  uint4 s;
  s.x = pack2(v[0], v[1]); s.y = pack2(v[2], v[3]);
  s.z = pack2(v[4], v[5]); s.w = pack2(v[6], v[7]);
  *(uint4*)(out + base) = s;
}

__global__ __launch_bounds__(256) void gather512(
    const bf16_t* __restrict__ src, const int* __restrict__ idx,
    bf16_t* __restrict__ out, int E)
{
  int g = blockIdx.x * blockDim.x + threadIdx.x;
  if (g >= E * 64) return;
  int e = g >> 6, c = g & 63;
  ((uint4*)out)[g] = ((const uint4*)src)[(size_t)idx[e] * 64 + c];
}

// afh = relu(answer_features @ W1 + b1) -> bf16, K=6, M=64
__global__ __launch_bounds__(256) void af_hidden(
    const float* __restrict__ af, const float* __restrict__ W1,
    const float* __restrict__ b1, bf16_t* __restrict__ out, int n)
{
  int t = blockIdx.x * blockDim.x + threadIdx.x;
  if (t >= n * 64) return;
  int i = t >> 6, j = t & 63;
  const float* a = af + (size_t)i * 6;
  float s = b1[j];
#pragma unroll
  for (int k = 0; k < 6; ++k) s = fmaf(a[k], W1[k * 64 + j], s);
  out[t] = (bf16_t)f2bf(fmaxf(s, 0.f));
}

__global__ __launch_bounds__(256) void build_sim(
    const int* __restrict__ ei, int* __restrict__ ss, int* __restrict__ sd)
{
  int t = blockIdx.x * blockDim.x + threadIdx.x;
  if (t >= E_SIM + NQ) return;
  if (t < E_SIM) { ss[t] = ei[t]; sd[t] = ei[E_SIM + t]; }
  else           { ss[t] = t - E_SIM; sd[t] = t - E_SIM; }
}

__global__ __launch_bounds__(256) void head_final(
    const float* __restrict__ qpre, const float* __restrict__ rpre,
    const float* __restrict__ qg, const float* __restrict__ qb,
    const float* __restrict__ rg, const float* __restrict__ rb,
    const float* __restrict__ score_bias, float* __restrict__ out, int E)
{
  int e = blockIdx.x * 4 + (threadIdx.x >> 6);
  if (e >= E) return;
  int lane = threadIdx.x & 63;

  float4 q = *(const float4*)(qpre + (size_t)e * 256 + lane * 4);
  float s = q.x + q.y + q.z + q.w;
#pragma unroll
  for (int m = 32; m >= 1; m >>= 1) s += __shfl_xor(s, m);
  float mu = s * (1.f / 256.f);
  float dq0 = q.x - mu, dq1 = q.y - mu, dq2 = q.z - mu, dq3 = q.w - mu;
  float v = dq0 * dq0 + dq1 * dq1 + dq2 * dq2 + dq3 * dq3;
#pragma unroll
  for (int m = 32; m >= 1; m >>= 1) v += __shfl_xor(v, m);
  float rstd = rsqrtf(v * (1.f / 256.f) + 1e-5f);
  float4 g4 = *(const float4*)(qg + lane * 4);
  float4 b4 = *(const float4*)(qb + lane * 4);
  float qn0 = dq0 * rstd * g4.x + b4.x, qn1 = dq1 * rstd * g4.y + b4.y;
  float qn2 = dq2 * rstd * g4.z + b4.z, qn3 = dq3 * rstd * g4.w + b4.w;

  float4 r = *(const float4*)(rpre + (size_t)e * 256 + lane * 4);
  s = r.x + r.y + r.z + r.w;
#pragma unroll
  for (int m = 32; m >= 1; m >>= 1) s += __shfl_xor(s, m);
  mu = s * (1.f / 256.f);
  float dr0 = r.x - mu, dr1 = r.y - mu, dr2 = r.z - mu, dr3 = r.w - mu;
  v = dr0 * dr0 + dr1 * dr1 + dr2 * dr2 + dr3 * dr3;
#pragma unroll
  for (int m = 32; m >= 1; m >>= 1) v += __shfl_xor(v, m);
  rstd = rsqrtf(v * (1.f / 256.f) + 1e-5f);
  g4 = *(const float4*)(rg + lane * 4);
  b4 = *(const float4*)(rb + lane * 4);
  float rn0 = dr0 * rstd * g4.x + b4.x, rn1 = dr1 * rstd * g4.y + b4.y;
  float rn2 = dr2 * rstd * g4.z + b4.z, rn3 = dr3 * rstd * g4.w + b4.w;

  float d = qn0 * rn0 + qn1 * rn1 + qn2 * rn2 + qn3 * rn3;
#pragma unroll
  for (int m = 32; m >= 1; m >>= 1) d += __shfl_xor(d, m);
  if (lane == 0) out[e] = d * 0.0625f + score_bias[0];
}

// ---------------------------------------------------------------------------
extern "C" void kernel_launch(void* const* d_in, const int* in_sizes, int n_in,
                              void* d_out, int out_size, void* d_ws, size_t ws_size,
                              hipStream_t stream) {
  (void)in_sizes; (void)n_in; (void)out_size;
  const float* xq      = (const float*)d_in[0];
  const float* xt      = (const float*)d_in[1];
  const float* xa      = (const float*)d_in[2];
  const float* af      = (const float*)d_in[3];
  const float* qp_W    = (const float*)d_in[4];
  const float* qp_b    = (const float*)d_in[5];
  const float* tp_W    = (const float*)d_in[6];
  const float* tp_b    = (const float*)d_in[7];
  const float* ap_W    = (const float*)d_in[8];
  const float* ap_b    = (const float*)d_in[9];
  const float* afp_W1  = (const float*)d_in[10];
  const float* afp_b1  = (const float*)d_in[11];
  const float* afp_W2  = (const float*)d_in[12];
  const float* afp_b2  = (const float*)d_in[13];
  const float* conv_Wl = (const float*)d_in[14];
  const float* conv_bl = (const float*)d_in[15];
  const float* conv_Wr = (const float*)d_in[16];
  const float* conv_br = (const float*)d_in[17];
  const float* conv_att  = (const float*)d_in[18];
  const float* conv_bias = (const float*)d_in[19];
  const float* qh_W    = (const float*)d_in[20];
  const float* qh_b    = (const float*)d_in[21];
  const float* qh_g    = (const float*)d_in[22];
  const float* qh_beta = (const float*)d_in[23];
  const float* rh_W    = (const float*)d_in[24];
  const float* rh_b    = (const float*)d_in[25];
  const float* rh_g    = (const float*)d_in[26];
  const float* rh_beta = (const float*)d_in[27];
  const float* score_b = (const float*)d_in[28];
  const int* ei_gr   = (const int*)d_in[29];
  const int* ei_lt   = (const int*)d_in[30];
  const int* ei_sim  = (const int*)d_in[31];
  const int* ei_comp = (const int*)d_in[32];
  const int* ei_gen  = (const int*)d_in[33];

  char* base = (char*)d_ws;
  size_t off = 0;
  auto alloc = [&](size_t bytes) {
    void* p = base + off;
    off = (off + bytes + 255) & ~(size_t)255;
    return p;
  };
  bf16_t* hq   = (bf16_t*)alloc((size_t)NQ * 512 * 2);
  bf16_t* ht   = (bf16_t*)alloc((size_t)NT * 512 * 2);
  bf16_t* ha   = (bf16_t*)alloc((size_t)NA * 512 * 2);
  bf16_t* acct = (bf16_t*)alloc((size_t)NT * 512 * 2);   // also qpre f32
  bf16_t* accq = (bf16_t*)alloc((size_t)NQ * 512 * 2);   // also afh bf16
  bf16_t* xlb  = (bf16_t*)alloc((size_t)50000 * 512 * 2);// staging/gathers/af_emb
  bf16_t* xrb  = (bf16_t*)alloc((size_t)50000 * 512 * 2);// also rpre f32
  int* simsrc  = (int*)alloc((size_t)(E_SIM + NQ) * 4);
  int* simdst  = (int*)alloc((size_t)(E_SIM + NQ) * 4);

  // bf16-transposed weights
  bf16_t* wqp  = (bf16_t*)alloc((size_t)512 * 384 * 2);
  bf16_t* wtp  = (bf16_t*)alloc((size_t)512 * 384 * 2);
  bf16_t* wap  = (bf16_t*)alloc((size_t)512 * 384 * 2);
  bf16_t* wl   = (bf16_t*)alloc((size_t)12 * 512 * 512 * 2);
  bf16_t* wr   = (bf16_t*)alloc((size_t)12 * 512 * 512 * 2);
  bf16_t* wafp2 = (bf16_t*)alloc((size_t)512 * 64 * 2);
  bf16_t* wqh  = (bf16_t*)alloc((size_t)256 * 512 * 2);
  bf16_t* wrh0 = (bf16_t*)alloc((size_t)256 * 512 * 2);
  bf16_t* wrh1 = (bf16_t*)alloc((size_t)256 * 512 * 2);
  bf16_t* wrh2 = (bf16_t*)alloc((size_t)256 * 512 * 2);

  // CSR topology. Order: 0=gr 1=rgr 2=rlt 3=sim 4=comp 5=lt (lt LAST)
  struct Topo { const int* src; const int* dst; int Nd, E; };
  Topo topo[6] = {
    {ei_gr,        ei_gr + E_GR,     NT, E_GR},
    {ei_gr + E_GR, ei_gr,            NQ, E_GR},
    {ei_lt + E_LT, ei_lt,            NT, E_LT},
    {simsrc,       simdst,           NQ, E_SIM + NQ},
    {ei_comp,      ei_comp + E_COMP, NT, E_COMP},
    {ei_lt,        ei_lt + E_LT,     NA, E_LT},
  };
  int *deg[6], *startp[6], *eidx[6];
  for (int r = 0; r < 6; ++r) {
    deg[r]    = (int*)alloc((size_t)topo[r].Nd * 4);
    startp[r] = (int*)alloc((size_t)topo[r].Nd * 4);
    eidx[r]   = (int*)alloc((size_t)topo[r].E * 4);
  }
  int* posb = (int*)alloc((size_t)MAXE * 4);
  int* bsum = (int*)alloc(64 * 4);
  if (off > ws_size) {
    fprintf(stderr, "kernel_launch: ws too small, need %zu have %zu\n", off, ws_size);
    return;
  }

  // --- weight conversion (fp32 [K][M] -> bf16 [M][K]) ---
  convert_wT<<<dim3(512 / 32, 512 / 32, 12), 256, 0, stream>>>(conv_Wl, wl, 512, 512);
  convert_wT<<<dim3(512 / 32, 512 / 32, 12), 256, 0, stream>>>(conv_Wr, wr, 512, 512);
  convert_wT<<<dim3(512 / 32, 384 / 32, 1), 256, 0, stream>>>(qp_W, wqp, 384, 512);
  convert_wT<<<dim3(512 / 32, 384 / 32, 1), 256, 0, stream>>>(tp_W, wtp, 384, 512);
  convert_wT<<<dim3(512 / 32, 384 / 32, 1), 256, 0, stream>>>(ap_W, wap, 384, 512);
  convert_wT<<<dim3(512 / 32, 64 / 32, 1), 256, 0, stream>>>(afp_W2, wafp2, 64, 512);
  convert_wT<<<dim3(256 / 32, 512 / 32, 1), 256, 0, stream>>>(qh_W, wqh, 512, 256);
  convert_wT<<<dim3(256 / 32, 512 / 32, 1), 256, 0, stream>>>(rh_W, wrh0, 512, 256);
  convert_wT<<<dim3(256 / 32, 512 / 32, 1), 256, 0, stream>>>(rh_W + 512 * 256, wrh1, 512, 256);
  convert_wT<<<dim3(256 / 32, 512 / 32, 1), 256, 0, stream>>>(rh_W + 1024 * 256, wrh2, 512, 256);

  build_sim<<<(E_SIM + NQ + 255) / 256, 256, 0, stream>>>(ei_sim, simsrc, simdst);
  for (int r = 0; r < 6; ++r) {
    const Topo& T = topo[r];
    hipMemsetAsync(deg[r], 0, (size_t)T.Nd * 4, stream);
    csr_hist<<<(T.E + 255) / 256, 256, 0, stream>>>(T.dst, deg[r], posb, T.E);
    int nb = (T.Nd + 1023) / 1024;
    scan1<<<nb, 256, 0, stream>>>(deg[r], startp[r], bsum, T.Nd);
    scan2<<<1, 64, 0, stream>>>(bsum, nb);
    scan3<<<(T.Nd + 255) / 256, 256, 0, stream>>>(startp[r], bsum, T.Nd);
    csr_scatter<<<(T.E + 255) / 256, 256, 0, stream>>>(T.dst, startp[r], posb,
                                                       eidx[r], T.E);
  }

  auto gemm = [&](const bf16_t* A, const bf16_t* Bt, const float* bias, bf16_t* C,
                  int N_, int K_, int M_) {
    dim3 g(M_ / 128, (N_ + 127) / 128);
    bgemm<bf16_t><<<g, 256, 0, stream>>>(A, Bt, bias, C, N_, K_, M_, 0);
  };
  auto gemmf = [&](const bf16_t* A, const bf16_t* Bt, const float* bias, float* C,
                   int N_, int K_, int M_, int acc_) {
    dim3 g(M_ / 128, (N_ + 127) / 128);
    bgemm<float><<<g, 256, 0, stream>>>(A, Bt, bias, C, N_, K_, M_, acc_);
  };

  // Input projections: cast fp32 inputs to bf16 in xlb, then MFMA GEMM.
  f2bf_vec<<<((long)NQ * 96 + 255) / 256, 256, 0, stream>>>(xq, xlb, (long)NQ * 96);
  gemm(xlb, wqp, qp_b, hq, NQ, 384, 512);
  f2bf_vec<<<((long)NT * 96 + 255) / 256, 256, 0, stream>>>(xt, xlb, (long)NT * 96);
  gemm(xlb, wtp, tp_b, ht, NT, 384, 512);
  f2bf_vec<<<((long)NA * 96 + 255) / 256, 256, 0, stream>>>(xa, xlb, (long)NA * 96);
  gemm(xlb, wap, ap_b, ha, NA, 384, 512);

  // Relations in processing order; po = parameter index of each relation.
  struct Rel { const bf16_t* xs; const bf16_t* xd; int Ns, po; bf16_t* acc; int accum; };
  for (int l = 0; l < 2; ++l) {
    Rel rels[6] = {
      {hq, ht, NQ, 0, acct, 0},  // gr    (first into acct)
      {ht, hq, NT, 1, accq, 0},  // rgr   (first into accq)
      {ha, ht, NA, 3, acct, 1},  // rlt
      {hq, hq, NQ, 4, accq, 1},  // sim
      {ht, ht, NT, 5, acct, 1},  // comp
      {ht, ha, NT, 2, ha,   0},  // lt LAST -> ha direct (old ha dead by now)
    };
    for (int r = 0; r < 6; ++r) {
      const Rel& R = rels[r];
      const Topo& T = topo[r];
      size_t po = (size_t)l * 6 + R.po;
      gemm(R.xs, wl + po * 512 * 512, conv_bl + po * 512, xlb, R.Ns, 512, 512);
      gemm(R.xd, wr + po * 512 * 512, conv_br + po * 512, xrb, T.Nd, 512, 512);
      int gb = (T.Nd + 3) / 4;
      gat_fused<<<gb, 256, 0, stream>>>(xlb, xrb, T.src, startp[r], deg[r],
                                        eidx[r], conv_att + po * 512, R.acc,
                                        T.Nd, R.accum);
    }
    size_t b = (size_t)l * 6;
    finalize_relu<<<(NQ * 64 + 255) / 256, 256, 0, stream>>>(
        accq, conv_bias + (b + 1) * 512, conv_bias + (b + 4) * 512, nullptr,
        0.5f, hq, (long)NQ * 64);
    finalize_relu<<<(NT * 64 + 255) / 256, 256, 0, stream>>>(
        acct, conv_bias + (b + 0) * 512, conv_bias + (b + 3) * 512,
        conv_bias + (b + 5) * 512, 1.f / 3.f, ht, (long)NT * 64);
    finalize_relu<<<(NA * 64 + 255) / 256, 256, 0, stream>>>(
        ha, conv_bias + (b + 2) * 512, nullptr, nullptr, 1.f, ha, (long)NA * 64);
  }

  // Head. qpre(f32)->acct region, rpre(f32)->xrb region, gathers/af_emb->xlb,
  // afh(bf16)->accq.
  float* qpre = (float*)acct;
  float* rpre = (float*)xrb;
  bf16_t* afh = accq;
  const int* gsrc = ei_gen;
  const int* gdst = ei_gen + E_GEN;
  dim3 gg((E_GEN * 64 + 255) / 256);

  gather512<<<gg, 256, 0, stream>>>(hq, gsrc, xlb, E_GEN);                // q_emb
  gemmf(xlb, wqh, qh_b, qpre, E_GEN, 512, 256, 0);
  gather512<<<gg, 256, 0, stream>>>(ht, gdst, xlb, E_GEN);                // t_emb
  gemmf(xlb, wrh0, rh_b, rpre, E_GEN, 512, 256, 0);
  gather512<<<gg, 256, 0, stream>>>(ha, gdst, xlb, E_GEN);                // a_emb
  gemmf(xlb, wrh1, nullptr, rpre, E_GEN, 512, 256, 1);
  af_hidden<<<(E_GEN * 64 + 255) / 256, 256, 0, stream>>>(af, afp_W1, afp_b1,
                                                          afh, E_GEN);
  gemm(afh, wafp2, afp_b2, xlb, E_GEN, 64, 512);                          // af_emb
  gemmf(xlb, wrh2, nullptr, rpre, E_GEN, 512, 256, 1);
  head_final<<<(E_GEN + 3) / 4, 256, 0, stream>>>(
      qpre, rpre, qh_g, qh_beta, rh_g, rh_beta, score_b, (float*)d_out, E_GEN);
}

// Round 6
// 2023.763 us; speedup vs baseline: 6.8416x; 1.4439x over previous
//
#include <hip/hip_runtime.h>
#include <cstdio>
#include <type_traits>

#define NQ 10000
#define NT 50000
#define NA 50000
#define E_GR 50000
#define E_LT 50000
#define E_SIM 80000
#define E_COMP 100000
#define E_GEN 50000
#define MAXE 100000
#define NEG_SLOPE 0.2f

typedef unsigned short bf16_t;
typedef unsigned int u32;
typedef __attribute__((ext_vector_type(8))) short short8v;
typedef __attribute__((ext_vector_type(4))) float f32x4;

__device__ __forceinline__ float bf2f(u32 bits) { return __uint_as_float(bits << 16); }
__device__ __forceinline__ u32 f2bf(float f) {
  u32 u = __float_as_uint(f);
  return (u + 0x7FFFu + ((u >> 16) & 1u)) >> 16;   // RTNE
}
__device__ __forceinline__ u32 pack2(float a, float b) { return f2bf(a) | (f2bf(b) << 16); }
__device__ __forceinline__ void unpack8(uint4 u, float* f) {
  f[0] = bf2f(u.x & 0xffffu); f[1] = bf2f(u.x >> 16);
  f[2] = bf2f(u.y & 0xffffu); f[3] = bf2f(u.y >> 16);
  f[4] = bf2f(u.z & 0xffffu); f[5] = bf2f(u.z >> 16);
  f[6] = bf2f(u.w & 0xffffu); f[7] = bf2f(u.w >> 16);
}

// async global->LDS, 16B per lane; LDS dest = wave-uniform base + lane*16.
__device__ __forceinline__ void gload16(const void* g, void* l) {
  __builtin_amdgcn_global_load_lds(
      (const __attribute__((address_space(1))) void*)g,
      (__attribute__((address_space(3))) void*)l, 16, 0, 0);
}

// ---------------------------------------------------------------------------
// MFMA bf16 GEMM. C[N,M] = A[N,K] @ Bt[M,K]^T (+bias | +=C).
// 128x128 tile, BK=32, 4 waves (2x2), 4x4 mfma_16x16x32_bf16 each.
// global_load_lds staging into linear LDS; bank spread via pre-swizzled
// global source chunk (kc ^= (row>>1)&3) and matching read XOR (rule #21).
// One barrier per K-step (dbuf LDS; next-tile loads fly under MFMA).
// Epilogue uses swapped mfma(b,a) so each lane's reg-quad = 4 consecutive
// C columns -> packed uint2 (bf16) / float4 (f32) stores.
// Requires M%128==0, K%32==0; N guarded (A rows clamped, stores guarded).
// ---------------------------------------------------------------------------
template <typename CT>
__global__ __launch_bounds__(256) void bgemm(
    const bf16_t* __restrict__ A, const bf16_t* __restrict__ Bt,
    const float* __restrict__ bias, CT* __restrict__ C,
    int N, int K, int M, int accumulate)
{
  __shared__ short lds[2][2][4096];   // [buf][A/B][128 rows x 32 shorts]
  const int tid = threadIdx.x;
  const int bm = blockIdx.y * 128;    // N block
  const int bn = blockIdx.x * 128;    // M block
  const int lane = tid & 63;
  const int w = tid >> 6;
  const int wm = (w >> 1) * 64, wn = (w & 1) * 64;
  const int fr = lane & 15, fg = lane >> 4;

  // staging: chunk c in [0,512): row=c>>2, kc=c&3. Thread owns c=tid, tid+256.
  const int row0 = tid >> 2, kc = tid & 3;
  const int row1 = row0 + 64;
  const int kg0 = (kc ^ ((row0 >> 1) & 3)) * 8;   // pre-swizzled k-octet
  const int kg1 = (kc ^ ((row1 >> 1) & 3)) * 8;
  const int ar0 = min(bm + row0, N - 1);
  const int ar1 = min(bm + row1, N - 1);
  const bf16_t* gA0 = A + (size_t)ar0 * K + kg0;
  const bf16_t* gA1 = A + (size_t)ar1 * K + kg1;
  const bf16_t* gB0 = Bt + (size_t)(bn + row0) * K + kg0;
  const bf16_t* gB1 = Bt + (size_t)(bn + row1) * K + kg1;
  const int wbase = w << 9;           // wave-uniform LDS short offset

  f32x4 acc[4][4];
#pragma unroll
  for (int i = 0; i < 4; ++i)
#pragma unroll
    for (int j = 0; j < 4; ++j) acc[i][j] = (f32x4){0.f, 0.f, 0.f, 0.f};

  auto stage = [&](int buf, int k0) {
    gload16(gA0 + k0, &lds[buf][0][wbase]);
    gload16(gA1 + k0, &lds[buf][0][2048 + wbase]);
    gload16(gB0 + k0, &lds[buf][1][wbase]);
    gload16(gB1 + k0, &lds[buf][1][2048 + wbase]);
  };

  stage(0, 0);
  const int nsteps = K >> 5;
  const int co = (fg ^ ((fr >> 1) & 3)) * 8;   // read-side XOR chunk offset
  for (int s = 0; s < nsteps; ++s) {
    int cur = s & 1;
    __syncthreads();                  // drains vmcnt: buf[cur] ready; all waves done reading buf[cur^1]
    if (s + 1 < nsteps) stage(cur ^ 1, (s + 1) << 5);
    short8v a[4], b[4];
#pragma unroll
    for (int f = 0; f < 4; ++f) {
      a[f] = *(const short8v*)&lds[cur][0][(wm + f * 16 + fr) * 32 + co];
      b[f] = *(const short8v*)&lds[cur][1][(wn + f * 16 + fr) * 32 + co];
    }
#pragma unroll
    for (int i = 0; i < 4; ++i)
#pragma unroll
      for (int j = 0; j < 4; ++j)
        acc[i][j] = __builtin_amdgcn_mfma_f32_16x16x32_bf16(b[i], a[j],
                                                            acc[i][j], 0, 0, 0);
  }

  // epilogue: D rows = Bt rows (C cols, quad fg*4+q), D cols = A rows (fr)
#pragma unroll
  for (int i = 0; i < 4; ++i) {
    const int m0 = bn + wn + i * 16 + fg * 4;
    float4 bv = make_float4(0.f, 0.f, 0.f, 0.f);
    if (!accumulate && bias) bv = *(const float4*)(bias + m0);
#pragma unroll
    for (int j = 0; j < 4; ++j) {
      const int n = bm + wm + j * 16 + fr;
      if (n >= N) continue;
      f32x4 v = acc[i][j];
      if constexpr (std::is_same<CT, float>::value) {
        float* p = C + (size_t)n * M + m0;
        if (accumulate) {
          float4 o = *(float4*)p;
          o.x += v[0]; o.y += v[1]; o.z += v[2]; o.w += v[3];
          *(float4*)p = o;
        } else {
          *(float4*)p = make_float4(v[0] + bv.x, v[1] + bv.y,
                                    v[2] + bv.z, v[3] + bv.w);
        }
      } else {
        uint2 o;
        o.x = pack2(v[0] + bv.x, v[1] + bv.y);
        o.y = pack2(v[2] + bv.z, v[3] + bv.w);
        *(uint2*)(C + (size_t)n * M + m0) = o;
      }
    }
  }
}

// fp32 W[K][M] -> bf16 Wt[M][K] (transpose), 32x32 LDS tiles, z-batched.
__global__ __launch_bounds__(256) void convert_wT(
    const float* __restrict__ W, bf16_t* __restrict__ Wt, int K, int M)
{
  __shared__ float sm[32][33];
  W  += (size_t)blockIdx.z * K * M;
  Wt += (size_t)blockIdx.z * K * M;
  int mb = blockIdx.x * 32, kb = blockIdx.y * 32;
  int tx = threadIdx.x & 31, ty = threadIdx.x >> 5;
#pragma unroll
  for (int i = 0; i < 4; ++i)
    sm[ty + i * 8][tx] = W[(size_t)(kb + ty + i * 8) * M + mb + tx];
  __syncthreads();
#pragma unroll
  for (int i = 0; i < 4; ++i)
    Wt[(size_t)(mb + ty + i * 8) * K + kb + tx] = (bf16_t)f2bf(sm[tx][ty + i * 8]);
}

// fp32 -> bf16 flat cast, 4 elems/thread
__global__ __launch_bounds__(256) void f2bf_vec(
    const float* __restrict__ in, bf16_t* __restrict__ out, long n4)
{
  long t = (long)blockIdx.x * 256 + threadIdx.x;
  if (t >= n4) return;
  float4 v = ((const float4*)in)[t];
  uint2 o;
  o.x = pack2(v.x, v.y);
  o.y = pack2(v.z, v.w);
  ((uint2*)out)[t] = o;
}

// bc = (b0 [+b1] [+b2]) * inv  (512 floats)
__global__ __launch_bounds__(256) void combine_bias(
    const float* __restrict__ b0, const float* __restrict__ b1,
    const float* __restrict__ b2, float inv, float* __restrict__ out)
{
  int j = blockIdx.x * 256 + threadIdx.x;
  if (j >= 512) return;
  float v = b0[j];
  if (b1) v += b1[j];
  if (b2) v += b2[j];
  out[j] = v * inv;
}

// ---------------------------------------------------------------------------
// CSR build: histogram w/ slot assignment, 3-kernel exclusive scan, scatter.
// ---------------------------------------------------------------------------
__global__ __launch_bounds__(256) void csr_hist(
    const int* __restrict__ dst, int* __restrict__ deg, int* __restrict__ pos, int E)
{
  int e = blockIdx.x * 256 + threadIdx.x;
  if (e >= E) return;
  pos[e] = atomicAdd(&deg[dst[e]], 1);
}

__global__ __launch_bounds__(256) void scan1(
    const int* __restrict__ in, int* __restrict__ out, int* __restrict__ bsum, int n)
{
  __shared__ int sm[256];
  int t = threadIdx.x;
  int base = blockIdx.x * 1024 + t * 4;
  int v[4], sum = 0;
#pragma unroll
  for (int k = 0; k < 4; ++k) { v[k] = (base + k < n) ? in[base + k] : 0; sum += v[k]; }
  sm[t] = sum;
  __syncthreads();
  for (int off = 1; off < 256; off <<= 1) {
    int x = (t >= off) ? sm[t - off] : 0;
    __syncthreads();
    sm[t] += x;
    __syncthreads();
  }
  int run = (t > 0) ? sm[t - 1] : 0;
  if (t == 255) bsum[blockIdx.x] = sm[255];
#pragma unroll
  for (int k = 0; k < 4; ++k) {
    if (base + k < n) out[base + k] = run;
    run += v[k];
  }
}

__global__ __launch_bounds__(64) void scan2(int* __restrict__ bsum, int nb)
{
  __shared__ int sm[64];
  int t = threadIdx.x;
  int v = (t < nb) ? bsum[t] : 0;
  sm[t] = v;
  __syncthreads();
  for (int off = 1; off < 64; off <<= 1) {
    int x = (t >= off) ? sm[t - off] : 0;
    __syncthreads();
    sm[t] += x;
    __syncthreads();
  }
  if (t < nb) bsum[t] = sm[t] - v;   // exclusive
}

__global__ __launch_bounds__(256) void scan3(
    int* __restrict__ out, const int* __restrict__ bsum, int n)
{
  int g = blockIdx.x * 256 + threadIdx.x;
  if (g < n) out[g] += bsum[g >> 10];
}

__global__ __launch_bounds__(256) void csr_scatter(
    const int* __restrict__ dst, const int* __restrict__ start,
    const int* __restrict__ pos, int* __restrict__ eidx, int E)
{
  int e = blockIdx.x * 256 + threadIdx.x;
  if (e >= E) return;
  eidx[start[dst[e]] + pos[e]] = e;
}

// ---------------------------------------------------------------------------
// Fused GATv2 message+softmax+aggregate, one wave per dst node, no atomics.
// If bc != nullptr: also applies HeteroConv-mean + bias + relu (final
// relation for this node type) and writes the NEW h in place of acc.
// ---------------------------------------------------------------------------
__global__ __launch_bounds__(256) void gat_fused(
    const bf16_t* __restrict__ xl, const bf16_t* __restrict__ xr,
    const int* __restrict__ srcArr, const int* __restrict__ start,
    const int* __restrict__ deg, const int* __restrict__ eidx,
    const float* __restrict__ att, bf16_t* __restrict__ acc,
    int Nd, int accumulate, const float* __restrict__ bc, float inv_div)
{
  int d = blockIdx.x * 4 + (threadIdx.x >> 6);
  if (d >= Nd) return;
  int lane = threadIdx.x & 63;

  float xrr[8];
  unpack8(*(const uint4*)(xr + (size_t)d * 512 + lane * 8), xrr);
  float at[8];
  *(float4*)(at)     = *(const float4*)(att + lane * 8);
  *(float4*)(at + 4) = *(const float4*)(att + lane * 8 + 4);

  float acc8[8] = {0.f, 0.f, 0.f, 0.f, 0.f, 0.f, 0.f, 0.f};
  float den = 0.f;
  int n = deg[d], s0 = start[d];
  for (int i = 0; i < n; ++i) {
    int e = eidx[s0 + i];
    int s = srcArr[e];
    float f[8];
    unpack8(*(const uint4*)(xl + (size_t)s * 512 + lane * 8), f);
    float p = 0.f;
#pragma unroll
    for (int k = 0; k < 8; ++k) {
      float x = f[k] + xrr[k];
      p = fmaf(at[k], x >= 0.f ? x : NEG_SLOPE * x, p);
    }
#pragma unroll
    for (int m = 8; m >= 1; m >>= 1) p += __shfl_xor(p, m);  // 16-lane group = head
    float ex = __expf(p);
    den += ex;
#pragma unroll
    for (int k = 0; k < 8; ++k) acc8[k] = fmaf(ex, f[k], acc8[k]);
  }
  float inv = 1.f / (den + 1e-16f);
#pragma unroll
  for (int k = 0; k < 8; ++k) acc8[k] *= inv;

  bf16_t* out = acc + (size_t)d * 512 + lane * 8;
  if (accumulate) {
    float old[8];
    unpack8(*(const uint4*)out, old);
#pragma unroll
    for (int k = 0; k < 8; ++k) acc8[k] += old[k];
  }
  if (bc) {   // finalize: mean + combined bias + relu
    float bcv[8];
    *(float4*)(bcv)     = *(const float4*)(bc + lane * 8);
    *(float4*)(bcv + 4) = *(const float4*)(bc + lane * 8 + 4);
#pragma unroll
    for (int k = 0; k < 8; ++k)
      acc8[k] = fmaxf(fmaf(acc8[k], inv_div, bcv[k]), 0.f);
  }
  uint4 s;
  s.x = pack2(acc8[0], acc8[1]); s.y = pack2(acc8[2], acc8[3]);
  s.z = pack2(acc8[4], acc8[5]); s.w = pack2(acc8[6], acc8[7]);
  *(uint4*)out = s;
}

__global__ __launch_bounds__(256) void gather512(
    const bf16_t* __restrict__ src, const int* __restrict__ idx,
    bf16_t* __restrict__ out, int E)
{
  int g = blockIdx.x * blockDim.x + threadIdx.x;
  if (g >= E * 64) return;
  int e = g >> 6, c = g & 63;
  ((uint4*)out)[g] = ((const uint4*)src)[(size_t)idx[e] * 64 + c];
}

// afh = relu(answer_features @ W1 + b1) -> bf16, K=6, M=64
__global__ __launch_bounds__(256) void af_hidden(
    const float* __restrict__ af, const float* __restrict__ W1,
    const float* __restrict__ b1, bf16_t* __restrict__ out, int n)
{
  int t = blockIdx.x * blockDim.x + threadIdx.x;
  if (t >= n * 64) return;
  int i = t >> 6, j = t & 63;
  const float* a = af + (size_t)i * 6;
  float s = b1[j];
#pragma unroll
  for (int k = 0; k < 6; ++k) s = fmaf(a[k], W1[k * 64 + j], s);
  out[t] = (bf16_t)f2bf(fmaxf(s, 0.f));
}

__global__ __launch_bounds__(256) void build_sim(
    const int* __restrict__ ei, int* __restrict__ ss, int* __restrict__ sd)
{
  int t = blockIdx.x * blockDim.x + threadIdx.x;
  if (t >= E_SIM + NQ) return;
  if (t < E_SIM) { ss[t] = ei[t]; sd[t] = ei[E_SIM + t]; }
  else           { ss[t] = t - E_SIM; sd[t] = t - E_SIM; }
}

__global__ __launch_bounds__(256) void head_final(
    const float* __restrict__ qpre, const float* __restrict__ rpre,
    const float* __restrict__ qg, const float* __restrict__ qb,
    const float* __restrict__ rg, const float* __restrict__ rb,
    const float* __restrict__ score_bias, float* __restrict__ out, int E)
{
  int e = blockIdx.x * 4 + (threadIdx.x >> 6);
  if (e >= E) return;
  int lane = threadIdx.x & 63;

  float4 q = *(const float4*)(qpre + (size_t)e * 256 + lane * 4);
  float s = q.x + q.y + q.z + q.w;
#pragma unroll
  for (int m = 32; m >= 1; m >>= 1) s += __shfl_xor(s, m);
  float mu = s * (1.f / 256.f);
  float dq0 = q.x - mu, dq1 = q.y - mu, dq2 = q.z - mu, dq3 = q.w - mu;
  float v = dq0 * dq0 + dq1 * dq1 + dq2 * dq2 + dq3 * dq3;
#pragma unroll
  for (int m = 32; m >= 1; m >>= 1) v += __shfl_xor(v, m);
  float rstd = rsqrtf(v * (1.f / 256.f) + 1e-5f);
  float4 g4 = *(const float4*)(qg + lane * 4);
  float4 b4 = *(const float4*)(qb + lane * 4);
  float qn0 = dq0 * rstd * g4.x + b4.x, qn1 = dq1 * rstd * g4.y + b4.y;
  float qn2 = dq2 * rstd * g4.z + b4.z, qn3 = dq3 * rstd * g4.w + b4.w;

  float4 r = *(const float4*)(rpre + (size_t)e * 256 + lane * 4);
  s = r.x + r.y + r.z + r.w;
#pragma unroll
  for (int m = 32; m >= 1; m >>= 1) s += __shfl_xor(s, m);
  mu = s * (1.f / 256.f);
  float dr0 = r.x - mu, dr1 = r.y - mu, dr2 = r.z - mu, dr3 = r.w - mu;
  v = dr0 * dr0 + dr1 * dr1 + dr2 * dr2 + dr3 * dr3;
#pragma unroll
  for (int m = 32; m >= 1; m >>= 1) v += __shfl_xor(v, m);
  rstd = rsqrtf(v * (1.f / 256.f) + 1e-5f);
  g4 = *(const float4*)(rg + lane * 4);
  b4 = *(const float4*)(rb + lane * 4);
  float rn0 = dr0 * rstd * g4.x + b4.x, rn1 = dr1 * rstd * g4.y + b4.y;
  float rn2 = dr2 * rstd * g4.z + b4.z, rn3 = dr3 * rstd * g4.w + b4.w;

  float d = qn0 * rn0 + qn1 * rn1 + qn2 * rn2 + qn3 * rn3;
#pragma unroll
  for (int m = 32; m >= 1; m >>= 1) d += __shfl_xor(d, m);
  if (lane == 0) out[e] = d * 0.0625f + score_bias[0];
}

// ---------------------------------------------------------------------------
extern "C" void kernel_launch(void* const* d_in, const int* in_sizes, int n_in,
                              void* d_out, int out_size, void* d_ws, size_t ws_size,
                              hipStream_t stream) {
  (void)in_sizes; (void)n_in; (void)out_size;
  const float* xq      = (const float*)d_in[0];
  const float* xt      = (const float*)d_in[1];
  const float* xa      = (const float*)d_in[2];
  const float* af      = (const float*)d_in[3];
  const float* qp_W    = (const float*)d_in[4];
  const float* qp_b    = (const float*)d_in[5];
  const float* tp_W    = (const float*)d_in[6];
  const float* tp_b    = (const float*)d_in[7];
  const float* ap_W    = (const float*)d_in[8];
  const float* ap_b    = (const float*)d_in[9];
  const float* afp_W1  = (const float*)d_in[10];
  const float* afp_b1  = (const float*)d_in[11];
  const float* afp_W2  = (const float*)d_in[12];
  const float* afp_b2  = (const float*)d_in[13];
  const float* conv_Wl = (const float*)d_in[14];
  const float* conv_bl = (const float*)d_in[15];
  const float* conv_Wr = (const float*)d_in[16];
  const float* conv_br = (const float*)d_in[17];
  const float* conv_att  = (const float*)d_in[18];
  const float* conv_bias = (const float*)d_in[19];
  const float* qh_W    = (const float*)d_in[20];
  const float* qh_b    = (const float*)d_in[21];
  const float* qh_g    = (const float*)d_in[22];
  const float* qh_beta = (const float*)d_in[23];
  const float* rh_W    = (const float*)d_in[24];
  const float* rh_b    = (const float*)d_in[25];
  const float* rh_g    = (const float*)d_in[26];
  const float* rh_beta = (const float*)d_in[27];
  const float* score_b = (const float*)d_in[28];
  const int* ei_gr   = (const int*)d_in[29];
  const int* ei_lt   = (const int*)d_in[30];
  const int* ei_sim  = (const int*)d_in[31];
  const int* ei_comp = (const int*)d_in[32];
  const int* ei_gen  = (const int*)d_in[33];

  char* base = (char*)d_ws;
  size_t off = 0;
  auto alloc = [&](size_t bytes) {
    void* p = base + off;
    off = (off + bytes + 255) & ~(size_t)255;
    return p;
  };
  bf16_t* hq   = (bf16_t*)alloc((size_t)NQ * 512 * 2);
  bf16_t* ht   = (bf16_t*)alloc((size_t)NT * 512 * 2);
  bf16_t* ha   = (bf16_t*)alloc((size_t)NA * 512 * 2);
  bf16_t* acct = (bf16_t*)alloc((size_t)NT * 512 * 2);   // ht ping-pong; qpre f32
  bf16_t* accq = (bf16_t*)alloc((size_t)NQ * 512 * 2);   // hq ping-pong; afh bf16
  bf16_t* xlb  = (bf16_t*)alloc((size_t)50000 * 512 * 2);// staging/gathers/af_emb
  bf16_t* xrb  = (bf16_t*)alloc((size_t)50000 * 512 * 2);// also rpre f32
  int* simsrc  = (int*)alloc((size_t)(E_SIM + NQ) * 4);
  int* simdst  = (int*)alloc((size_t)(E_SIM + NQ) * 4);

  // bf16-transposed weights
  bf16_t* wqp  = (bf16_t*)alloc((size_t)512 * 384 * 2);
  bf16_t* wtp  = (bf16_t*)alloc((size_t)512 * 384 * 2);
  bf16_t* wap  = (bf16_t*)alloc((size_t)512 * 384 * 2);
  bf16_t* wl   = (bf16_t*)alloc((size_t)12 * 512 * 512 * 2);
  bf16_t* wr   = (bf16_t*)alloc((size_t)12 * 512 * 512 * 2);
  bf16_t* wafp2 = (bf16_t*)alloc((size_t)512 * 64 * 2);
  bf16_t* wqh  = (bf16_t*)alloc((size_t)256 * 512 * 2);
  bf16_t* wrh0 = (bf16_t*)alloc((size_t)256 * 512 * 2);
  bf16_t* wrh1 = (bf16_t*)alloc((size_t)256 * 512 * 2);
  bf16_t* wrh2 = (bf16_t*)alloc((size_t)256 * 512 * 2);
  float* bc_t  = (float*)alloc(512 * 4);
  float* bc_q  = (float*)alloc(512 * 4);
  float* bc_a  = (float*)alloc(512 * 4);

  // CSR topology. Order: 0=gr 1=rgr 2=rlt 3=sim 4=comp 5=lt (lt LAST)
  struct Topo { const int* src; const int* dst; int Nd, E; };
  Topo topo[6] = {
    {ei_gr,        ei_gr + E_GR,     NT, E_GR},
    {ei_gr + E_GR, ei_gr,            NQ, E_GR},
    {ei_lt + E_LT, ei_lt,            NT, E_LT},
    {simsrc,       simdst,           NQ, E_SIM + NQ},
    {ei_comp,      ei_comp + E_COMP, NT, E_COMP},
    {ei_lt,        ei_lt + E_LT,     NA, E_LT},
  };
  int *deg[6], *startp[6], *eidx[6];
  for (int r = 0; r < 6; ++r) {
    deg[r]    = (int*)alloc((size_t)topo[r].Nd * 4);
    startp[r] = (int*)alloc((size_t)topo[r].Nd * 4);
    eidx[r]   = (int*)alloc((size_t)topo[r].E * 4);
  }
  int* posb = (int*)alloc((size_t)MAXE * 4);
  int* bsum = (int*)alloc(64 * 4);
  if (off > ws_size) {
    fprintf(stderr, "kernel_launch: ws too small, need %zu have %zu\n", off, ws_size);
    return;
  }

  // --- weight conversion (fp32 [K][M] -> bf16 [M][K]) ---
  convert_wT<<<dim3(512 / 32, 512 / 32, 12), 256, 0, stream>>>(conv_Wl, wl, 512, 512);
  convert_wT<<<dim3(512 / 32, 512 / 32, 12), 256, 0, stream>>>(conv_Wr, wr, 512, 512);
  convert_wT<<<dim3(512 / 32, 384 / 32, 1), 256, 0, stream>>>(qp_W, wqp, 384, 512);
  convert_wT<<<dim3(512 / 32, 384 / 32, 1), 256, 0, stream>>>(tp_W, wtp, 384, 512);
  convert_wT<<<dim3(512 / 32, 384 / 32, 1), 256, 0, stream>>>(ap_W, wap, 384, 512);
  convert_wT<<<dim3(512 / 32, 64 / 32, 1), 256, 0, stream>>>(afp_W2, wafp2, 64, 512);
  convert_wT<<<dim3(256 / 32, 512 / 32, 1), 256, 0, stream>>>(qh_W, wqh, 512, 256);
  convert_wT<<<dim3(256 / 32, 512 / 32, 1), 256, 0, stream>>>(rh_W, wrh0, 512, 256);
  convert_wT<<<dim3(256 / 32, 512 / 32, 1), 256, 0, stream>>>(rh_W + 512 * 256, wrh1, 512, 256);
  convert_wT<<<dim3(256 / 32, 512 / 32, 1), 256, 0, stream>>>(rh_W + 1024 * 256, wrh2, 512, 256);

  build_sim<<<(E_SIM + NQ + 255) / 256, 256, 0, stream>>>(ei_sim, simsrc, simdst);
  for (int r = 0; r < 6; ++r) {
    const Topo& T = topo[r];
    hipMemsetAsync(deg[r], 0, (size_t)T.Nd * 4, stream);
    csr_hist<<<(T.E + 255) / 256, 256, 0, stream>>>(T.dst, deg[r], posb, T.E);
    int nb = (T.Nd + 1023) / 1024;
    scan1<<<nb, 256, 0, stream>>>(deg[r], startp[r], bsum, T.Nd);
    scan2<<<1, 64, 0, stream>>>(bsum, nb);
    scan3<<<(T.Nd + 255) / 256, 256, 0, stream>>>(startp[r], bsum, T.Nd);
    csr_scatter<<<(T.E + 255) / 256, 256, 0, stream>>>(T.dst, startp[r], posb,
                                                       eidx[r], T.E);
  }

  auto gemm = [&](const bf16_t* A, const bf16_t* Bt, const float* bias, bf16_t* C,
                  int N_, int K_, int M_) {
    dim3 g(M_ / 128, (N_ + 127) / 128);
    bgemm<bf16_t><<<g, 256, 0, stream>>>(A, Bt, bias, C, N_, K_, M_, 0);
  };
  auto gemmf = [&](const bf16_t* A, const bf16_t* Bt, const float* bias, float* C,
                   int N_, int K_, int M_, int acc_) {
    dim3 g(M_ / 128, (N_ + 127) / 128);
    bgemm<float><<<g, 256, 0, stream>>>(A, Bt, bias, C, N_, K_, M_, acc_);
  };

  // Input projections: cast fp32 inputs to bf16 in xlb, then MFMA GEMM.
  f2bf_vec<<<((long)NQ * 96 + 255) / 256, 256, 0, stream>>>(xq, xlb, (long)NQ * 96);
  gemm(xlb, wqp, qp_b, hq, NQ, 384, 512);
  f2bf_vec<<<((long)NT * 96 + 255) / 256, 256, 0, stream>>>(xt, xlb, (long)NT * 96);
  gemm(xlb, wtp, tp_b, ht, NT, 384, 512);
  f2bf_vec<<<((long)NA * 96 + 255) / 256, 256, 0, stream>>>(xa, xlb, (long)NA * 96);
  gemm(xlb, wap, ap_b, ha, NA, 384, 512);

  // Layer loop with ping-pong h buffers; last relation per dst type carries
  // the fused mean+bias+relu (bc != null) and produces the new h in acc.
  bf16_t *hq_i = hq, *ht_i = ht, *hq_o = accq, *ht_o = acct;
  for (int l = 0; l < 2; ++l) {
    size_t b = (size_t)l * 6;
    combine_bias<<<2, 256, 0, stream>>>(conv_bias + (b + 0) * 512,
        conv_bias + (b + 3) * 512, conv_bias + (b + 5) * 512, 1.f / 3.f, bc_t);
    combine_bias<<<2, 256, 0, stream>>>(conv_bias + (b + 1) * 512,
        conv_bias + (b + 4) * 512, nullptr, 0.5f, bc_q);
    combine_bias<<<2, 256, 0, stream>>>(conv_bias + (b + 2) * 512,
        nullptr, nullptr, 1.f, bc_a);

    struct Rel { const bf16_t* xs; const bf16_t* xd; int Ns, po; bf16_t* acc;
                 int accum; const float* bc; float inv; };
    Rel rels[6] = {
      {hq_i, ht_i, NQ, 0, ht_o, 0, nullptr, 0.f},      // gr
      {ht_i, hq_i, NT, 1, hq_o, 0, nullptr, 0.f},      // rgr
      {ha,   ht_i, NA, 3, ht_o, 1, nullptr, 0.f},      // rlt
      {hq_i, hq_i, NQ, 4, hq_o, 1, bc_q, 0.5f},        // sim (final for q)
      {ht_i, ht_i, NT, 5, ht_o, 1, bc_t, 1.f / 3.f},   // comp (final for t)
      {ht_i, ha,   NT, 2, ha,   0, bc_a, 1.f},         // lt (final for a, in-place)
    };
    for (int r = 0; r < 6; ++r) {
      const Rel& R = rels[r];
      const Topo& T = topo[r];
      size_t po = (size_t)l * 6 + R.po;
      gemm(R.xs, wl + po * 512 * 512, conv_bl + po * 512, xlb, R.Ns, 512, 512);
      gemm(R.xd, wr + po * 512 * 512, conv_br + po * 512, xrb, T.Nd, 512, 512);
      int gb = (T.Nd + 3) / 4;
      gat_fused<<<gb, 256, 0, stream>>>(xlb, xrb, T.src, startp[r], deg[r],
                                        eidx[r], conv_att + po * 512, R.acc,
                                        T.Nd, R.accum, R.bc, R.inv);
    }
    bf16_t* t;
    t = hq_i; hq_i = hq_o; hq_o = t;
    t = ht_i; ht_i = ht_o; ht_o = t;
  }
  // after 2 swaps: hq_i==hq, ht_i==ht; scratch acct/accq free again.

  // Head. qpre(f32)->acct region, rpre(f32)->xrb region, gathers/af_emb->xlb,
  // afh(bf16)->accq.
  float* qpre = (float*)acct;
  float* rpre = (float*)xrb;
  bf16_t* afh = accq;
  const int* gsrc = ei_gen;
  const int* gdst = ei_gen + E_GEN;
  dim3 gg((E_GEN * 64 + 255) / 256);

  gather512<<<gg, 256, 0, stream>>>(hq_i, gsrc, xlb, E_GEN);               // q_emb
  gemmf(xlb, wqh, qh_b, qpre, E_GEN, 512, 256, 0);
  gather512<<<gg, 256, 0, stream>>>(ht_i, gdst, xlb, E_GEN);               // t_emb
  gemmf(xlb, wrh0, rh_b, rpre, E_GEN, 512, 256, 0);
  gather512<<<gg, 256, 0, stream>>>(ha, gdst, xlb, E_GEN);                 // a_emb
  gemmf(xlb, wrh1, nullptr, rpre, E_GEN, 512, 256, 1);
  af_hidden<<<(E_GEN * 64 + 255) / 256, 256, 0, stream>>>(af, afp_W1, afp_b1,
                                                          afh, E_GEN);
  gemm(afh, wafp2, afp_b2, xlb, E_GEN, 64, 512);                           // af_emb
  gemmf(xlb, wrh2, nullptr, rpre, E_GEN, 512, 256, 1);
  head_final<<<(E_GEN + 3) / 4, 256, 0, stream>>>(
      qpre, rpre, qh_g, qh_beta, rh_g, rh_beta, score_b, (float*)d_out, E_GEN);
}

// Round 7
// 2001.845 us; speedup vs baseline: 6.9165x; 1.0109x over previous
//
#include <hip/hip_runtime.h>
#include <cstdio>
#include <type_traits>

#define NQ 10000
#define NT 50000
#define NA 50000
#define E_GR 50000
#define E_LT 50000
#define E_SIM 80000
#define E_COMP 100000
#define E_GEN 50000
#define MAXE 100000
#define NEG_SLOPE 0.2f

typedef unsigned short bf16_t;
typedef unsigned int u32;
typedef __attribute__((ext_vector_type(8))) short short8v;
typedef __attribute__((ext_vector_type(4))) float f32x4;

__device__ __forceinline__ float bf2f(u32 bits) { return __uint_as_float(bits << 16); }
__device__ __forceinline__ u32 f2bf(float f) {
  u32 u = __float_as_uint(f);
  return (u + 0x7FFFu + ((u >> 16) & 1u)) >> 16;   // RTNE
}
__device__ __forceinline__ u32 pack2(float a, float b) { return f2bf(a) | (f2bf(b) << 16); }
__device__ __forceinline__ void unpack8(uint4 u, float* f) {
  f[0] = bf2f(u.x & 0xffffu); f[1] = bf2f(u.x >> 16);
  f[2] = bf2f(u.y & 0xffffu); f[3] = bf2f(u.y >> 16);
  f[4] = bf2f(u.z & 0xffffu); f[5] = bf2f(u.z >> 16);
  f[6] = bf2f(u.w & 0xffffu); f[7] = bf2f(u.w >> 16);
}

// async global->LDS, 16B per lane; LDS dest = wave-uniform base + lane*16.
__device__ __forceinline__ void gload16(const void* g, void* l) {
  __builtin_amdgcn_global_load_lds(
      (const __attribute__((address_space(1))) void*)g,
      (__attribute__((address_space(3))) void*)l, 16, 0, 0);
}

// ---------------------------------------------------------------------------
// MFMA bf16 GEMM. C[N,M] = A[N,K] @ Bt[M,K]^T (+bias | +=C).
// 256x128 tile, BK=32, 4 waves; wave w = rows [w*64, w*64+64) x all 128 cols:
// acc[8][4], 32 mfma : 12 ds_read_b128 per K-step (2x compute cover vs 128²).
// global_load_lds staging, linear LDS dest + pre-swizzled global source
// (kc ^= (row>>1)&3, rule #21) -> 2-way-max bank aliasing on frag reads.
// XCD-grouped block swizzle: all col-tiles of one row band share an XCD so
// the A band is fetched once per L2 (T1, bijective incl. tail bands).
// Epilogue j-outer: every store completes a 32B sector (bf16) or 64B line
// (f32) -> no write-allocate fetch. M%128==0, K%32==0; N guarded.
// ---------------------------------------------------------------------------
template <typename CT>
__global__ __launch_bounds__(256, 2) void bgemm(
    const bf16_t* __restrict__ A, const bf16_t* __restrict__ Bt,
    const float* __restrict__ bias, CT* __restrict__ C,
    int N, int K, int M, int accumulate)
{
  __shared__ short As[2][8192];   // [buf][256 rows x 32 shorts]
  __shared__ short Bs[2][4096];   // [buf][128 rows x 32 shorts]
  const int tid = threadIdx.x;
  const int ncol = gridDim.x, nband = gridDim.y;

  // XCD-grouping swizzle (assumes wg->XCD = id%8). Bijective with tail.
  int lin = blockIdx.y * ncol + blockIdx.x;
  int band, col;
  const int full = (nband >> 3) * 8 * ncol;
  if (lin < full) {
    int g = lin >> 3, x = lin & 7;
    band = x + 8 * (g / ncol);
    col  = g % ncol;
  } else {
    int r = lin - full;
    band = (nband & ~7) + r / ncol;
    col  = r % ncol;
  }
  const int bm = band * 256, bn = col * 128;

  const int lane = tid & 63;
  const int w = tid >> 6;
  const int fr = lane & 15, fg = lane >> 4;

  // staging: chunk c = tid + t*256 -> row c>>2, k-octet (c&3) ^ ((row>>1)&3)
  const int rr = tid >> 2;
  const int kg = ((tid & 3) ^ ((tid >> 3) & 3)) << 3;   // pre-swizzled octet
  const bf16_t* gA[4];
  const bf16_t* gB[2];
#pragma unroll
  for (int t = 0; t < 4; ++t)
    gA[t] = A + (size_t)min(bm + rr + t * 64, N - 1) * K + kg;
#pragma unroll
  for (int t = 0; t < 2; ++t)
    gB[t] = Bt + (size_t)(bn + rr + t * 64) * K + kg;
  const int wb = w << 9;   // wave-uniform LDS short offset (w*64 chunks * 8)

  f32x4 acc[8][4];
#pragma unroll
  for (int i = 0; i < 8; ++i)
#pragma unroll
    for (int j = 0; j < 4; ++j) acc[i][j] = (f32x4){0.f, 0.f, 0.f, 0.f};

  auto stage = [&](int buf, int k0) {
#pragma unroll
    for (int t = 0; t < 4; ++t) gload16(gA[t] + k0, &As[buf][wb + t * 2048]);
#pragma unroll
    for (int t = 0; t < 2; ++t) gload16(gB[t] + k0, &Bs[buf][wb + t * 2048]);
  };

  stage(0, 0);
  const int nsteps = K >> 5;
  const int co = (fg ^ ((fr >> 1) & 3)) << 3;   // read-side XOR octet
  for (int s = 0; s < nsteps; ++s) {
    int cur = s & 1;
    __syncthreads();                 // buf[cur] staged; all done reading cur^1
    if (s + 1 < nsteps) stage(cur ^ 1, (s + 1) << 5);
    short8v a[4], b[8];
#pragma unroll
    for (int j = 0; j < 4; ++j)
      a[j] = *(const short8v*)&As[cur][(w * 64 + j * 16 + fr) * 32 + co];
#pragma unroll
    for (int i = 0; i < 8; ++i)
      b[i] = *(const short8v*)&Bs[cur][(i * 16 + fr) * 32 + co];
#pragma unroll
    for (int i = 0; i < 8; ++i)
#pragma unroll
      for (int j = 0; j < 4; ++j)
        acc[i][j] = __builtin_amdgcn_mfma_f32_16x16x32_bf16(b[i], a[j],
                                                            acc[i][j], 0, 0, 0);
  }

  // epilogue: D cols (fr) = A rows; D row quad (fg*4+q) = C cols.
  float4 bv[8];
#pragma unroll
  for (int i = 0; i < 8; ++i) {
    bv[i] = make_float4(0.f, 0.f, 0.f, 0.f);
    if (!accumulate && bias) bv[i] = *(const float4*)(bias + bn + i * 16 + fg * 4);
  }
#pragma unroll
  for (int j = 0; j < 4; ++j) {
    const int n = bm + w * 64 + j * 16 + fr;
    if (n >= N) continue;
#pragma unroll
    for (int i = 0; i < 8; ++i) {
      const int m0 = bn + i * 16 + fg * 4;
      f32x4 v = acc[i][j];
      if constexpr (std::is_same<CT, float>::value) {
        float* p = C + (size_t)n * M + m0;
        if (accumulate) {
          float4 o = *(float4*)p;
          o.x += v[0]; o.y += v[1]; o.z += v[2]; o.w += v[3];
          *(float4*)p = o;
        } else {
          *(float4*)p = make_float4(v[0] + bv[i].x, v[1] + bv[i].y,
                                    v[2] + bv[i].z, v[3] + bv[i].w);
        }
      } else {
        uint2 o;
        o.x = pack2(v[0] + bv[i].x, v[1] + bv[i].y);
        o.y = pack2(v[2] + bv[i].z, v[3] + bv[i].w);
        *(uint2*)(C + (size_t)n * M + m0) = o;
      }
    }
  }
}

// fp32 W[K][M] -> bf16 Wt[M][K] (transpose), 32x32 LDS tiles, z-batched.
__global__ __launch_bounds__(256) void convert_wT(
    const float* __restrict__ W, bf16_t* __restrict__ Wt, int K, int M)
{
  __shared__ float sm[32][33];
  W  += (size_t)blockIdx.z * K * M;
  Wt += (size_t)blockIdx.z * K * M;
  int mb = blockIdx.x * 32, kb = blockIdx.y * 32;
  int tx = threadIdx.x & 31, ty = threadIdx.x >> 5;
#pragma unroll
  for (int i = 0; i < 4; ++i)
    sm[ty + i * 8][tx] = W[(size_t)(kb + ty + i * 8) * M + mb + tx];
  __syncthreads();
#pragma unroll
  for (int i = 0; i < 4; ++i)
    Wt[(size_t)(mb + ty + i * 8) * K + kb + tx] = (bf16_t)f2bf(sm[tx][ty + i * 8]);
}

// fp32 -> bf16 flat cast, 4 elems/thread
__global__ __launch_bounds__(256) void f2bf_vec(
    const float* __restrict__ in, bf16_t* __restrict__ out, long n4)
{
  long t = (long)blockIdx.x * 256 + threadIdx.x;
  if (t >= n4) return;
  float4 v = ((const float4*)in)[t];
  uint2 o;
  o.x = pack2(v.x, v.y);
  o.y = pack2(v.z, v.w);
  ((uint2*)out)[t] = o;
}

// bc = (b0 [+b1] [+b2]) * inv  (512 floats)
__global__ __launch_bounds__(256) void combine_bias(
    const float* __restrict__ b0, const float* __restrict__ b1,
    const float* __restrict__ b2, float inv, float* __restrict__ out)
{
  int j = blockIdx.x * 256 + threadIdx.x;
  if (j >= 512) return;
  float v = b0[j];
  if (b1) v += b1[j];
  if (b2) v += b2[j];
  out[j] = v * inv;
}

// ---------------------------------------------------------------------------
// CSR build: histogram w/ slot assignment, 3-kernel exclusive scan, scatter.
// ---------------------------------------------------------------------------
__global__ __launch_bounds__(256) void csr_hist(
    const int* __restrict__ dst, int* __restrict__ deg, int* __restrict__ pos, int E)
{
  int e = blockIdx.x * 256 + threadIdx.x;
  if (e >= E) return;
  pos[e] = atomicAdd(&deg[dst[e]], 1);
}

__global__ __launch_bounds__(256) void scan1(
    const int* __restrict__ in, int* __restrict__ out, int* __restrict__ bsum, int n)
{
  __shared__ int sm[256];
  int t = threadIdx.x;
  int base = blockIdx.x * 1024 + t * 4;
  int v[4], sum = 0;
#pragma unroll
  for (int k = 0; k < 4; ++k) { v[k] = (base + k < n) ? in[base + k] : 0; sum += v[k]; }
  sm[t] = sum;
  __syncthreads();
  for (int off = 1; off < 256; off <<= 1) {
    int x = (t >= off) ? sm[t - off] : 0;
    __syncthreads();
    sm[t] += x;
    __syncthreads();
  }
  int run = (t > 0) ? sm[t - 1] : 0;
  if (t == 255) bsum[blockIdx.x] = sm[255];
#pragma unroll
  for (int k = 0; k < 4; ++k) {
    if (base + k < n) out[base + k] = run;
    run += v[k];
  }
}

__global__ __launch_bounds__(64) void scan2(int* __restrict__ bsum, int nb)
{
  __shared__ int sm[64];
  int t = threadIdx.x;
  int v = (t < nb) ? bsum[t] : 0;
  sm[t] = v;
  __syncthreads();
  for (int off = 1; off < 64; off <<= 1) {
    int x = (t >= off) ? sm[t - off] : 0;
    __syncthreads();
    sm[t] += x;
    __syncthreads();
  }
  if (t < nb) bsum[t] = sm[t] - v;   // exclusive
}

__global__ __launch_bounds__(256) void scan3(
    int* __restrict__ out, const int* __restrict__ bsum, int n)
{
  int g = blockIdx.x * 256 + threadIdx.x;
  if (g < n) out[g] += bsum[g >> 10];
}

__global__ __launch_bounds__(256) void csr_scatter(
    const int* __restrict__ dst, const int* __restrict__ start,
    const int* __restrict__ pos, int* __restrict__ eidx, int E)
{
  int e = blockIdx.x * 256 + threadIdx.x;
  if (e >= E) return;
  eidx[start[dst[e]] + pos[e]] = e;
}

// ---------------------------------------------------------------------------
// Fused GATv2 message+softmax+aggregate, one wave per dst node, no atomics.
// If bc != nullptr: also applies HeteroConv-mean + bias + relu (final
// relation for this node type) and writes the NEW h in place of acc.
// ---------------------------------------------------------------------------
__global__ __launch_bounds__(256) void gat_fused(
    const bf16_t* __restrict__ xl, const bf16_t* __restrict__ xr,
    const int* __restrict__ srcArr, const int* __restrict__ start,
    const int* __restrict__ deg, const int* __restrict__ eidx,
    const float* __restrict__ att, bf16_t* __restrict__ acc,
    int Nd, int accumulate, const float* __restrict__ bc, float inv_div)
{
  int d = blockIdx.x * 4 + (threadIdx.x >> 6);
  if (d >= Nd) return;
  int lane = threadIdx.x & 63;

  float xrr[8];
  unpack8(*(const uint4*)(xr + (size_t)d * 512 + lane * 8), xrr);
  float at[8];
  *(float4*)(at)     = *(const float4*)(att + lane * 8);
  *(float4*)(at + 4) = *(const float4*)(att + lane * 8 + 4);

  float acc8[8] = {0.f, 0.f, 0.f, 0.f, 0.f, 0.f, 0.f, 0.f};
  float den = 0.f;
  int n = deg[d], s0 = start[d];
  for (int i = 0; i < n; ++i) {
    int e = eidx[s0 + i];
    int s = srcArr[e];
    float f[8];
    unpack8(*(const uint4*)(xl + (size_t)s * 512 + lane * 8), f);
    float p = 0.f;
#pragma unroll
    for (int k = 0; k < 8; ++k) {
      float x = f[k] + xrr[k];
      p = fmaf(at[k], x >= 0.f ? x : NEG_SLOPE * x, p);
    }
#pragma unroll
    for (int m = 8; m >= 1; m >>= 1) p += __shfl_xor(p, m);  // 16-lane group = head
    float ex = __expf(p);
    den += ex;
#pragma unroll
    for (int k = 0; k < 8; ++k) acc8[k] = fmaf(ex, f[k], acc8[k]);
  }
  float inv = 1.f / (den + 1e-16f);
#pragma unroll
  for (int k = 0; k < 8; ++k) acc8[k] *= inv;

  bf16_t* out = acc + (size_t)d * 512 + lane * 8;
  if (accumulate) {
    float old[8];
    unpack8(*(const uint4*)out, old);
#pragma unroll
    for (int k = 0; k < 8; ++k) acc8[k] += old[k];
  }
  if (bc) {   // finalize: mean + combined bias + relu
    float bcv[8];
    *(float4*)(bcv)     = *(const float4*)(bc + lane * 8);
    *(float4*)(bcv + 4) = *(const float4*)(bc + lane * 8 + 4);
#pragma unroll
    for (int k = 0; k < 8; ++k)
      acc8[k] = fmaxf(fmaf(acc8[k], inv_div, bcv[k]), 0.f);
  }
  uint4 s;
  s.x = pack2(acc8[0], acc8[1]); s.y = pack2(acc8[2], acc8[3]);
  s.z = pack2(acc8[4], acc8[5]); s.w = pack2(acc8[6], acc8[7]);
  *(uint4*)out = s;
}

__global__ __launch_bounds__(256) void gather512(
    const bf16_t* __restrict__ src, const int* __restrict__ idx,
    bf16_t* __restrict__ out, int E)
{
  int g = blockIdx.x * blockDim.x + threadIdx.x;
  if (g >= E * 64) return;
  int e = g >> 6, c = g & 63;
  ((uint4*)out)[g] = ((const uint4*)src)[(size_t)idx[e] * 64 + c];
}

// afh = relu(answer_features @ W1 + b1) -> bf16, K=6, M=64
__global__ __launch_bounds__(256) void af_hidden(
    const float* __restrict__ af, const float* __restrict__ W1,
    const float* __restrict__ b1, bf16_t* __restrict__ out, int n)
{
  int t = blockIdx.x * blockDim.x + threadIdx.x;
  if (t >= n * 64) return;
  int i = t >> 6, j = t & 63;
  const float* a = af + (size_t)i * 6;
  float s = b1[j];
#pragma unroll
  for (int k = 0; k < 6; ++k) s = fmaf(a[k], W1[k * 64 + j], s);
  out[t] = (bf16_t)f2bf(fmaxf(s, 0.f));
}

__global__ __launch_bounds__(256) void build_sim(
    const int* __restrict__ ei, int* __restrict__ ss, int* __restrict__ sd)
{
  int t = blockIdx.x * blockDim.x + threadIdx.x;
  if (t >= E_SIM + NQ) return;
  if (t < E_SIM) { ss[t] = ei[t]; sd[t] = ei[E_SIM + t]; }
  else           { ss[t] = t - E_SIM; sd[t] = t - E_SIM; }
}

__global__ __launch_bounds__(256) void head_final(
    const float* __restrict__ qpre, const float* __restrict__ rpre,
    const float* __restrict__ qg, const float* __restrict__ qb,
    const float* __restrict__ rg, const float* __restrict__ rb,
    const float* __restrict__ score_bias, float* __restrict__ out, int E)
{
  int e = blockIdx.x * 4 + (threadIdx.x >> 6);
  if (e >= E) return;
  int lane = threadIdx.x & 63;

  float4 q = *(const float4*)(qpre + (size_t)e * 256 + lane * 4);
  float s = q.x + q.y + q.z + q.w;
#pragma unroll
  for (int m = 32; m >= 1; m >>= 1) s += __shfl_xor(s, m);
  float mu = s * (1.f / 256.f);
  float dq0 = q.x - mu, dq1 = q.y - mu, dq2 = q.z - mu, dq3 = q.w - mu;
  float v = dq0 * dq0 + dq1 * dq1 + dq2 * dq2 + dq3 * dq3;
#pragma unroll
  for (int m = 32; m >= 1; m >>= 1) v += __shfl_xor(v, m);
  float rstd = rsqrtf(v * (1.f / 256.f) + 1e-5f);
  float4 g4 = *(const float4*)(qg + lane * 4);
  float4 b4 = *(const float4*)(qb + lane * 4);
  float qn0 = dq0 * rstd * g4.x + b4.x, qn1 = dq1 * rstd * g4.y + b4.y;
  float qn2 = dq2 * rstd * g4.z + b4.z, qn3 = dq3 * rstd * g4.w + b4.w;

  float4 r = *(const float4*)(rpre + (size_t)e * 256 + lane * 4);
  s = r.x + r.y + r.z + r.w;
#pragma unroll
  for (int m = 32; m >= 1; m >>= 1) s += __shfl_xor(s, m);
  mu = s * (1.f / 256.f);
  float dr0 = r.x - mu, dr1 = r.y - mu, dr2 = r.z - mu, dr3 = r.w - mu;
  v = dr0 * dr0 + dr1 * dr1 + dr2 * dr2 + dr3 * dr3;
#pragma unroll
  for (int m = 32; m >= 1; m >>= 1) v += __shfl_xor(v, m);
  rstd = rsqrtf(v * (1.f / 256.f) + 1e-5f);
  g4 = *(const float4*)(rg + lane * 4);
  b4 = *(const float4*)(rb + lane * 4);
  float rn0 = dr0 * rstd * g4.x + b4.x, rn1 = dr1 * rstd * g4.y + b4.y;
  float rn2 = dr2 * rstd * g4.z + b4.z, rn3 = dr3 * rstd * g4.w + b4.w;

  float d = qn0 * rn0 + qn1 * rn1 + qn2 * rn2 + qn3 * rn3;
#pragma unroll
  for (int m = 32; m >= 1; m >>= 1) d += __shfl_xor(d, m);
  if (lane == 0) out[e] = d * 0.0625f + score_bias[0];
}

// ---------------------------------------------------------------------------
extern "C" void kernel_launch(void* const* d_in, const int* in_sizes, int n_in,
                              void* d_out, int out_size, void* d_ws, size_t ws_size,
                              hipStream_t stream) {
  (void)in_sizes; (void)n_in; (void)out_size;
  const float* xq      = (const float*)d_in[0];
  const float* xt      = (const float*)d_in[1];
  const float* xa      = (const float*)d_in[2];
  const float* af      = (const float*)d_in[3];
  const float* qp_W    = (const float*)d_in[4];
  const float* qp_b    = (const float*)d_in[5];
  const float* tp_W    = (const float*)d_in[6];
  const float* tp_b    = (const float*)d_in[7];
  const float* ap_W    = (const float*)d_in[8];
  const float* ap_b    = (const float*)d_in[9];
  const float* afp_W1  = (const float*)d_in[10];
  const float* afp_b1  = (const float*)d_in[11];
  const float* afp_W2  = (const float*)d_in[12];
  const float* afp_b2  = (const float*)d_in[13];
  const float* conv_Wl = (const float*)d_in[14];
  const float* conv_bl = (const float*)d_in[15];
  const float* conv_Wr = (const float*)d_in[16];
  const float* conv_br = (const float*)d_in[17];
  const float* conv_att  = (const float*)d_in[18];
  const float* conv_bias = (const float*)d_in[19];
  const float* qh_W    = (const float*)d_in[20];
  const float* qh_b    = (const float*)d_in[21];
  const float* qh_g    = (const float*)d_in[22];
  const float* qh_beta = (const float*)d_in[23];
  const float* rh_W    = (const float*)d_in[24];
  const float* rh_b    = (const float*)d_in[25];
  const float* rh_g    = (const float*)d_in[26];
  const float* rh_beta = (const float*)d_in[27];
  const float* score_b = (const float*)d_in[28];
  const int* ei_gr   = (const int*)d_in[29];
  const int* ei_lt   = (const int*)d_in[30];
  const int* ei_sim  = (const int*)d_in[31];
  const int* ei_comp = (const int*)d_in[32];
  const int* ei_gen  = (const int*)d_in[33];

  char* base = (char*)d_ws;
  size_t off = 0;
  auto alloc = [&](size_t bytes) {
    void* p = base + off;
    off = (off + bytes + 255) & ~(size_t)255;
    return p;
  };
  bf16_t* hq   = (bf16_t*)alloc((size_t)NQ * 512 * 2);
  bf16_t* ht   = (bf16_t*)alloc((size_t)NT * 512 * 2);
  bf16_t* ha   = (bf16_t*)alloc((size_t)NA * 512 * 2);
  bf16_t* acct = (bf16_t*)alloc((size_t)NT * 512 * 2);   // ht ping-pong; qpre f32
  bf16_t* accq = (bf16_t*)alloc((size_t)NQ * 512 * 2);   // hq ping-pong; afh bf16
  bf16_t* xlb  = (bf16_t*)alloc((size_t)50000 * 512 * 2);// staging/gathers/af_emb
  bf16_t* xrb  = (bf16_t*)alloc((size_t)50000 * 512 * 2);// also rpre f32
  int* simsrc  = (int*)alloc((size_t)(E_SIM + NQ) * 4);
  int* simdst  = (int*)alloc((size_t)(E_SIM + NQ) * 4);

  // bf16-transposed weights
  bf16_t* wqp  = (bf16_t*)alloc((size_t)512 * 384 * 2);
  bf16_t* wtp  = (bf16_t*)alloc((size_t)512 * 384 * 2);
  bf16_t* wap  = (bf16_t*)alloc((size_t)512 * 384 * 2);
  bf16_t* wl   = (bf16_t*)alloc((size_t)12 * 512 * 512 * 2);
  bf16_t* wr   = (bf16_t*)alloc((size_t)12 * 512 * 512 * 2);
  bf16_t* wafp2 = (bf16_t*)alloc((size_t)512 * 64 * 2);
  bf16_t* wqh  = (bf16_t*)alloc((size_t)256 * 512 * 2);
  bf16_t* wrh0 = (bf16_t*)alloc((size_t)256 * 512 * 2);
  bf16_t* wrh1 = (bf16_t*)alloc((size_t)256 * 512 * 2);
  bf16_t* wrh2 = (bf16_t*)alloc((size_t)256 * 512 * 2);
  float* bc_t  = (float*)alloc(512 * 4);
  float* bc_q  = (float*)alloc(512 * 4);
  float* bc_a  = (float*)alloc(512 * 4);

  // CSR topology. Order: 0=gr 1=rgr 2=rlt 3=sim 4=comp 5=lt (lt LAST)
  struct Topo { const int* src; const int* dst; int Nd, E; };
  Topo topo[6] = {
    {ei_gr,        ei_gr + E_GR,     NT, E_GR},
    {ei_gr + E_GR, ei_gr,            NQ, E_GR},
    {ei_lt + E_LT, ei_lt,            NT, E_LT},
    {simsrc,       simdst,           NQ, E_SIM + NQ},
    {ei_comp,      ei_comp + E_COMP, NT, E_COMP},
    {ei_lt,        ei_lt + E_LT,     NA, E_LT},
  };
  int *deg[6], *startp[6], *eidx[6];
  for (int r = 0; r < 6; ++r) {
    deg[r]    = (int*)alloc((size_t)topo[r].Nd * 4);
    startp[r] = (int*)alloc((size_t)topo[r].Nd * 4);
    eidx[r]   = (int*)alloc((size_t)topo[r].E * 4);
  }
  int* posb = (int*)alloc((size_t)MAXE * 4);
  int* bsum = (int*)alloc(64 * 4);
  if (off > ws_size) {
    fprintf(stderr, "kernel_launch: ws too small, need %zu have %zu\n", off, ws_size);
    return;
  }

  // --- weight conversion (fp32 [K][M] -> bf16 [M][K]) ---
  convert_wT<<<dim3(512 / 32, 512 / 32, 12), 256, 0, stream>>>(conv_Wl, wl, 512, 512);
  convert_wT<<<dim3(512 / 32, 512 / 32, 12), 256, 0, stream>>>(conv_Wr, wr, 512, 512);
  convert_wT<<<dim3(512 / 32, 384 / 32, 1), 256, 0, stream>>>(qp_W, wqp, 384, 512);
  convert_wT<<<dim3(512 / 32, 384 / 32, 1), 256, 0, stream>>>(tp_W, wtp, 384, 512);
  convert_wT<<<dim3(512 / 32, 384 / 32, 1), 256, 0, stream>>>(ap_W, wap, 384, 512);
  convert_wT<<<dim3(512 / 32, 64 / 32, 1), 256, 0, stream>>>(afp_W2, wafp2, 64, 512);
  convert_wT<<<dim3(256 / 32, 512 / 32, 1), 256, 0, stream>>>(qh_W, wqh, 512, 256);
  convert_wT<<<dim3(256 / 32, 512 / 32, 1), 256, 0, stream>>>(rh_W, wrh0, 512, 256);
  convert_wT<<<dim3(256 / 32, 512 / 32, 1), 256, 0, stream>>>(rh_W + 512 * 256, wrh1, 512, 256);
  convert_wT<<<dim3(256 / 32, 512 / 32, 1), 256, 0, stream>>>(rh_W + 1024 * 256, wrh2, 512, 256);

  build_sim<<<(E_SIM + NQ + 255) / 256, 256, 0, stream>>>(ei_sim, simsrc, simdst);
  for (int r = 0; r < 6; ++r) {
    const Topo& T = topo[r];
    hipMemsetAsync(deg[r], 0, (size_t)T.Nd * 4, stream);
    csr_hist<<<(T.E + 255) / 256, 256, 0, stream>>>(T.dst, deg[r], posb, T.E);
    int nb = (T.Nd + 1023) / 1024;
    scan1<<<nb, 256, 0, stream>>>(deg[r], startp[r], bsum, T.Nd);
    scan2<<<1, 64, 0, stream>>>(bsum, nb);
    scan3<<<(T.Nd + 255) / 256, 256, 0, stream>>>(startp[r], bsum, T.Nd);
    csr_scatter<<<(T.E + 255) / 256, 256, 0, stream>>>(T.dst, startp[r], posb,
                                                       eidx[r], T.E);
  }

  auto gemm = [&](const bf16_t* A, const bf16_t* Bt, const float* bias, bf16_t* C,
                  int N_, int K_, int M_) {
    dim3 g(M_ / 128, (N_ + 255) / 256);
    bgemm<bf16_t><<<g, 256, 0, stream>>>(A, Bt, bias, C, N_, K_, M_, 0);
  };
  auto gemmf = [&](const bf16_t* A, const bf16_t* Bt, const float* bias, float* C,
                   int N_, int K_, int M_, int acc_) {
    dim3 g(M_ / 128, (N_ + 255) / 256);
    bgemm<float><<<g, 256, 0, stream>>>(A, Bt, bias, C, N_, K_, M_, acc_);
  };

  // Input projections: cast fp32 inputs to bf16 in xlb, then MFMA GEMM.
  f2bf_vec<<<((long)NQ * 96 + 255) / 256, 256, 0, stream>>>(xq, xlb, (long)NQ * 96);
  gemm(xlb, wqp, qp_b, hq, NQ, 384, 512);
  f2bf_vec<<<((long)NT * 96 + 255) / 256, 256, 0, stream>>>(xt, xlb, (long)NT * 96);
  gemm(xlb, wtp, tp_b, ht, NT, 384, 512);
  f2bf_vec<<<((long)NA * 96 + 255) / 256, 256, 0, stream>>>(xa, xlb, (long)NA * 96);
  gemm(xlb, wap, ap_b, ha, NA, 384, 512);

  // Layer loop with ping-pong h buffers; last relation per dst type carries
  // the fused mean+bias+relu (bc != null) and produces the new h in acc.
  bf16_t *hq_i = hq, *ht_i = ht, *hq_o = accq, *ht_o = acct;
  for (int l = 0; l < 2; ++l) {
    size_t b = (size_t)l * 6;
    combine_bias<<<2, 256, 0, stream>>>(conv_bias + (b + 0) * 512,
        conv_bias + (b + 3) * 512, conv_bias + (b + 5) * 512, 1.f / 3.f, bc_t);
    combine_bias<<<2, 256, 0, stream>>>(conv_bias + (b + 1) * 512,
        conv_bias + (b + 4) * 512, nullptr, 0.5f, bc_q);
    combine_bias<<<2, 256, 0, stream>>>(conv_bias + (b + 2) * 512,
        nullptr, nullptr, 1.f, bc_a);

    struct Rel { const bf16_t* xs; const bf16_t* xd; int Ns, po; bf16_t* acc;
                 int accum; const float* bc; float inv; };
    Rel rels[6] = {
      {hq_i, ht_i, NQ, 0, ht_o, 0, nullptr, 0.f},      // gr
      {ht_i, hq_i, NT, 1, hq_o, 0, nullptr, 0.f},      // rgr
      {ha,   ht_i, NA, 3, ht_o, 1, nullptr, 0.f},      // rlt
      {hq_i, hq_i, NQ, 4, hq_o, 1, bc_q, 0.5f},        // sim (final for q)
      {ht_i, ht_i, NT, 5, ht_o, 1, bc_t, 1.f / 3.f},   // comp (final for t)
      {ht_i, ha,   NT, 2, ha,   0, bc_a, 1.f},         // lt (final for a, in-place)
    };
    for (int r = 0; r < 6; ++r) {
      const Rel& R = rels[r];
      const Topo& T = topo[r];
      size_t po = (size_t)l * 6 + R.po;
      gemm(R.xs, wl + po * 512 * 512, conv_bl + po * 512, xlb, R.Ns, 512, 512);
      gemm(R.xd, wr + po * 512 * 512, conv_br + po * 512, xrb, T.Nd, 512, 512);
      int gb = (T.Nd + 3) / 4;
      gat_fused<<<gb, 256, 0, stream>>>(xlb, xrb, T.src, startp[r], deg[r],
                                        eidx[r], conv_att + po * 512, R.acc,
                                        T.Nd, R.accum, R.bc, R.inv);
    }
    bf16_t* t;
    t = hq_i; hq_i = hq_o; hq_o = t;
    t = ht_i; ht_i = ht_o; ht_o = t;
  }
  // after 2 swaps: hq_i==hq, ht_i==ht; scratch acct/accq free again.

  // Head. qpre(f32)->acct region, rpre(f32)->xrb region, gathers/af_emb->xlb,
  // afh(bf16)->accq.
  float* qpre = (float*)acct;
  float* rpre = (float*)xrb;
  bf16_t* afh = accq;
  const int* gsrc = ei_gen;
  const int* gdst = ei_gen + E_GEN;
  dim3 gg((E_GEN * 64 + 255) / 256);

  gather512<<<gg, 256, 0, stream>>>(hq_i, gsrc, xlb, E_GEN);               // q_emb
  gemmf(xlb, wqh, qh_b, qpre, E_GEN, 512, 256, 0);
  gather512<<<gg, 256, 0, stream>>>(ht_i, gdst, xlb, E_GEN);               // t_emb
  gemmf(xlb, wrh0, rh_b, rpre, E_GEN, 512, 256, 0);
  gather512<<<gg, 256, 0, stream>>>(ha, gdst, xlb, E_GEN);                 // a_emb
  gemmf(xlb, wrh1, nullptr, rpre, E_GEN, 512, 256, 1);
  af_hidden<<<(E_GEN * 64 + 255) / 256, 256, 0, stream>>>(af, afp_W1, afp_b1,
                                                          afh, E_GEN);
  gemm(afh, wafp2, afp_b2, xlb, E_GEN, 64, 512);                           // af_emb
  gemmf(xlb, wrh2, nullptr, rpre, E_GEN, 512, 256, 1);
  head_final<<<(E_GEN + 3) / 4, 256, 0, stream>>>(
      qpre, rpre, qh_g, qh_beta, rh_g, rh_beta, score_b, (float*)d_out, E_GEN);
}

// Round 8
// 1951.590 us; speedup vs baseline: 7.0946x; 1.0258x over previous
//
#include <hip/hip_runtime.h>
#include <cstdio>
#include <type_traits>

#define NQ 10000
#define NT 50000
#define NA 50000
#define E_GR 50000
#define E_LT 50000
#define E_SIM 80000
#define E_COMP 100000
#define E_GEN 50000
#define MAXE 100000
#define NEG_SLOPE 0.2f

typedef unsigned short bf16_t;
typedef unsigned int u32;
typedef __attribute__((ext_vector_type(8))) short short8v;
typedef __attribute__((ext_vector_type(4))) float f32x4;

__device__ __forceinline__ float bf2f(u32 bits) { return __uint_as_float(bits << 16); }
__device__ __forceinline__ u32 f2bf(float f) {
  u32 u = __float_as_uint(f);
  return (u + 0x7FFFu + ((u >> 16) & 1u)) >> 16;   // RTNE
}
__device__ __forceinline__ u32 pack2(float a, float b) { return f2bf(a) | (f2bf(b) << 16); }
__device__ __forceinline__ void unpack8(uint4 u, float* f) {
  f[0] = bf2f(u.x & 0xffffu); f[1] = bf2f(u.x >> 16);
  f[2] = bf2f(u.y & 0xffffu); f[3] = bf2f(u.y >> 16);
  f[4] = bf2f(u.z & 0xffffu); f[5] = bf2f(u.z >> 16);
  f[6] = bf2f(u.w & 0xffffu); f[7] = bf2f(u.w >> 16);
}

// async global->LDS, 16B per lane; LDS dest = wave-uniform base + lane*16.
__device__ __forceinline__ void gload16(const void* g, void* l) {
  __builtin_amdgcn_global_load_lds(
      (const __attribute__((address_space(1))) void*)g,
      (__attribute__((address_space(3))) void*)l, 16, 0, 0);
}

// ---------------------------------------------------------------------------
// MFMA bf16 GEMM. C[N,M] = A[N,K] @ Bt[M,K]^T (+bias | +=C).
// 256x128 tile, BK=32, 4 waves; acc[8][4] per wave (rows w*64..w*64+63).
// T4 pipeline: 3 LDS buffers, 2-deep prefetch via global_load_lds; raw
// s_barrier + counted vmcnt(12/6/0) so prefetch loads stay in flight across
// barriers (never drain except at tail). Two barriers per K-step:
//   [stage s+2] vmcnt(12) bar1 [ds_read+MFMA buf s] bar2
// bar1: buf[s] writes published; bar2: all reads done before buf reuse.
// Linear LDS dest + pre-swizzled global k-octet (rule #21) -> <=2-way bank
// aliasing (free). XCD-grouped swizzle keeps one A row-band per XCD L2.
// Optional ridx: A-row indirection (fuses gather into staging).
// M%128==0, K%32==0 (nsteps>=2); N guarded.
// ---------------------------------------------------------------------------
template <typename CT>
__global__ __launch_bounds__(256, 2) void bgemm(
    const bf16_t* __restrict__ A, const bf16_t* __restrict__ Bt,
    const float* __restrict__ bias, CT* __restrict__ C,
    const int* __restrict__ ridx, int N, int K, int M, int accumulate)
{
  __shared__ short As[3][8192];   // [buf][256 rows x 32 shorts]
  __shared__ short Bs[3][4096];   // [buf][128 rows x 32 shorts]
  const int tid = threadIdx.x;
  const int ncol = gridDim.x, nband = gridDim.y;

  // XCD-grouping swizzle (wg->XCD = id%8). Bijective incl. tail bands.
  int lin = blockIdx.y * ncol + blockIdx.x;
  int band, col;
  const int full = (nband >> 3) * 8 * ncol;
  if (lin < full) {
    int g = lin >> 3, x = lin & 7;
    band = x + 8 * (g / ncol);
    col  = g % ncol;
  } else {
    int r = lin - full;
    band = (nband & ~7) + r / ncol;
    col  = r % ncol;
  }
  const int bm = band * 256, bn = col * 128;

  const int lane = tid & 63;
  const int w = tid >> 6;
  const int fr = lane & 15, fg = lane >> 4;

  // staging: chunk c = tid + t*256 -> row c>>2, k-octet (c&3)^((row>>1)&3).
  const int rr = tid >> 2;
  const int kg = ((tid & 3) ^ ((tid >> 3) & 3)) << 3;   // pre-swizzled octet
  const bf16_t* gA[4];
  const bf16_t* gB[2];
#pragma unroll
  for (int t = 0; t < 4; ++t) {
    int rc = min(bm + rr + t * 64, N - 1);
    int arow = ridx ? ridx[rc] : rc;
    gA[t] = A + (size_t)arow * K + kg;
  }
#pragma unroll
  for (int t = 0; t < 2; ++t)
    gB[t] = Bt + (size_t)(bn + rr + t * 64) * K + kg;
  const int wb = w << 9;   // wave-uniform LDS short offset

  f32x4 acc[8][4];
#pragma unroll
  for (int i = 0; i < 8; ++i)
#pragma unroll
    for (int j = 0; j < 4; ++j) acc[i][j] = (f32x4){0.f, 0.f, 0.f, 0.f};

  auto stage = [&](int buf, int k0) {
#pragma unroll
    for (int t = 0; t < 4; ++t) gload16(gA[t] + k0, &As[buf][wb + t * 2048]);
#pragma unroll
    for (int t = 0; t < 2; ++t) gload16(gB[t] + k0, &Bs[buf][wb + t * 2048]);
  };

  const int nsteps = K >> 5;
  stage(0, 0);
  if (nsteps > 1) stage(1, 32);
  const int co = (fg ^ ((fr >> 1) & 3)) << 3;   // read-side XOR octet
  for (int s = 0; s < nsteps; ++s) {
    int cur = s % 3;
    if (s + 2 < nsteps) stage((s + 2) % 3, (s + 2) << 5);
    // wait only for buf[cur]'s 6 loads (oldest); deeper prefetch stays in flight
    if (s + 3 <= nsteps)      asm volatile("s_waitcnt vmcnt(12)" ::: "memory");
    else if (s + 2 == nsteps) asm volatile("s_waitcnt vmcnt(6)" ::: "memory");
    else                      asm volatile("s_waitcnt vmcnt(0)" ::: "memory");
    __builtin_amdgcn_s_barrier();           // publish buf[cur] to all waves
    asm volatile("" ::: "memory");
    short8v a[4], b[8];
#pragma unroll
    for (int j = 0; j < 4; ++j)
      a[j] = *(const short8v*)&As[cur][(w * 64 + j * 16 + fr) * 32 + co];
#pragma unroll
    for (int i = 0; i < 8; ++i)
      b[i] = *(const short8v*)&Bs[cur][(i * 16 + fr) * 32 + co];
#pragma unroll
    for (int i = 0; i < 8; ++i)
#pragma unroll
      for (int j = 0; j < 4; ++j)
        acc[i][j] = __builtin_amdgcn_mfma_f32_16x16x32_bf16(b[i], a[j],
                                                            acc[i][j], 0, 0, 0);
    asm volatile("" ::: "memory");
    __builtin_amdgcn_s_barrier();           // reads done before buf reuse
  }

  // epilogue: D cols (fr) = A rows; D row quad (fg*4+q) = C cols.
  float4 bv[8];
#pragma unroll
  for (int i = 0; i < 8; ++i) {
    bv[i] = make_float4(0.f, 0.f, 0.f, 0.f);
    if (!accumulate && bias) bv[i] = *(const float4*)(bias + bn + i * 16 + fg * 4);
  }
#pragma unroll
  for (int j = 0; j < 4; ++j) {
    const int n = bm + w * 64 + j * 16 + fr;
    if (n >= N) continue;
#pragma unroll
    for (int i = 0; i < 8; ++i) {
      const int m0 = bn + i * 16 + fg * 4;
      f32x4 v = acc[i][j];
      if constexpr (std::is_same<CT, float>::value) {
        float* p = C + (size_t)n * M + m0;
        if (accumulate) {
          float4 o = *(float4*)p;
          o.x += v[0]; o.y += v[1]; o.z += v[2]; o.w += v[3];
          *(float4*)p = o;
        } else {
          *(float4*)p = make_float4(v[0] + bv[i].x, v[1] + bv[i].y,
                                    v[2] + bv[i].z, v[3] + bv[i].w);
        }
      } else {
        uint2 o;
        o.x = pack2(v[0] + bv[i].x, v[1] + bv[i].y);
        o.y = pack2(v[2] + bv[i].z, v[3] + bv[i].w);
        *(uint2*)(C + (size_t)n * M + m0) = o;
      }
    }
  }
}

// fp32 W[K][M] -> bf16 Wt[M][K] (transpose), 32x32 LDS tiles, z-batched.
__global__ __launch_bounds__(256) void convert_wT(
    const float* __restrict__ W, bf16_t* __restrict__ Wt, int K, int M)
{
  __shared__ float sm[32][33];
  W  += (size_t)blockIdx.z * K * M;
  Wt += (size_t)blockIdx.z * K * M;
  int mb = blockIdx.x * 32, kb = blockIdx.y * 32;
  int tx = threadIdx.x & 31, ty = threadIdx.x >> 5;
#pragma unroll
  for (int i = 0; i < 4; ++i)
    sm[ty + i * 8][tx] = W[(size_t)(kb + ty + i * 8) * M + mb + tx];
  __syncthreads();
#pragma unroll
  for (int i = 0; i < 4; ++i)
    Wt[(size_t)(mb + ty + i * 8) * K + kb + tx] = (bf16_t)f2bf(sm[tx][ty + i * 8]);
}

// fp32 -> bf16 flat cast, 4 elems/thread
__global__ __launch_bounds__(256) void f2bf_vec(
    const float* __restrict__ in, bf16_t* __restrict__ out, long n4)
{
  long t = (long)blockIdx.x * 256 + threadIdx.x;
  if (t >= n4) return;
  float4 v = ((const float4*)in)[t];
  uint2 o;
  o.x = pack2(v.x, v.y);
  o.y = pack2(v.z, v.w);
  ((uint2*)out)[t] = o;
}

// bc = (b0 [+b1] [+b2]) * inv  (512 floats)
__global__ __launch_bounds__(256) void combine_bias(
    const float* __restrict__ b0, const float* __restrict__ b1,
    const float* __restrict__ b2, float inv, float* __restrict__ out)
{
  int j = blockIdx.x * 256 + threadIdx.x;
  if (j >= 512) return;
  float v = b0[j];
  if (b1) v += b1[j];
  if (b2) v += b2[j];
  out[j] = v * inv;
}

// ---------------------------------------------------------------------------
// CSR build: histogram w/ slot assignment, 3-kernel exclusive scan, scatter.
// ---------------------------------------------------------------------------
__global__ __launch_bounds__(256) void csr_hist(
    const int* __restrict__ dst, int* __restrict__ deg, int* __restrict__ pos, int E)
{
  int e = blockIdx.x * 256 + threadIdx.x;
  if (e >= E) return;
  pos[e] = atomicAdd(&deg[dst[e]], 1);
}

__global__ __launch_bounds__(256) void scan1(
    const int* __restrict__ in, int* __restrict__ out, int* __restrict__ bsum, int n)
{
  __shared__ int sm[256];
  int t = threadIdx.x;
  int base = blockIdx.x * 1024 + t * 4;
  int v[4], sum = 0;
#pragma unroll
  for (int k = 0; k < 4; ++k) { v[k] = (base + k < n) ? in[base + k] : 0; sum += v[k]; }
  sm[t] = sum;
  __syncthreads();
  for (int off = 1; off < 256; off <<= 1) {
    int x = (t >= off) ? sm[t - off] : 0;
    __syncthreads();
    sm[t] += x;
    __syncthreads();
  }
  int run = (t > 0) ? sm[t - 1] : 0;
  if (t == 255) bsum[blockIdx.x] = sm[255];
#pragma unroll
  for (int k = 0; k < 4; ++k) {
    if (base + k < n) out[base + k] = run;
    run += v[k];
  }
}

__global__ __launch_bounds__(64) void scan2(int* __restrict__ bsum, int nb)
{
  __shared__ int sm[64];
  int t = threadIdx.x;
  int v = (t < nb) ? bsum[t] : 0;
  sm[t] = v;
  __syncthreads();
  for (int off = 1; off < 64; off <<= 1) {
    int x = (t >= off) ? sm[t - off] : 0;
    __syncthreads();
    sm[t] += x;
    __syncthreads();
  }
  if (t < nb) bsum[t] = sm[t] - v;   // exclusive
}

__global__ __launch_bounds__(256) void scan3(
    int* __restrict__ out, const int* __restrict__ bsum, int n)
{
  int g = blockIdx.x * 256 + threadIdx.x;
  if (g < n) out[g] += bsum[g >> 10];
}

__global__ __launch_bounds__(256) void csr_scatter(
    const int* __restrict__ dst, const int* __restrict__ start,
    const int* __restrict__ pos, int* __restrict__ eidx, int E)
{
  int e = blockIdx.x * 256 + threadIdx.x;
  if (e >= E) return;
  eidx[start[dst[e]] + pos[e]] = e;
}

// ---------------------------------------------------------------------------
// Fused GATv2 message+softmax+aggregate, one wave per dst node, no atomics.
// If bc != nullptr: also applies HeteroConv-mean + bias + relu (final
// relation for this node type) and writes the NEW h in place of acc.
// ---------------------------------------------------------------------------
__global__ __launch_bounds__(256) void gat_fused(
    const bf16_t* __restrict__ xl, const bf16_t* __restrict__ xr,
    const int* __restrict__ srcArr, const int* __restrict__ start,
    const int* __restrict__ deg, const int* __restrict__ eidx,
    const float* __restrict__ att, bf16_t* __restrict__ acc,
    int Nd, int accumulate, const float* __restrict__ bc, float inv_div)
{
  int d = blockIdx.x * 4 + (threadIdx.x >> 6);
  if (d >= Nd) return;
  int lane = threadIdx.x & 63;

  float xrr[8];
  unpack8(*(const uint4*)(xr + (size_t)d * 512 + lane * 8), xrr);
  float at[8];
  *(float4*)(at)     = *(const float4*)(att + lane * 8);
  *(float4*)(at + 4) = *(const float4*)(att + lane * 8 + 4);

  float acc8[8] = {0.f, 0.f, 0.f, 0.f, 0.f, 0.f, 0.f, 0.f};
  float den = 0.f;
  int n = deg[d], s0 = start[d];
  for (int i = 0; i < n; ++i) {
    int e = eidx[s0 + i];
    int s = srcArr[e];
    float f[8];
    unpack8(*(const uint4*)(xl + (size_t)s * 512 + lane * 8), f);
    float p = 0.f;
#pragma unroll
    for (int k = 0; k < 8; ++k) {
      float x = f[k] + xrr[k];
      p = fmaf(at[k], x >= 0.f ? x : NEG_SLOPE * x, p);
    }
#pragma unroll
    for (int m = 8; m >= 1; m >>= 1) p += __shfl_xor(p, m);  // 16-lane group = head
    float ex = __expf(p);
    den += ex;
#pragma unroll
    for (int k = 0; k < 8; ++k) acc8[k] = fmaf(ex, f[k], acc8[k]);
  }
  float inv = 1.f / (den + 1e-16f);
#pragma unroll
  for (int k = 0; k < 8; ++k) acc8[k] *= inv;

  bf16_t* out = acc + (size_t)d * 512 + lane * 8;
  if (accumulate) {
    float old[8];
    unpack8(*(const uint4*)out, old);
#pragma unroll
    for (int k = 0; k < 8; ++k) acc8[k] += old[k];
  }
  if (bc) {   // finalize: mean + combined bias + relu
    float bcv[8];
    *(float4*)(bcv)     = *(const float4*)(bc + lane * 8);
    *(float4*)(bcv + 4) = *(const float4*)(bc + lane * 8 + 4);
#pragma unroll
    for (int k = 0; k < 8; ++k)
      acc8[k] = fmaxf(fmaf(acc8[k], inv_div, bcv[k]), 0.f);
  }
  uint4 s;
  s.x = pack2(acc8[0], acc8[1]); s.y = pack2(acc8[2], acc8[3]);
  s.z = pack2(acc8[4], acc8[5]); s.w = pack2(acc8[6], acc8[7]);
  *(uint4*)out = s;
}

// afh = relu(answer_features @ W1 + b1) -> bf16, K=6, M=64
__global__ __launch_bounds__(256) void af_hidden(
    const float* __restrict__ af, const float* __restrict__ W1,
    const float* __restrict__ b1, bf16_t* __restrict__ out, int n)
{
  int t = blockIdx.x * blockDim.x + threadIdx.x;
  if (t >= n * 64) return;
  int i = t >> 6, j = t & 63;
  const float* a = af + (size_t)i * 6;
  float s = b1[j];
#pragma unroll
  for (int k = 0; k < 6; ++k) s = fmaf(a[k], W1[k * 64 + j], s);
  out[t] = (bf16_t)f2bf(fmaxf(s, 0.f));
}

__global__ __launch_bounds__(256) void build_sim(
    const int* __restrict__ ei, int* __restrict__ ss, int* __restrict__ sd)
{
  int t = blockIdx.x * blockDim.x + threadIdx.x;
  if (t >= E_SIM + NQ) return;
  if (t < E_SIM) { ss[t] = ei[t]; sd[t] = ei[E_SIM + t]; }
  else           { ss[t] = t - E_SIM; sd[t] = t - E_SIM; }
}

__global__ __launch_bounds__(256) void head_final(
    const float* __restrict__ qpre, const float* __restrict__ rpre,
    const float* __restrict__ qg, const float* __restrict__ qb,
    const float* __restrict__ rg, const float* __restrict__ rb,
    const float* __restrict__ score_bias, float* __restrict__ out, int E)
{
  int e = blockIdx.x * 4 + (threadIdx.x >> 6);
  if (e >= E) return;
  int lane = threadIdx.x & 63;

  float4 q = *(const float4*)(qpre + (size_t)e * 256 + lane * 4);
  float s = q.x + q.y + q.z + q.w;
#pragma unroll
  for (int m = 32; m >= 1; m >>= 1) s += __shfl_xor(s, m);
  float mu = s * (1.f / 256.f);
  float dq0 = q.x - mu, dq1 = q.y - mu, dq2 = q.z - mu, dq3 = q.w - mu;
  float v = dq0 * dq0 + dq1 * dq1 + dq2 * dq2 + dq3 * dq3;
#pragma unroll
  for (int m = 32; m >= 1; m >>= 1) v += __shfl_xor(v, m);
  float rstd = rsqrtf(v * (1.f / 256.f) + 1e-5f);
  float4 g4 = *(const float4*)(qg + lane * 4);
  float4 b4 = *(const float4*)(qb + lane * 4);
  float qn0 = dq0 * rstd * g4.x + b4.x, qn1 = dq1 * rstd * g4.y + b4.y;
  float qn2 = dq2 * rstd * g4.z + b4.z, qn3 = dq3 * rstd * g4.w + b4.w;

  float4 r = *(const float4*)(rpre + (size_t)e * 256 + lane * 4);
  s = r.x + r.y + r.z + r.w;
#pragma unroll
  for (int m = 32; m >= 1; m >>= 1) s += __shfl_xor(s, m);
  mu = s * (1.f / 256.f);
  float dr0 = r.x - mu, dr1 = r.y - mu, dr2 = r.z - mu, dr3 = r.w - mu;
  v = dr0 * dr0 + dr1 * dr1 + dr2 * dr2 + dr3 * dr3;
#pragma unroll
  for (int m = 32; m >= 1; m >>= 1) v += __shfl_xor(v, m);
  rstd = rsqrtf(v * (1.f / 256.f) + 1e-5f);
  g4 = *(const float4*)(rg + lane * 4);
  b4 = *(const float4*)(rb + lane * 4);
  float rn0 = dr0 * rstd * g4.x + b4.x, rn1 = dr1 * rstd * g4.y + b4.y;
  float rn2 = dr2 * rstd * g4.z + b4.z, rn3 = dr3 * rstd * g4.w + b4.w;

  float d = qn0 * rn0 + qn1 * rn1 + qn2 * rn2 + qn3 * rn3;
#pragma unroll
  for (int m = 32; m >= 1; m >>= 1) d += __shfl_xor(d, m);
  if (lane == 0) out[e] = d * 0.0625f + score_bias[0];
}

// ---------------------------------------------------------------------------
extern "C" void kernel_launch(void* const* d_in, const int* in_sizes, int n_in,
                              void* d_out, int out_size, void* d_ws, size_t ws_size,
                              hipStream_t stream) {
  (void)in_sizes; (void)n_in; (void)out_size;
  const float* xq      = (const float*)d_in[0];
  const float* xt      = (const float*)d_in[1];
  const float* xa      = (const float*)d_in[2];
  const float* af      = (const float*)d_in[3];
  const float* qp_W    = (const float*)d_in[4];
  const float* qp_b    = (const float*)d_in[5];
  const float* tp_W    = (const float*)d_in[6];
  const float* tp_b    = (const float*)d_in[7];
  const float* ap_W    = (const float*)d_in[8];
  const float* ap_b    = (const float*)d_in[9];
  const float* afp_W1  = (const float*)d_in[10];
  const float* afp_b1  = (const float*)d_in[11];
  const float* afp_W2  = (const float*)d_in[12];
  const float* afp_b2  = (const float*)d_in[13];
  const float* conv_Wl = (const float*)d_in[14];
  const float* conv_bl = (const float*)d_in[15];
  const float* conv_Wr = (const float*)d_in[16];
  const float* conv_br = (const float*)d_in[17];
  const float* conv_att  = (const float*)d_in[18];
  const float* conv_bias = (const float*)d_in[19];
  const float* qh_W    = (const float*)d_in[20];
  const float* qh_b    = (const float*)d_in[21];
  const float* qh_g    = (const float*)d_in[22];
  const float* qh_beta = (const float*)d_in[23];
  const float* rh_W    = (const float*)d_in[24];
  const float* rh_b    = (const float*)d_in[25];
  const float* rh_g    = (const float*)d_in[26];
  const float* rh_beta = (const float*)d_in[27];
  const float* score_b = (const float*)d_in[28];
  const int* ei_gr   = (const int*)d_in[29];
  const int* ei_lt   = (const int*)d_in[30];
  const int* ei_sim  = (const int*)d_in[31];
  const int* ei_comp = (const int*)d_in[32];
  const int* ei_gen  = (const int*)d_in[33];

  char* base = (char*)d_ws;
  size_t off = 0;
  auto alloc = [&](size_t bytes) {
    void* p = base + off;
    off = (off + bytes + 255) & ~(size_t)255;
    return p;
  };
  bf16_t* hq   = (bf16_t*)alloc((size_t)NQ * 512 * 2);
  bf16_t* ht   = (bf16_t*)alloc((size_t)NT * 512 * 2);
  bf16_t* ha   = (bf16_t*)alloc((size_t)NA * 512 * 2);
  bf16_t* acct = (bf16_t*)alloc((size_t)NT * 512 * 2);   // ht ping-pong; qpre f32
  bf16_t* accq = (bf16_t*)alloc((size_t)NQ * 512 * 2);   // hq ping-pong; afh bf16
  bf16_t* xlb  = (bf16_t*)alloc((size_t)50000 * 512 * 2);// staging/af_emb
  bf16_t* xrb  = (bf16_t*)alloc((size_t)50000 * 512 * 2);// also rpre f32
  int* simsrc  = (int*)alloc((size_t)(E_SIM + NQ) * 4);
  int* simdst  = (int*)alloc((size_t)(E_SIM + NQ) * 4);

  // bf16-transposed weights
  bf16_t* wqp  = (bf16_t*)alloc((size_t)512 * 384 * 2);
  bf16_t* wtp  = (bf16_t*)alloc((size_t)512 * 384 * 2);
  bf16_t* wap  = (bf16_t*)alloc((size_t)512 * 384 * 2);
  bf16_t* wl   = (bf16_t*)alloc((size_t)12 * 512 * 512 * 2);
  bf16_t* wr   = (bf16_t*)alloc((size_t)12 * 512 * 512 * 2);
  bf16_t* wafp2 = (bf16_t*)alloc((size_t)512 * 64 * 2);
  bf16_t* wqh  = (bf16_t*)alloc((size_t)256 * 512 * 2);
  bf16_t* wrh0 = (bf16_t*)alloc((size_t)256 * 512 * 2);
  bf16_t* wrh1 = (bf16_t*)alloc((size_t)256 * 512 * 2);
  bf16_t* wrh2 = (bf16_t*)alloc((size_t)256 * 512 * 2);
  float* bc_t  = (float*)alloc(512 * 4);
  float* bc_q  = (float*)alloc(512 * 4);
  float* bc_a  = (float*)alloc(512 * 4);

  // CSR topology. Order: 0=gr 1=rgr 2=rlt 3=sim 4=comp 5=lt (lt LAST)
  struct Topo { const int* src; const int* dst; int Nd, E; };
  Topo topo[6] = {
    {ei_gr,        ei_gr + E_GR,     NT, E_GR},
    {ei_gr + E_GR, ei_gr,            NQ, E_GR},
    {ei_lt + E_LT, ei_lt,            NT, E_LT},
    {simsrc,       simdst,           NQ, E_SIM + NQ},
    {ei_comp,      ei_comp + E_COMP, NT, E_COMP},
    {ei_lt,        ei_lt + E_LT,     NA, E_LT},
  };
  int *deg[6], *startp[6], *eidx[6];
  for (int r = 0; r < 6; ++r) {
    deg[r]    = (int*)alloc((size_t)topo[r].Nd * 4);
    startp[r] = (int*)alloc((size_t)topo[r].Nd * 4);
    eidx[r]   = (int*)alloc((size_t)topo[r].E * 4);
  }
  int* posb = (int*)alloc((size_t)MAXE * 4);
  int* bsum = (int*)alloc(64 * 4);
  if (off > ws_size) {
    fprintf(stderr, "kernel_launch: ws too small, need %zu have %zu\n", off, ws_size);
    return;
  }

  // --- weight conversion (fp32 [K][M] -> bf16 [M][K]) ---
  convert_wT<<<dim3(512 / 32, 512 / 32, 12), 256, 0, stream>>>(conv_Wl, wl, 512, 512);
  convert_wT<<<dim3(512 / 32, 512 / 32, 12), 256, 0, stream>>>(conv_Wr, wr, 512, 512);
  convert_wT<<<dim3(512 / 32, 384 / 32, 1), 256, 0, stream>>>(qp_W, wqp, 384, 512);
  convert_wT<<<dim3(512 / 32, 384 / 32, 1), 256, 0, stream>>>(tp_W, wtp, 384, 512);
  convert_wT<<<dim3(512 / 32, 384 / 32, 1), 256, 0, stream>>>(ap_W, wap, 384, 512);
  convert_wT<<<dim3(512 / 32, 64 / 32, 1), 256, 0, stream>>>(afp_W2, wafp2, 64, 512);
  convert_wT<<<dim3(256 / 32, 512 / 32, 1), 256, 0, stream>>>(qh_W, wqh, 512, 256);
  convert_wT<<<dim3(256 / 32, 512 / 32, 1), 256, 0, stream>>>(rh_W, wrh0, 512, 256);
  convert_wT<<<dim3(256 / 32, 512 / 32, 1), 256, 0, stream>>>(rh_W + 512 * 256, wrh1, 512, 256);
  convert_wT<<<dim3(256 / 32, 512 / 32, 1), 256, 0, stream>>>(rh_W + 1024 * 256, wrh2, 512, 256);

  build_sim<<<(E_SIM + NQ + 255) / 256, 256, 0, stream>>>(ei_sim, simsrc, simdst);
  for (int r = 0; r < 6; ++r) {
    const Topo& T = topo[r];
    hipMemsetAsync(deg[r], 0, (size_t)T.Nd * 4, stream);
    csr_hist<<<(T.E + 255) / 256, 256, 0, stream>>>(T.dst, deg[r], posb, T.E);
    int nb = (T.Nd + 1023) / 1024;
    scan1<<<nb, 256, 0, stream>>>(deg[r], startp[r], bsum, T.Nd);
    scan2<<<1, 64, 0, stream>>>(bsum, nb);
    scan3<<<(T.Nd + 255) / 256, 256, 0, stream>>>(startp[r], bsum, T.Nd);
    csr_scatter<<<(T.E + 255) / 256, 256, 0, stream>>>(T.dst, startp[r], posb,
                                                       eidx[r], T.E);
  }

  auto gemm = [&](const bf16_t* A, const bf16_t* Bt, const float* bias, bf16_t* C,
                  int N_, int K_, int M_, const int* ridx = nullptr) {
    dim3 g(M_ / 128, (N_ + 255) / 256);
    bgemm<bf16_t><<<g, 256, 0, stream>>>(A, Bt, bias, C, ridx, N_, K_, M_, 0);
  };
  auto gemmf = [&](const bf16_t* A, const bf16_t* Bt, const float* bias, float* C,
                   int N_, int K_, int M_, int acc_, const int* ridx = nullptr) {
    dim3 g(M_ / 128, (N_ + 255) / 256);
    bgemm<float><<<g, 256, 0, stream>>>(A, Bt, bias, C, ridx, N_, K_, M_, acc_);
  };

  // Input projections: cast fp32 inputs to bf16 in xlb, then MFMA GEMM.
  f2bf_vec<<<((long)NQ * 96 + 255) / 256, 256, 0, stream>>>(xq, xlb, (long)NQ * 96);
  gemm(xlb, wqp, qp_b, hq, NQ, 384, 512);
  f2bf_vec<<<((long)NT * 96 + 255) / 256, 256, 0, stream>>>(xt, xlb, (long)NT * 96);
  gemm(xlb, wtp, tp_b, ht, NT, 384, 512);
  f2bf_vec<<<((long)NA * 96 + 255) / 256, 256, 0, stream>>>(xa, xlb, (long)NA * 96);
  gemm(xlb, wap, ap_b, ha, NA, 384, 512);

  // Layer loop with ping-pong h buffers; last relation per dst type carries
  // the fused mean+bias+relu (bc != null) and produces the new h in acc.
  bf16_t *hq_i = hq, *ht_i = ht, *hq_o = accq, *ht_o = acct;
  for (int l = 0; l < 2; ++l) {
    size_t b = (size_t)l * 6;
    combine_bias<<<2, 256, 0, stream>>>(conv_bias + (b + 0) * 512,
        conv_bias + (b + 3) * 512, conv_bias + (b + 5) * 512, 1.f / 3.f, bc_t);
    combine_bias<<<2, 256, 0, stream>>>(conv_bias + (b + 1) * 512,
        conv_bias + (b + 4) * 512, nullptr, 0.5f, bc_q);
    combine_bias<<<2, 256, 0, stream>>>(conv_bias + (b + 2) * 512,
        nullptr, nullptr, 1.f, bc_a);

    struct Rel { const bf16_t* xs; const bf16_t* xd; int Ns, po; bf16_t* acc;
                 int accum; const float* bc; float inv; };
    Rel rels[6] = {
      {hq_i, ht_i, NQ, 0, ht_o, 0, nullptr, 0.f},      // gr
      {ht_i, hq_i, NT, 1, hq_o, 0, nullptr, 0.f},      // rgr
      {ha,   ht_i, NA, 3, ht_o, 1, nullptr, 0.f},      // rlt
      {hq_i, hq_i, NQ, 4, hq_o, 1, bc_q, 0.5f},        // sim (final for q)
      {ht_i, ht_i, NT, 5, ht_o, 1, bc_t, 1.f / 3.f},   // comp (final for t)
      {ht_i, ha,   NT, 2, ha,   0, bc_a, 1.f},         // lt (final for a, in-place)
    };
    for (int r = 0; r < 6; ++r) {
      const Rel& R = rels[r];
      const Topo& T = topo[r];
      size_t po = (size_t)l * 6 + R.po;
      gemm(R.xs, wl + po * 512 * 512, conv_bl + po * 512, xlb, R.Ns, 512, 512);
      gemm(R.xd, wr + po * 512 * 512, conv_br + po * 512, xrb, T.Nd, 512, 512);
      int gb = (T.Nd + 3) / 4;
      gat_fused<<<gb, 256, 0, stream>>>(xlb, xrb, T.src, startp[r], deg[r],
                                        eidx[r], conv_att + po * 512, R.acc,
                                        T.Nd, R.accum, R.bc, R.inv);
    }
    bf16_t* t;
    t = hq_i; hq_i = hq_o; hq_o = t;
    t = ht_i; ht_i = ht_o; ht_o = t;
  }
  // after 2 swaps: hq_i==hq, ht_i==ht; scratch acct/accq free again.

  // Head: gathers fused into bgemm via ridx. qpre(f32)->acct region,
  // rpre(f32)->xrb region, af_emb->xlb, afh(bf16)->accq.
  float* qpre = (float*)acct;
  float* rpre = (float*)xrb;
  bf16_t* afh = accq;
  const int* gsrc = ei_gen;
  const int* gdst = ei_gen + E_GEN;

  gemmf(hq_i, wqh, qh_b, qpre, E_GEN, 512, 256, 0, gsrc);    // q_emb @ qh_W
  gemmf(ht_i, wrh0, rh_b, rpre, E_GEN, 512, 256, 0, gdst);   // t_emb @ rh_W[0]
  gemmf(ha,  wrh1, nullptr, rpre, E_GEN, 512, 256, 1, gdst); // + a_emb @ rh_W[1]
  af_hidden<<<(E_GEN * 64 + 255) / 256, 256, 0, stream>>>(af, afp_W1, afp_b1,
                                                          afh, E_GEN);
  gemm(afh, wafp2, afp_b2, xlb, E_GEN, 64, 512);             // af_emb
  gemmf(xlb, wrh2, nullptr, rpre, E_GEN, 512, 256, 1);       // + af_emb @ rh_W[2]
  head_final<<<(E_GEN + 3) / 4, 256, 0, stream>>>(
      qpre, rpre, qh_g, qh_beta, rh_g, rh_beta, score_b, (float*)d_out, E_GEN);
}

// Round 9
// 1795.706 us; speedup vs baseline: 7.7105x; 1.0868x over previous
//
#include <hip/hip_runtime.h>
#include <cstdio>
#include <type_traits>

#define NQ 10000
#define NT 50000
#define NA 50000
#define E_GR 50000
#define E_LT 50000
#define E_SIM 80000
#define E_COMP 100000
#define E_GEN 50000
#define MAXE 100000
#define NEG_SLOPE 0.2f

typedef unsigned short bf16_t;
typedef unsigned int u32;
typedef __attribute__((ext_vector_type(8))) short short8v;
typedef __attribute__((ext_vector_type(4))) float f32x4;

__device__ __forceinline__ float bf2f(u32 bits) { return __uint_as_float(bits << 16); }
__device__ __forceinline__ u32 f2bf(float f) {
  u32 u = __float_as_uint(f);
  return (u + 0x7FFFu + ((u >> 16) & 1u)) >> 16;   // RTNE
}
__device__ __forceinline__ u32 pack2(float a, float b) { return f2bf(a) | (f2bf(b) << 16); }
__device__ __forceinline__ void unpack8(uint4 u, float* f) {
  f[0] = bf2f(u.x & 0xffffu); f[1] = bf2f(u.x >> 16);
  f[2] = bf2f(u.y & 0xffffu); f[3] = bf2f(u.y >> 16);
  f[4] = bf2f(u.z & 0xffffu); f[5] = bf2f(u.z >> 16);
  f[6] = bf2f(u.w & 0xffffu); f[7] = bf2f(u.w >> 16);
}

// async global->LDS, 16B per lane; LDS dest = wave-uniform base + lane*16.
__device__ __forceinline__ void gload16(const void* g, void* l) {
  __builtin_amdgcn_global_load_lds(
      (const __attribute__((address_space(1))) void*)g,
      (__attribute__((address_space(3))) void*)l, 16, 0, 0);
}

// ---------------------------------------------------------------------------
// MFMA bf16 GEMM. C[N,M] = A[N,K] @ Bt[M,K]^T (+bias | +=C).
// 256x256 tile, BK=64, 512 threads = 8 waves (2x4), wave tile 128x64,
// acc[8][4]. ONE covered drain per K64-tile (vs 2 barriers per K32 before):
//   stage A(s+1) | ds_read kh0 | 32 MFMA | stage B(s+1) | ds_read kh1 |
//   32 MFMA | vmcnt(0) + s_barrier
// A (cold HBM stream) issued first -> ~2 phases of latency cover; B is the
// 0.5MB L2-hot weight. Race-sound: reads touch only buf[cur], writes only
// buf[cur^1]; each wave drains its own loads before the single barrier.
// LDS 2 x (A 32KB + B 32KB) = 128KB, linear dest + both-sides XOR-octet
// swizzle (rule #21): store k-octet = (t&7)^((t>>4)&7); read octet =
// (fg+kh*4)^((row>>1)&7). Row stride 128B -> every row starts at bank 0;
// octet XOR spreads each 16-lane cohort across all 32 banks 2-way (free).
// XCD-grouped band swizzle; optional ridx A-row indirection.
// M%256==0, K%64==0; N guarded.
// ---------------------------------------------------------------------------
template <typename CT>
__global__ __launch_bounds__(512, 2) void bgemm(
    const bf16_t* __restrict__ A, const bf16_t* __restrict__ Bt,
    const float* __restrict__ bias, CT* __restrict__ C,
    const int* __restrict__ ridx, int N, int K, int M, int accumulate)
{
  __shared__ short lds[2][32768];   // [buf][A: 0..16383 | B: 16384..32767]
  const int tid = threadIdx.x;
  const int ncol = gridDim.x, nband = gridDim.y;

  // XCD-grouping swizzle (wg->XCD = id%8). Bijective incl. tail bands.
  int lin = blockIdx.y * ncol + blockIdx.x;
  int band, col;
  const int full = (nband >> 3) * 8 * ncol;
  if (lin < full) {
    int g = lin >> 3, x = lin & 7;
    band = x + 8 * (g / ncol);
    col  = g % ncol;
  } else {
    int r = lin - full;
    band = (nband & ~7) + r / ncol;
    col  = r % ncol;
  }
  const int bm = band * 256, bn = col * 256;

  const int lane = tid & 63;
  const int w = tid >> 6;          // 8 waves
  const int wr = w >> 2, wc = w & 3;
  const int fr = lane & 15, fg = lane >> 4;

  // staging: per matrix 2048 chunks (256 rows x 8 octets); thread t owns
  // chunks t+512r (r=0..3): row = (t>>3)+64r, store-octet = (t&7)^((t>>4)&7)
  // ((row>>1)&7 == (t>>4)&7 for all r since 64r>>1 is a multiple of 8).
  const int kg = (((tid & 7) ^ ((tid >> 4) & 7)) << 3);
  const bf16_t* gA[4];
  const bf16_t* gB[4];
#pragma unroll
  for (int r = 0; r < 4; ++r) {
    int rl = (tid >> 3) + 64 * r;
    int rc = min(bm + rl, N - 1);
    int arow = ridx ? ridx[rc] : rc;
    gA[r] = A + (size_t)arow * K + kg;
    gB[r] = Bt + (size_t)(bn + rl) * K + kg;
  }
  const int wdst = w << 9;   // wave-uniform LDS short offset (w*64 chunks *8)

  f32x4 acc[8][4];
#pragma unroll
  for (int i = 0; i < 8; ++i)
#pragma unroll
    for (int j = 0; j < 4; ++j) acc[i][j] = (f32x4){0.f, 0.f, 0.f, 0.f};

  auto stageA = [&](int buf, int k0) {
#pragma unroll
    for (int r = 0; r < 4; ++r)
      gload16(gA[r] + k0, &lds[buf][r * 4096 + wdst]);
  };
  auto stageB = [&](int buf, int k0) {
#pragma unroll
    for (int r = 0; r < 4; ++r)
      gload16(gB[r] + k0, &lds[buf][16384 + r * 4096 + wdst]);
  };

  const int nt = K >> 6;
  stageA(0, 0);
  stageB(0, 0);
  asm volatile("s_waitcnt vmcnt(0)" ::: "memory");
  __builtin_amdgcn_s_barrier();

  for (int s = 0; s < nt; ++s) {
    const int cur = s & 1;
    const short* LA = &lds[cur][0];
    const short* LB = &lds[cur][16384];
    const int k1 = (s + 1) << 6;
#pragma unroll
    for (int kh = 0; kh < 2; ++kh) {
      // issue next-tile stage first (A: cold stream, long cover; B: L2-hot)
      if (s + 1 < nt) {
        if (kh == 0) stageA(cur ^ 1, k1);
        else         stageB(cur ^ 1, k1);
      }
      short8v a[8], b[4];
#pragma unroll
      for (int f = 0; f < 8; ++f) {
        int R = wr * 128 + f * 16 + fr;
        a[f] = *(const short8v*)&LA[R * 64 + (((fg + kh * 4) ^ ((R >> 1) & 7)) << 3)];
      }
#pragma unroll
      for (int j = 0; j < 4; ++j) {
        int R = wc * 64 + j * 16 + fr;
        b[j] = *(const short8v*)&LB[R * 64 + (((fg + kh * 4) ^ ((R >> 1) & 7)) << 3)];
      }
#pragma unroll
      for (int i = 0; i < 8; ++i)
#pragma unroll
        for (int j = 0; j < 4; ++j)
          acc[i][j] = __builtin_amdgcn_mfma_f32_16x16x32_bf16(b[j], a[i],
                                                              acc[i][j], 0, 0, 0);
    }
    if (s + 1 < nt) {
      asm volatile("s_waitcnt vmcnt(0)" ::: "memory");   // covered drain
      __builtin_amdgcn_s_barrier();
    }
  }

  // epilogue: D cols (fr) = A rows; D row quad (fg*4+q) = C cols.
  float4 bv[4];
#pragma unroll
  for (int j = 0; j < 4; ++j) {
    bv[j] = make_float4(0.f, 0.f, 0.f, 0.f);
    if (!accumulate && bias)
      bv[j] = *(const float4*)(bias + bn + wc * 64 + j * 16 + fg * 4);
  }
#pragma unroll
  for (int i = 0; i < 8; ++i) {
    const int n = bm + wr * 128 + i * 16 + fr;
    if (n >= N) continue;
#pragma unroll
    for (int j = 0; j < 4; ++j) {
      const int m0 = bn + wc * 64 + j * 16 + fg * 4;
      f32x4 v = acc[i][j];
      if constexpr (std::is_same<CT, float>::value) {
        float* p = C + (size_t)n * M + m0;
        if (accumulate) {
          float4 o = *(float4*)p;
          o.x += v[0]; o.y += v[1]; o.z += v[2]; o.w += v[3];
          *(float4*)p = o;
        } else {
          *(float4*)p = make_float4(v[0] + bv[j].x, v[1] + bv[j].y,
                                    v[2] + bv[j].z, v[3] + bv[j].w);
        }
      } else {
        uint2 o;
        o.x = pack2(v[0] + bv[j].x, v[1] + bv[j].y);
        o.y = pack2(v[2] + bv[j].z, v[3] + bv[j].w);
        *(uint2*)(C + (size_t)n * M + m0) = o;
      }
    }
  }
}

// fp32 W[K][M] -> bf16 Wt[M][K] (transpose), 32x32 LDS tiles, z-batched.
__global__ __launch_bounds__(256) void convert_wT(
    const float* __restrict__ W, bf16_t* __restrict__ Wt, int K, int M)
{
  __shared__ float sm[32][33];
  W  += (size_t)blockIdx.z * K * M;
  Wt += (size_t)blockIdx.z * K * M;
  int mb = blockIdx.x * 32, kb = blockIdx.y * 32;
  int tx = threadIdx.x & 31, ty = threadIdx.x >> 5;
#pragma unroll
  for (int i = 0; i < 4; ++i)
    sm[ty + i * 8][tx] = W[(size_t)(kb + ty + i * 8) * M + mb + tx];
  __syncthreads();
#pragma unroll
  for (int i = 0; i < 4; ++i)
    Wt[(size_t)(mb + ty + i * 8) * K + kb + tx] = (bf16_t)f2bf(sm[tx][ty + i * 8]);
}

// fp32 -> bf16 flat cast, 4 elems/thread
__global__ __launch_bounds__(256) void f2bf_vec(
    const float* __restrict__ in, bf16_t* __restrict__ out, long n4)
{
  long t = (long)blockIdx.x * 256 + threadIdx.x;
  if (t >= n4) return;
  float4 v = ((const float4*)in)[t];
  uint2 o;
  o.x = pack2(v.x, v.y);
  o.y = pack2(v.z, v.w);
  ((uint2*)out)[t] = o;
}

// bc = (b0 [+b1] [+b2]) * inv  (512 floats)
__global__ __launch_bounds__(256) void combine_bias(
    const float* __restrict__ b0, const float* __restrict__ b1,
    const float* __restrict__ b2, float inv, float* __restrict__ out)
{
  int j = blockIdx.x * 256 + threadIdx.x;
  if (j >= 512) return;
  float v = b0[j];
  if (b1) v += b1[j];
  if (b2) v += b2[j];
  out[j] = v * inv;
}

// ---------------------------------------------------------------------------
// CSR build: histogram w/ slot assignment, 3-kernel exclusive scan, scatter.
// ---------------------------------------------------------------------------
__global__ __launch_bounds__(256) void csr_hist(
    const int* __restrict__ dst, int* __restrict__ deg, int* __restrict__ pos, int E)
{
  int e = blockIdx.x * 256 + threadIdx.x;
  if (e >= E) return;
  pos[e] = atomicAdd(&deg[dst[e]], 1);
}

__global__ __launch_bounds__(256) void scan1(
    const int* __restrict__ in, int* __restrict__ out, int* __restrict__ bsum, int n)
{
  __shared__ int sm[256];
  int t = threadIdx.x;
  int base = blockIdx.x * 1024 + t * 4;
  int v[4], sum = 0;
#pragma unroll
  for (int k = 0; k < 4; ++k) { v[k] = (base + k < n) ? in[base + k] : 0; sum += v[k]; }
  sm[t] = sum;
  __syncthreads();
  for (int off = 1; off < 256; off <<= 1) {
    int x = (t >= off) ? sm[t - off] : 0;
    __syncthreads();
    sm[t] += x;
    __syncthreads();
  }
  int run = (t > 0) ? sm[t - 1] : 0;
  if (t == 255) bsum[blockIdx.x] = sm[255];
#pragma unroll
  for (int k = 0; k < 4; ++k) {
    if (base + k < n) out[base + k] = run;
    run += v[k];
  }
}

__global__ __launch_bounds__(64) void scan2(int* __restrict__ bsum, int nb)
{
  __shared__ int sm[64];
  int t = threadIdx.x;
  int v = (t < nb) ? bsum[t] : 0;
  sm[t] = v;
  __syncthreads();
  for (int off = 1; off < 64; off <<= 1) {
    int x = (t >= off) ? sm[t - off] : 0;
    __syncthreads();
    sm[t] += x;
    __syncthreads();
  }
  if (t < nb) bsum[t] = sm[t] - v;   // exclusive
}

__global__ __launch_bounds__(256) void scan3(
    int* __restrict__ out, const int* __restrict__ bsum, int n)
{
  int g = blockIdx.x * 256 + threadIdx.x;
  if (g < n) out[g] += bsum[g >> 10];
}

__global__ __launch_bounds__(256) void csr_scatter(
    const int* __restrict__ dst, const int* __restrict__ start,
    const int* __restrict__ pos, int* __restrict__ eidx, int E)
{
  int e = blockIdx.x * 256 + threadIdx.x;
  if (e >= E) return;
  eidx[start[dst[e]] + pos[e]] = e;
}

// ---------------------------------------------------------------------------
// Fused GATv2 message+softmax+aggregate, one wave per dst node, no atomics.
// If bc != nullptr: also applies HeteroConv-mean + bias + relu (final
// relation for this node type) and writes the NEW h in place of acc.
// ---------------------------------------------------------------------------
__global__ __launch_bounds__(256) void gat_fused(
    const bf16_t* __restrict__ xl, const bf16_t* __restrict__ xr,
    const int* __restrict__ srcArr, const int* __restrict__ start,
    const int* __restrict__ deg, const int* __restrict__ eidx,
    const float* __restrict__ att, bf16_t* __restrict__ acc,
    int Nd, int accumulate, const float* __restrict__ bc, float inv_div)
{
  int d = blockIdx.x * 4 + (threadIdx.x >> 6);
  if (d >= Nd) return;
  int lane = threadIdx.x & 63;

  float xrr[8];
  unpack8(*(const uint4*)(xr + (size_t)d * 512 + lane * 8), xrr);
  float at[8];
  *(float4*)(at)     = *(const float4*)(att + lane * 8);
  *(float4*)(at + 4) = *(const float4*)(att + lane * 8 + 4);

  float acc8[8] = {0.f, 0.f, 0.f, 0.f, 0.f, 0.f, 0.f, 0.f};
  float den = 0.f;
  int n = deg[d], s0 = start[d];
  for (int i = 0; i < n; ++i) {
    int e = eidx[s0 + i];
    int s = srcArr[e];
    float f[8];
    unpack8(*(const uint4*)(xl + (size_t)s * 512 + lane * 8), f);
    float p = 0.f;
#pragma unroll
    for (int k = 0; k < 8; ++k) {
      float x = f[k] + xrr[k];
      p = fmaf(at[k], x >= 0.f ? x : NEG_SLOPE * x, p);
    }
#pragma unroll
    for (int m = 8; m >= 1; m >>= 1) p += __shfl_xor(p, m);  // 16-lane group = head
    float ex = __expf(p);
    den += ex;
#pragma unroll
    for (int k = 0; k < 8; ++k) acc8[k] = fmaf(ex, f[k], acc8[k]);
  }
  float inv = 1.f / (den + 1e-16f);
#pragma unroll
  for (int k = 0; k < 8; ++k) acc8[k] *= inv;

  bf16_t* out = acc + (size_t)d * 512 + lane * 8;
  if (accumulate) {
    float old[8];
    unpack8(*(const uint4*)out, old);
#pragma unroll
    for (int k = 0; k < 8; ++k) acc8[k] += old[k];
  }
  if (bc) {   // finalize: mean + combined bias + relu
    float bcv[8];
    *(float4*)(bcv)     = *(const float4*)(bc + lane * 8);
    *(float4*)(bcv + 4) = *(const float4*)(bc + lane * 8 + 4);
#pragma unroll
    for (int k = 0; k < 8; ++k)
      acc8[k] = fmaxf(fmaf(acc8[k], inv_div, bcv[k]), 0.f);
  }
  uint4 s;
  s.x = pack2(acc8[0], acc8[1]); s.y = pack2(acc8[2], acc8[3]);
  s.z = pack2(acc8[4], acc8[5]); s.w = pack2(acc8[6], acc8[7]);
  *(uint4*)out = s;
}

// afh = relu(answer_features @ W1 + b1) -> bf16, K=6, M=64
__global__ __launch_bounds__(256) void af_hidden(
    const float* __restrict__ af, const float* __restrict__ W1,
    const float* __restrict__ b1, bf16_t* __restrict__ out, int n)
{
  int t = blockIdx.x * blockDim.x + threadIdx.x;
  if (t >= n * 64) return;
  int i = t >> 6, j = t & 63;
  const float* a = af + (size_t)i * 6;
  float s = b1[j];
#pragma unroll
  for (int k = 0; k < 6; ++k) s = fmaf(a[k], W1[k * 64 + j], s);
  out[t] = (bf16_t)f2bf(fmaxf(s, 0.f));
}

__global__ __launch_bounds__(256) void build_sim(
    const int* __restrict__ ei, int* __restrict__ ss, int* __restrict__ sd)
{
  int t = blockIdx.x * blockDim.x + threadIdx.x;
  if (t >= E_SIM + NQ) return;
  if (t < E_SIM) { ss[t] = ei[t]; sd[t] = ei[E_SIM + t]; }
  else           { ss[t] = t - E_SIM; sd[t] = t - E_SIM; }
}

__global__ __launch_bounds__(256) void head_final(
    const float* __restrict__ qpre, const float* __restrict__ rpre,
    const float* __restrict__ qg, const float* __restrict__ qb,
    const float* __restrict__ rg, const float* __restrict__ rb,
    const float* __restrict__ score_bias, float* __restrict__ out, int E)
{
  int e = blockIdx.x * 4 + (threadIdx.x >> 6);
  if (e >= E) return;
  int lane = threadIdx.x & 63;

  float4 q = *(const float4*)(qpre + (size_t)e * 256 + lane * 4);
  float s = q.x + q.y + q.z + q.w;
#pragma unroll
  for (int m = 32; m >= 1; m >>= 1) s += __shfl_xor(s, m);
  float mu = s * (1.f / 256.f);
  float dq0 = q.x - mu, dq1 = q.y - mu, dq2 = q.z - mu, dq3 = q.w - mu;
  float v = dq0 * dq0 + dq1 * dq1 + dq2 * dq2 + dq3 * dq3;
#pragma unroll
  for (int m = 32; m >= 1; m >>= 1) v += __shfl_xor(v, m);
  float rstd = rsqrtf(v * (1.f / 256.f) + 1e-5f);
  float4 g4 = *(const float4*)(qg + lane * 4);
  float4 b4 = *(const float4*)(qb + lane * 4);
  float qn0 = dq0 * rstd * g4.x + b4.x, qn1 = dq1 * rstd * g4.y + b4.y;
  float qn2 = dq2 * rstd * g4.z + b4.z, qn3 = dq3 * rstd * g4.w + b4.w;

  float4 r = *(const float4*)(rpre + (size_t)e * 256 + lane * 4);
  s = r.x + r.y + r.z + r.w;
#pragma unroll
  for (int m = 32; m >= 1; m >>= 1) s += __shfl_xor(s, m);
  mu = s * (1.f / 256.f);
  float dr0 = r.x - mu, dr1 = r.y - mu, dr2 = r.z - mu, dr3 = r.w - mu;
  v = dr0 * dr0 + dr1 * dr1 + dr2 * dr2 + dr3 * dr3;
#pragma unroll
  for (int m = 32; m >= 1; m >>= 1) v += __shfl_xor(v, m);
  rstd = rsqrtf(v * (1.f / 256.f) + 1e-5f);
  g4 = *(const float4*)(rg + lane * 4);
  b4 = *(const float4*)(rb + lane * 4);
  float rn0 = dr0 * rstd * g4.x + b4.x, rn1 = dr1 * rstd * g4.y + b4.y;
  float rn2 = dr2 * rstd * g4.z + b4.z, rn3 = dr3 * rstd * g4.w + b4.w;

  float d = qn0 * rn0 + qn1 * rn1 + qn2 * rn2 + qn3 * rn3;
#pragma unroll
  for (int m = 32; m >= 1; m >>= 1) d += __shfl_xor(d, m);
  if (lane == 0) out[e] = d * 0.0625f + score_bias[0];
}

// ---------------------------------------------------------------------------
extern "C" void kernel_launch(void* const* d_in, const int* in_sizes, int n_in,
                              void* d_out, int out_size, void* d_ws, size_t ws_size,
                              hipStream_t stream) {
  (void)in_sizes; (void)n_in; (void)out_size;
  const float* xq      = (const float*)d_in[0];
  const float* xt      = (const float*)d_in[1];
  const float* xa      = (const float*)d_in[2];
  const float* af      = (const float*)d_in[3];
  const float* qp_W    = (const float*)d_in[4];
  const float* qp_b    = (const float*)d_in[5];
  const float* tp_W    = (const float*)d_in[6];
  const float* tp_b    = (const float*)d_in[7];
  const float* ap_W    = (const float*)d_in[8];
  const float* ap_b    = (const float*)d_in[9];
  const float* afp_W1  = (const float*)d_in[10];
  const float* afp_b1  = (const float*)d_in[11];
  const float* afp_W2  = (const float*)d_in[12];
  const float* afp_b2  = (const float*)d_in[13];
  const float* conv_Wl = (const float*)d_in[14];
  const float* conv_bl = (const float*)d_in[15];
  const float* conv_Wr = (const float*)d_in[16];
  const float* conv_br = (const float*)d_in[17];
  const float* conv_att  = (const float*)d_in[18];
  const float* conv_bias = (const float*)d_in[19];
  const float* qh_W    = (const float*)d_in[20];
  const float* qh_b    = (const float*)d_in[21];
  const float* qh_g    = (const float*)d_in[22];
  const float* qh_beta = (const float*)d_in[23];
  const float* rh_W    = (const float*)d_in[24];
  const float* rh_b    = (const float*)d_in[25];
  const float* rh_g    = (const float*)d_in[26];
  const float* rh_beta = (const float*)d_in[27];
  const float* score_b = (const float*)d_in[28];
  const int* ei_gr   = (const int*)d_in[29];
  const int* ei_lt   = (const int*)d_in[30];
  const int* ei_sim  = (const int*)d_in[31];
  const int* ei_comp = (const int*)d_in[32];
  const int* ei_gen  = (const int*)d_in[33];

  char* base = (char*)d_ws;
  size_t off = 0;
  auto alloc = [&](size_t bytes) {
    void* p = base + off;
    off = (off + bytes + 255) & ~(size_t)255;
    return p;
  };
  bf16_t* hq   = (bf16_t*)alloc((size_t)NQ * 512 * 2);
  bf16_t* ht   = (bf16_t*)alloc((size_t)NT * 512 * 2);
  bf16_t* ha   = (bf16_t*)alloc((size_t)NA * 512 * 2);
  bf16_t* acct = (bf16_t*)alloc((size_t)NT * 512 * 2);   // ht ping-pong; qpre f32
  bf16_t* accq = (bf16_t*)alloc((size_t)NQ * 512 * 2);   // hq ping-pong; afh bf16
  bf16_t* xlb  = (bf16_t*)alloc((size_t)50000 * 512 * 2);// staging/af_emb
  bf16_t* xrb  = (bf16_t*)alloc((size_t)50000 * 512 * 2);// also rpre f32
  int* simsrc  = (int*)alloc((size_t)(E_SIM + NQ) * 4);
  int* simdst  = (int*)alloc((size_t)(E_SIM + NQ) * 4);

  // bf16-transposed weights
  bf16_t* wqp  = (bf16_t*)alloc((size_t)512 * 384 * 2);
  bf16_t* wtp  = (bf16_t*)alloc((size_t)512 * 384 * 2);
  bf16_t* wap  = (bf16_t*)alloc((size_t)512 * 384 * 2);
  bf16_t* wl   = (bf16_t*)alloc((size_t)12 * 512 * 512 * 2);
  bf16_t* wr   = (bf16_t*)alloc((size_t)12 * 512 * 512 * 2);
  bf16_t* wafp2 = (bf16_t*)alloc((size_t)512 * 64 * 2);
  bf16_t* wqh  = (bf16_t*)alloc((size_t)256 * 512 * 2);
  bf16_t* wrh0 = (bf16_t*)alloc((size_t)256 * 512 * 2);
  bf16_t* wrh1 = (bf16_t*)alloc((size_t)256 * 512 * 2);
  bf16_t* wrh2 = (bf16_t*)alloc((size_t)256 * 512 * 2);
  float* bc_t  = (float*)alloc(512 * 4);
  float* bc_q  = (float*)alloc(512 * 4);
  float* bc_a  = (float*)alloc(512 * 4);

  // CSR topology. Order: 0=gr 1=rgr 2=rlt 3=sim 4=comp 5=lt (lt LAST)
  struct Topo { const int* src; const int* dst; int Nd, E; };
  Topo topo[6] = {
    {ei_gr,        ei_gr + E_GR,     NT, E_GR},
    {ei_gr + E_GR, ei_gr,            NQ, E_GR},
    {ei_lt + E_LT, ei_lt,            NT, E_LT},
    {simsrc,       simdst,           NQ, E_SIM + NQ},
    {ei_comp,      ei_comp + E_COMP, NT, E_COMP},
    {ei_lt,        ei_lt + E_LT,     NA, E_LT},
  };
  int *deg[6], *startp[6], *eidx[6];
  for (int r = 0; r < 6; ++r) {
    deg[r]    = (int*)alloc((size_t)topo[r].Nd * 4);
    startp[r] = (int*)alloc((size_t)topo[r].Nd * 4);
    eidx[r]   = (int*)alloc((size_t)topo[r].E * 4);
  }
  int* posb = (int*)alloc((size_t)MAXE * 4);
  int* bsum = (int*)alloc(64 * 4);
  if (off > ws_size) {
    fprintf(stderr, "kernel_launch: ws too small, need %zu have %zu\n", off, ws_size);
    return;
  }

  // --- weight conversion (fp32 [K][M] -> bf16 [M][K]) ---
  convert_wT<<<dim3(512 / 32, 512 / 32, 12), 256, 0, stream>>>(conv_Wl, wl, 512, 512);
  convert_wT<<<dim3(512 / 32, 512 / 32, 12), 256, 0, stream>>>(conv_Wr, wr, 512, 512);
  convert_wT<<<dim3(512 / 32, 384 / 32, 1), 256, 0, stream>>>(qp_W, wqp, 384, 512);
  convert_wT<<<dim3(512 / 32, 384 / 32, 1), 256, 0, stream>>>(tp_W, wtp, 384, 512);
  convert_wT<<<dim3(512 / 32, 384 / 32, 1), 256, 0, stream>>>(ap_W, wap, 384, 512);
  convert_wT<<<dim3(512 / 32, 64 / 32, 1), 256, 0, stream>>>(afp_W2, wafp2, 64, 512);
  convert_wT<<<dim3(256 / 32, 512 / 32, 1), 256, 0, stream>>>(qh_W, wqh, 512, 256);
  convert_wT<<<dim3(256 / 32, 512 / 32, 1), 256, 0, stream>>>(rh_W, wrh0, 512, 256);
  convert_wT<<<dim3(256 / 32, 512 / 32, 1), 256, 0, stream>>>(rh_W + 512 * 256, wrh1, 512, 256);
  convert_wT<<<dim3(256 / 32, 512 / 32, 1), 256, 0, stream>>>(rh_W + 1024 * 256, wrh2, 512, 256);

  build_sim<<<(E_SIM + NQ + 255) / 256, 256, 0, stream>>>(ei_sim, simsrc, simdst);
  for (int r = 0; r < 6; ++r) {
    const Topo& T = topo[r];
    hipMemsetAsync(deg[r], 0, (size_t)T.Nd * 4, stream);
    csr_hist<<<(T.E + 255) / 256, 256, 0, stream>>>(T.dst, deg[r], posb, T.E);
    int nb = (T.Nd + 1023) / 1024;
    scan1<<<nb, 256, 0, stream>>>(deg[r], startp[r], bsum, T.Nd);
    scan2<<<1, 64, 0, stream>>>(bsum, nb);
    scan3<<<(T.Nd + 255) / 256, 256, 0, stream>>>(startp[r], bsum, T.Nd);
    csr_scatter<<<(T.E + 255) / 256, 256, 0, stream>>>(T.dst, startp[r], posb,
                                                       eidx[r], T.E);
  }

  auto gemm = [&](const bf16_t* A, const bf16_t* Bt, const float* bias, bf16_t* C,
                  int N_, int K_, int M_, const int* ridx = nullptr) {
    dim3 g(M_ / 256, (N_ + 255) / 256);
    bgemm<bf16_t><<<g, 512, 0, stream>>>(A, Bt, bias, C, ridx, N_, K_, M_, 0);
  };
  auto gemmf = [&](const bf16_t* A, const bf16_t* Bt, const float* bias, float* C,
                   int N_, int K_, int M_, int acc_, const int* ridx = nullptr) {
    dim3 g(M_ / 256, (N_ + 255) / 256);
    bgemm<float><<<g, 512, 0, stream>>>(A, Bt, bias, C, ridx, N_, K_, M_, acc_);
  };

  // Input projections: cast fp32 inputs to bf16 in xlb, then MFMA GEMM.
  f2bf_vec<<<((long)NQ * 96 + 255) / 256, 256, 0, stream>>>(xq, xlb, (long)NQ * 96);
  gemm(xlb, wqp, qp_b, hq, NQ, 384, 512);
  f2bf_vec<<<((long)NT * 96 + 255) / 256, 256, 0, stream>>>(xt, xlb, (long)NT * 96);
  gemm(xlb, wtp, tp_b, ht, NT, 384, 512);
  f2bf_vec<<<((long)NA * 96 + 255) / 256, 256, 0, stream>>>(xa, xlb, (long)NA * 96);
  gemm(xlb, wap, ap_b, ha, NA, 384, 512);

  // Layer loop with ping-pong h buffers; last relation per dst type carries
  // the fused mean+bias+relu (bc != null) and produces the new h in acc.
  bf16_t *hq_i = hq, *ht_i = ht, *hq_o = accq, *ht_o = acct;
  for (int l = 0; l < 2; ++l) {
    size_t b = (size_t)l * 6;
    combine_bias<<<2, 256, 0, stream>>>(conv_bias + (b + 0) * 512,
        conv_bias + (b + 3) * 512, conv_bias + (b + 5) * 512, 1.f / 3.f, bc_t);
    combine_bias<<<2, 256, 0, stream>>>(conv_bias + (b + 1) * 512,
        conv_bias + (b + 4) * 512, nullptr, 0.5f, bc_q);
    combine_bias<<<2, 256, 0, stream>>>(conv_bias + (b + 2) * 512,
        nullptr, nullptr, 1.f, bc_a);

    struct Rel { const bf16_t* xs; const bf16_t* xd; int Ns, po; bf16_t* acc;
                 int accum; const float* bc; float inv; };
    Rel rels[6] = {
      {hq_i, ht_i, NQ, 0, ht_o, 0, nullptr, 0.f},      // gr
      {ht_i, hq_i, NT, 1, hq_o, 0, nullptr, 0.f},      // rgr
      {ha,   ht_i, NA, 3, ht_o, 1, nullptr, 0.f},      // rlt
      {hq_i, hq_i, NQ, 4, hq_o, 1, bc_q, 0.5f},        // sim (final for q)
      {ht_i, ht_i, NT, 5, ht_o, 1, bc_t, 1.f / 3.f},   // comp (final for t)
      {ht_i, ha,   NT, 2, ha,   0, bc_a, 1.f},         // lt (final for a, in-place)
    };
    for (int r = 0; r < 6; ++r) {
      const Rel& R = rels[r];
      const Topo& T = topo[r];
      size_t po = (size_t)l * 6 + R.po;
      gemm(R.xs, wl + po * 512 * 512, conv_bl + po * 512, xlb, R.Ns, 512, 512);
      gemm(R.xd, wr + po * 512 * 512, conv_br + po * 512, xrb, T.Nd, 512, 512);
      int gb = (T.Nd + 3) / 4;
      gat_fused<<<gb, 256, 0, stream>>>(xlb, xrb, T.src, startp[r], deg[r],
                                        eidx[r], conv_att + po * 512, R.acc,
                                        T.Nd, R.accum, R.bc, R.inv);
    }
    bf16_t* t;
    t = hq_i; hq_i = hq_o; hq_o = t;
    t = ht_i; ht_i = ht_o; ht_o = t;
  }
  // after 2 swaps: hq_i==hq, ht_i==ht; scratch acct/accq free again.

  // Head: gathers fused into bgemm via ridx. qpre(f32)->acct region,
  // rpre(f32)->xrb region, af_emb->xlb, afh(bf16)->accq.
  float* qpre = (float*)acct;
  float* rpre = (float*)xrb;
  bf16_t* afh = accq;
  const int* gsrc = ei_gen;
  const int* gdst = ei_gen + E_GEN;

  gemmf(hq_i, wqh, qh_b, qpre, E_GEN, 512, 256, 0, gsrc);    // q_emb @ qh_W
  gemmf(ht_i, wrh0, rh_b, rpre, E_GEN, 512, 256, 0, gdst);   // t_emb @ rh_W[0]
  gemmf(ha,  wrh1, nullptr, rpre, E_GEN, 512, 256, 1, gdst); // + a_emb @ rh_W[1]
  af_hidden<<<(E_GEN * 64 + 255) / 256, 256, 0, stream>>>(af, afp_W1, afp_b1,
                                                          afh, E_GEN);
  gemm(afh, wafp2, afp_b2, xlb, E_GEN, 64, 512);             // af_emb
  gemmf(xlb, wrh2, nullptr, rpre, E_GEN, 512, 256, 1);       // + af_emb @ rh_W[2]
  head_final<<<(E_GEN + 3) / 4, 256, 0, stream>>>(
      qpre, rpre, qh_g, qh_beta, rh_g, rh_beta, score_b, (float*)d_out, E_GEN);
}